// Round 4
// baseline (690.809 us; speedup 1.0000x reference)
//
#include <hip/hip_runtime.h>

#define N_NODES 100000
#define N_EDGES 1600000
#define HID 64
#define BN_EPS 1e-5f

#define GEMM_BLOCKS 1024     // 256 threads = 4 waves each
#define GATHER_BLOCKS 2048
#define SCAN_CHUNK 512
#define SCAN_BLOCKS ((N_NODES + SCAN_CHUNK - 1) / SCAN_CHUNK)   // 196

// XCD-ownership partition for CSR build
#define NXCD 8
#define NODES_PER_XCD (N_NODES / NXCD)          // 12500
#define FILL_CHUNKS 32
#define EDGES_PER_CHUNK (N_EDGES / FILL_CHUNKS) // 50000

__device__ __forceinline__ float bcastf(float v, int k) {
    return __int_as_float(__builtin_amdgcn_readlane(__float_as_int(v), k));
}

// ---------------- CSR build (XCD-ownership variant) ----------------
// block b: owns dst range [(b%8)*12500, +12500), scans edge chunk b/8.
// All RMW/writes for a given deg/eidx window come from one XCD -> lines
// stay in that XCD's L2 until full.
__global__ __launch_bounds__(256) void hist_xcd_kernel(
        const int* __restrict__ dst, int* __restrict__ deg) {
    const int X  = blockIdx.x & (NXCD - 1);
    const int g  = blockIdx.x >> 3;
    const int lo = X * NODES_PER_XCD;
    const int e0 = g * EDGES_PER_CHUNK;
    for (int e = e0 + threadIdx.x; e < e0 + EDGES_PER_CHUNK; e += 256) {
        int d = dst[e];
        if ((unsigned)(d - lo) < (unsigned)NODES_PER_XCD)
            atomicAdd(&deg[d], 1);
    }
}

__global__ __launch_bounds__(256) void fill_xcd_kernel(
        const int* __restrict__ src, const int* __restrict__ dst,
        int* __restrict__ cursor, int* __restrict__ eidx) {
    const int X  = blockIdx.x & (NXCD - 1);
    const int g  = blockIdx.x >> 3;
    const int lo = X * NODES_PER_XCD;
    const int e0 = g * EDGES_PER_CHUNK;
    for (int e = e0 + threadIdx.x; e < e0 + EDGES_PER_CHUNK; e += 256) {
        int d = dst[e];
        if ((unsigned)(d - lo) < (unsigned)NODES_PER_XCD) {
            int p = atomicAdd(&cursor[d], 1);
            eidx[p] = src[e];
        }
    }
}

// block-local exclusive scan of 512 elements (2 per thread)
__global__ __launch_bounds__(256) void scan_partial_kernel(
        const int* __restrict__ deg, int* __restrict__ off, int* __restrict__ bsums) {
    __shared__ int sd[256];
    int t = threadIdx.x;
    int base = blockIdx.x * SCAN_CHUNK;
    int i0 = base + 2 * t, i1 = i0 + 1;
    int d0 = (i0 < N_NODES) ? deg[i0] : 0;
    int d1 = (i1 < N_NODES) ? deg[i1] : 0;
    sd[t] = d0 + d1;
    __syncthreads();
    for (int o = 1; o < 256; o <<= 1) {
        int v = (t >= o) ? sd[t - o] : 0;
        __syncthreads();
        sd[t] += v;
        __syncthreads();
    }
    int excl = sd[t] - (d0 + d1);   // exclusive within block
    if (i0 < N_NODES) off[i0] = excl;
    if (i1 < N_NODES) off[i1] = excl + d0;
    if (t == 255) bsums[blockIdx.x] = sd[255];
}

__global__ __launch_bounds__(256) void scan_bsums_kernel(int* __restrict__ bsums) {
    __shared__ int sd[256];
    int t = threadIdx.x;
    int v = (t < SCAN_BLOCKS) ? bsums[t] : 0;
    sd[t] = v;
    __syncthreads();
    for (int o = 1; o < 256; o <<= 1) {
        int u = (t >= o) ? sd[t - o] : 0;
        __syncthreads();
        sd[t] += u;
        __syncthreads();
    }
    if (t < SCAN_BLOCKS) bsums[t] = sd[t] - v;   // exclusive
}

__global__ __launch_bounds__(256) void scan_addback_kernel(
        int* __restrict__ off, int* __restrict__ cursor, const int* __restrict__ bsums) {
    int t = threadIdx.x;
    int b = bsums[blockIdx.x];
    int base = blockIdx.x * SCAN_CHUNK;
    int i0 = base + 2 * t, i1 = i0 + 1;
    if (i0 < N_NODES) { int v = off[i0] + b; off[i0] = v; cursor[i0] = v; }
    if (i1 < N_NODES) { int v = off[i1] + b; off[i1] = v; cursor[i1] = v; }
    if (blockIdx.x == 0 && t == 0) off[N_NODES] = N_EDGES;
}

// ---------------- fused gather + GEMM1 + BN stats ----------------
// agg[n] = xin[n] + sum_{j in-edges} xin[src_j]; h[n] = agg[n] @ W1 + b1; stats over h
__global__ __launch_bounds__(256) void gin_gather_gemm_kernel(
        const float* __restrict__ xin, const int* __restrict__ off,
        const int* __restrict__ eidx, const float* __restrict__ W,
        const float* __restrict__ bias, float* __restrict__ h,
        float* __restrict__ stats_partial) {
    const int lane = threadIdx.x & 63;
    const int w    = threadIdx.x >> 6;

    float wcol[64];
#pragma unroll
    for (int k = 0; k < 64; ++k) wcol[k] = W[k * HID + lane];
    const float bs = bias[lane];

    float ssum = 0.f, ssumsq = 0.f;
    const int gw = blockIdx.x * 4 + w;
    const int stride = gridDim.x * 4;
    for (int n = gw; n < N_NODES; n += stride) {
        float v = xin[(size_t)n * HID + lane];   // (1+eps)*x self term, eps=0
        int beg = off[n], end = off[n + 1];
        int j = beg;
        for (; j + 8 <= end; j += 8) {
            int s0 = eidx[j],     s1 = eidx[j + 1], s2 = eidx[j + 2], s3 = eidx[j + 3];
            int s4 = eidx[j + 4], s5 = eidx[j + 5], s6 = eidx[j + 6], s7 = eidx[j + 7];
            float v0 = xin[(size_t)s0 * HID + lane];
            float v1 = xin[(size_t)s1 * HID + lane];
            float v2 = xin[(size_t)s2 * HID + lane];
            float v3 = xin[(size_t)s3 * HID + lane];
            float v4 = xin[(size_t)s4 * HID + lane];
            float v5 = xin[(size_t)s5 * HID + lane];
            float v6 = xin[(size_t)s6 * HID + lane];
            float v7 = xin[(size_t)s7 * HID + lane];
            v += ((v0 + v1) + (v2 + v3)) + ((v4 + v5) + (v6 + v7));
        }
        if (j + 4 <= end) {
            int s0 = eidx[j], s1 = eidx[j + 1], s2 = eidx[j + 2], s3 = eidx[j + 3];
            float v0 = xin[(size_t)s0 * HID + lane];
            float v1 = xin[(size_t)s1 * HID + lane];
            float v2 = xin[(size_t)s2 * HID + lane];
            float v3 = xin[(size_t)s3 * HID + lane];
            v += (v0 + v1) + (v2 + v3);
            j += 4;
        }
        for (; j < end; ++j) v += xin[(size_t)eidx[j] * HID + lane];

        float acc = bs;
#pragma unroll
        for (int k = 0; k < 64; ++k)
            acc = fmaf(bcastf(v, k), wcol[k], acc);
        h[(size_t)n * HID + lane] = acc;
        ssum += acc; ssumsq += acc * acc;
    }

    __shared__ float red[2][256];
    red[0][threadIdx.x] = ssum;
    red[1][threadIdx.x] = ssumsq;
    __syncthreads();
    if (w == 0) {
        float s = red[0][lane] + red[0][64 + lane] + red[0][128 + lane] + red[0][192 + lane];
        float q = red[1][lane] + red[1][64 + lane] + red[1][128 + lane] + red[1][192 + lane];
        stats_partial[(size_t)blockIdx.x * 128 + lane]      = s;
        stats_partial[(size_t)blockIdx.x * 128 + 64 + lane] = q;
    }
}

// ---------------- fused row-GEMM ----------------
template<bool PRE_BN, bool POST_RELU, bool ACCUM>
__global__ __launch_bounds__(256) void fused_gemm_kernel(
        const float* __restrict__ in, const float* __restrict__ W,
        const float* __restrict__ bias, const float* __restrict__ scale,
        const float* __restrict__ shift, float* __restrict__ out, int nrows) {
    const int lane = threadIdx.x & 63;
    const int w    = threadIdx.x >> 6;

    float wcol[64];
#pragma unroll
    for (int k = 0; k < 64; ++k) wcol[k] = W[k * HID + lane];

    float sc = 0.f, sh = 0.f, bs = 0.f;
    if (PRE_BN) { sc = scale[lane]; sh = shift[lane]; }
    if (!ACCUM) bs = bias[lane];

    const int gw = blockIdx.x * 4 + w;
    const int stride = gridDim.x * 4;
    for (int r = gw; r < nrows; r += stride) {
        float v = in[(size_t)r * HID + lane];
        if (PRE_BN) v = fmaxf(fmaf(sc, v, sh), 0.f);
        float acc = ACCUM ? out[(size_t)r * HID + lane] : bs;
#pragma unroll
        for (int k = 0; k < 64; ++k)
            acc = fmaf(bcastf(v, k), wcol[k], acc);
        if (POST_RELU) acc = fmaxf(acc, 0.f);
        out[(size_t)r * HID + lane] = acc;
    }
}

// ---------------- BN finalize: parallel reduce of partials ----------------
__global__ __launch_bounds__(1024) void bn_finalize_kernel(
        const float* __restrict__ stats_partial, int nblocks,
        const float* __restrict__ gamma, const float* __restrict__ beta,
        float* __restrict__ scale, float* __restrict__ shift) {
    __shared__ float red[2][1024];
    const int t = threadIdx.x;
    const int c = t & 63;
    const int chunk = t >> 6;        // 0..15
    float s = 0.f, q = 0.f;
    for (int b = chunk; b < nblocks; b += 16) {
        s += stats_partial[(size_t)b * 128 + c];
        q += stats_partial[(size_t)b * 128 + 64 + c];
    }
    red[0][t] = s;
    red[1][t] = q;
    __syncthreads();
    if (chunk == 0) {
        float ss = 0.f, qq = 0.f;
#pragma unroll
        for (int k = 0; k < 16; ++k) {
            ss += red[0][k * 64 + c];
            qq += red[1][k * 64 + c];
        }
        float mean = ss / (float)N_NODES;
        float var  = qq / (float)N_NODES - mean * mean;
        float scl  = gamma[c] * rsqrtf(var + BN_EPS);
        scale[c] = scl;
        shift[c] = beta[c] - mean * scl;
    }
}

extern "C" void kernel_launch(void* const* d_in, const int* in_sizes, int n_in,
                              void* d_out, int out_size, void* d_ws, size_t ws_size,
                              hipStream_t stream) {
    const float* x    = (const float*)d_in[0];
    const int*   ei   = (const int*)d_in[1];
    const int*   src  = ei;
    const int*   dst  = ei + N_EDGES;
    const float* W1_0 = (const float*)d_in[3];
    const float* b1_0 = (const float*)d_in[4];
    const float* g_0  = (const float*)d_in[5];
    const float* be_0 = (const float*)d_in[6];
    const float* W2_0 = (const float*)d_in[7];
    const float* b2_0 = (const float*)d_in[8];
    const float* W1_1 = (const float*)d_in[9];
    const float* b1_1 = (const float*)d_in[10];
    const float* g_1  = (const float*)d_in[11];
    const float* be_1 = (const float*)d_in[12];
    const float* W2_1 = (const float*)d_in[13];
    const float* b2_1 = (const float*)d_in[14];
    const float* Wjk  = (const float*)d_in[15];
    const float* bjk  = (const float*)d_in[16];

    const size_t FEAT = (size_t)N_NODES * HID;

    float* tmp   = (float*)d_ws;                       // FEAT (pre-BN h, then h2 in-place)
    float* h1    = tmp + FEAT;                         // FEAT
    float* stats = h1 + FEAT;                          // GATHER_BLOCKS * 128
    float* scale = stats + (size_t)GATHER_BLOCKS * 128;
    float* shift = scale + 64;
    int*   deg    = (int*)(shift + 64);                // N_NODES
    int*   off    = deg + N_NODES;                     // N_NODES + 1 (pad 2)
    int*   cursor = off + N_NODES + 2;                 // N_NODES
    int*   bsums  = cursor + N_NODES;                  // 256
    int*   eidx   = bsums + 256;                       // N_EDGES
    float* out    = (float*)d_out;

    // ---------------- CSR build (once; reused by both layers) ----------------
    hipMemsetAsync(deg, 0, N_NODES * sizeof(int), stream);
    hist_xcd_kernel<<<NXCD * FILL_CHUNKS, 256, 0, stream>>>(dst, deg);
    scan_partial_kernel<<<SCAN_BLOCKS, 256, 0, stream>>>(deg, off, bsums);
    scan_bsums_kernel<<<1, 256, 0, stream>>>(bsums);
    scan_addback_kernel<<<SCAN_BLOCKS, 256, 0, stream>>>(off, cursor, bsums);
    fill_xcd_kernel<<<NXCD * FILL_CHUNKS, 256, 0, stream>>>(src, dst, cursor, eidx);

    // ---------------- layer 0 ----------------
    gin_gather_gemm_kernel<<<GATHER_BLOCKS, 256, 0, stream>>>(
        x, off, eidx, W1_0, b1_0, tmp, stats);
    bn_finalize_kernel<<<1, 1024, 0, stream>>>(stats, GATHER_BLOCKS, g_0, be_0, scale, shift);
    fused_gemm_kernel<true, true, false><<<GEMM_BLOCKS, 256, 0, stream>>>(
        tmp, W2_0, b2_0, scale, shift, h1, N_NODES);

    // ---------------- layer 1 ----------------
    gin_gather_gemm_kernel<<<GATHER_BLOCKS, 256, 0, stream>>>(
        h1, off, eidx, W1_1, b1_1, tmp, stats);
    bn_finalize_kernel<<<1, 1024, 0, stream>>>(stats, GATHER_BLOCKS, g_1, be_1, scale, shift);
    fused_gemm_kernel<true, true, false><<<GEMM_BLOCKS, 256, 0, stream>>>(
        tmp, W2_1, b2_1, scale, shift, tmp, N_NODES);   // in-place: tmp becomes h2

    // ---------------- jump head: out = [x|h1|h2] @ Wjk + bjk ----------------
    fused_gemm_kernel<false, false, false><<<GEMM_BLOCKS, 256, 0, stream>>>(
        x, Wjk, bjk, nullptr, nullptr, out, N_NODES);
    fused_gemm_kernel<false, false, true><<<GEMM_BLOCKS, 256, 0, stream>>>(
        h1, Wjk + (size_t)64 * HID, nullptr, nullptr, nullptr, out, N_NODES);
    fused_gemm_kernel<false, false, true><<<GEMM_BLOCKS, 256, 0, stream>>>(
        tmp, Wjk + (size_t)128 * HID, nullptr, nullptr, nullptr, out, N_NODES);
}

// Round 5
// 499.324 us; speedup vs baseline: 1.3835x; 1.3835x over previous
//
#include <hip/hip_runtime.h>

#define N_NODES 100000
#define N_EDGES 1600000
#define HID 64
#define BN_EPS 1e-5f

#define GEMM_BLOCKS 1024     // 256 threads = 4 waves each
#define GATHER_BLOCKS 2048

// ---- multi-split CSR build parameters ----
#define NB 196                              // coarse buckets of 512 nodes (dst>>9)
#define MS_BLOCKS 128
#define MS_EPB (N_EDGES / MS_BLOCKS)        // 12500 edges per block
#define MS_CNT (NB * MS_BLOCKS)             // 25088 segment counters
#define GS_CHUNK 512
#define GS_BLOCKS ((MS_CNT + GS_CHUNK - 1) / GS_CHUNK)   // 49

__device__ __forceinline__ float bcastf(float v, int k) {
    return __int_as_float(__builtin_amdgcn_readlane(__float_as_int(v), k));
}

// ---------------- multi-split phase A: per-(block,bucket) histogram ----------------
__global__ __launch_bounds__(256) void msplit_hist_kernel(
        const int* __restrict__ dst, int* __restrict__ cnt) {
    __shared__ int h[NB];
    for (int i = threadIdx.x; i < NB; i += 256) h[i] = 0;
    __syncthreads();
    const int e0 = blockIdx.x * MS_EPB;
    for (int e = e0 + threadIdx.x; e < e0 + MS_EPB; e += 256)
        atomicAdd(&h[dst[e] >> 9], 1);
    __syncthreads();
    for (int i = threadIdx.x; i < NB; i += 256)
        cnt[i * MS_BLOCKS + blockIdx.x] = h[i];   // j-major: segments land bucket-contiguous
}

// ---------------- generic exclusive scan (3 kernels) ----------------
__global__ __launch_bounds__(256) void scan_partial_g(
        const int* __restrict__ in, int* __restrict__ out,
        int* __restrict__ bsums, int n) {
    __shared__ int sd[256];
    int t = threadIdx.x;
    int base = blockIdx.x * GS_CHUNK;
    int i0 = base + 2 * t, i1 = i0 + 1;
    int d0 = (i0 < n) ? in[i0] : 0;
    int d1 = (i1 < n) ? in[i1] : 0;
    sd[t] = d0 + d1;
    __syncthreads();
    for (int o = 1; o < 256; o <<= 1) {
        int v = (t >= o) ? sd[t - o] : 0;
        __syncthreads();
        sd[t] += v;
        __syncthreads();
    }
    int excl = sd[t] - (d0 + d1);
    if (i0 < n) out[i0] = excl;
    if (i1 < n) out[i1] = excl + d0;
    if (t == 255) bsums[blockIdx.x] = sd[255];
}

__global__ __launch_bounds__(256) void scan_bsums_kernel(int* __restrict__ bsums, int nb) {
    __shared__ int sd[256];
    int t = threadIdx.x;
    int v = (t < nb) ? bsums[t] : 0;
    sd[t] = v;
    __syncthreads();
    for (int o = 1; o < 256; o <<= 1) {
        int u = (t >= o) ? sd[t - o] : 0;
        __syncthreads();
        sd[t] += u;
        __syncthreads();
    }
    if (t < nb) bsums[t] = sd[t] - v;   // exclusive
}

__global__ __launch_bounds__(256) void scan_addback_g(
        int* __restrict__ out, const int* __restrict__ bsums, int n, int total) {
    int t = threadIdx.x;
    int b = bsums[blockIdx.x];
    int base = blockIdx.x * GS_CHUNK;
    int i0 = base + 2 * t, i1 = i0 + 1;
    if (i0 < n) out[i0] += b;
    if (i1 < n) out[i1] += b;
    if (blockIdx.x == 0 && t == 0) out[n] = total;   // sentinel
}

// ---------------- multi-split phase B: scatter into bucket-ordered edge array ----------------
__global__ __launch_bounds__(256) void msplit_scatter_kernel(
        const int* __restrict__ src, const int* __restrict__ dst,
        const int* __restrict__ psum, int2* __restrict__ bucketed) {
    __shared__ int cur[NB];
    for (int i = threadIdx.x; i < NB; i += 256)
        cur[i] = psum[i * MS_BLOCKS + blockIdx.x];
    __syncthreads();
    const int e0 = blockIdx.x * MS_EPB;
    for (int e = e0 + threadIdx.x; e < e0 + MS_EPB; e += 256) {
        int d = dst[e];
        int p = atomicAdd(&cur[d >> 9], 1);
        bucketed[p] = make_int2(src[e], d);
    }
}

// ---------------- per-bucket local CSR: off + eidx, all writes block-local ----------------
__global__ __launch_bounds__(256) void bucket_csr_kernel(
        const int2* __restrict__ bucketed, const int* __restrict__ psum,
        int* __restrict__ off, int* __restrict__ eidx) {
    const int j = blockIdx.x;
    const int t = threadIdx.x;
    __shared__ int deg[512];
    __shared__ int sd[256];
    __shared__ int base_s, size_s;
    if (t == 0) {
        int b = psum[j * MS_BLOCKS];
        int nxt = (j == NB - 1) ? N_EDGES : psum[(j + 1) * MS_BLOCKS];
        base_s = b; size_s = nxt - b;
    }
    deg[t] = 0; deg[t + 256] = 0;
    __syncthreads();
    const int base = base_s, size = size_s;
    const int nlo = j << 9;
    for (int i = t; i < size; i += 256)
        atomicAdd(&deg[bucketed[base + i].y - nlo], 1);
    __syncthreads();
    // exclusive scan over 512 local degrees
    int d0 = deg[2 * t], d1 = deg[2 * t + 1];
    sd[t] = d0 + d1;
    __syncthreads();
    for (int o = 1; o < 256; o <<= 1) {
        int v = (t >= o) ? sd[t - o] : 0;
        __syncthreads();
        sd[t] += v;
        __syncthreads();
    }
    int excl = sd[t] - (d0 + d1);
    int g0 = nlo + 2 * t, g1 = g0 + 1;
    if (g0 <= N_NODES) off[g0] = base + excl;
    if (g1 <= N_NODES) off[g1] = base + excl + d0;
    __syncthreads();          // everyone done reading deg before cursor re-init
    deg[2 * t] = excl;
    deg[2 * t + 1] = excl + d0;
    __syncthreads();
    for (int i = t; i < size; i += 256) {
        int2 e = bucketed[base + i];
        int p = atomicAdd(&deg[e.y - nlo], 1);
        eidx[base + p] = e.x;
    }
}

// ---------------- fused gather + GEMM1 + BN stats ----------------
__global__ __launch_bounds__(256) void gin_gather_gemm_kernel(
        const float* __restrict__ xin, const int* __restrict__ off,
        const int* __restrict__ eidx, const float* __restrict__ W,
        const float* __restrict__ bias, float* __restrict__ h,
        float* __restrict__ stats_partial) {
    const int lane = threadIdx.x & 63;
    const int w    = threadIdx.x >> 6;

    float wcol[64];
#pragma unroll
    for (int k = 0; k < 64; ++k) wcol[k] = W[k * HID + lane];
    const float bs = bias[lane];

    float ssum = 0.f, ssumsq = 0.f;
    const int gw = blockIdx.x * 4 + w;
    const int stride = gridDim.x * 4;
    for (int n = gw; n < N_NODES; n += stride) {
        float v = xin[(size_t)n * HID + lane];   // (1+eps)*x self term, eps=0
        int beg = off[n], end = off[n + 1];
        int j = beg;
        for (; j + 8 <= end; j += 8) {
            int s0 = eidx[j],     s1 = eidx[j + 1], s2 = eidx[j + 2], s3 = eidx[j + 3];
            int s4 = eidx[j + 4], s5 = eidx[j + 5], s6 = eidx[j + 6], s7 = eidx[j + 7];
            float v0 = xin[(size_t)s0 * HID + lane];
            float v1 = xin[(size_t)s1 * HID + lane];
            float v2 = xin[(size_t)s2 * HID + lane];
            float v3 = xin[(size_t)s3 * HID + lane];
            float v4 = xin[(size_t)s4 * HID + lane];
            float v5 = xin[(size_t)s5 * HID + lane];
            float v6 = xin[(size_t)s6 * HID + lane];
            float v7 = xin[(size_t)s7 * HID + lane];
            v += ((v0 + v1) + (v2 + v3)) + ((v4 + v5) + (v6 + v7));
        }
        if (j + 4 <= end) {
            int s0 = eidx[j], s1 = eidx[j + 1], s2 = eidx[j + 2], s3 = eidx[j + 3];
            float v0 = xin[(size_t)s0 * HID + lane];
            float v1 = xin[(size_t)s1 * HID + lane];
            float v2 = xin[(size_t)s2 * HID + lane];
            float v3 = xin[(size_t)s3 * HID + lane];
            v += (v0 + v1) + (v2 + v3);
            j += 4;
        }
        for (; j < end; ++j) v += xin[(size_t)eidx[j] * HID + lane];

        float acc = bs;
#pragma unroll
        for (int k = 0; k < 64; ++k)
            acc = fmaf(bcastf(v, k), wcol[k], acc);
        h[(size_t)n * HID + lane] = acc;
        ssum += acc; ssumsq += acc * acc;
    }

    __shared__ float red[2][256];
    red[0][threadIdx.x] = ssum;
    red[1][threadIdx.x] = ssumsq;
    __syncthreads();
    if (w == 0) {
        float s = red[0][lane] + red[0][64 + lane] + red[0][128 + lane] + red[0][192 + lane];
        float q = red[1][lane] + red[1][64 + lane] + red[1][128 + lane] + red[1][192 + lane];
        stats_partial[(size_t)blockIdx.x * 128 + lane]      = s;
        stats_partial[(size_t)blockIdx.x * 128 + 64 + lane] = q;
    }
}

// ---------------- fused row-GEMM ----------------
template<bool PRE_BN, bool POST_RELU, bool ACCUM>
__global__ __launch_bounds__(256) void fused_gemm_kernel(
        const float* __restrict__ in, const float* __restrict__ W,
        const float* __restrict__ bias, const float* __restrict__ scale,
        const float* __restrict__ shift, float* __restrict__ out, int nrows) {
    const int lane = threadIdx.x & 63;
    const int w    = threadIdx.x >> 6;

    float wcol[64];
#pragma unroll
    for (int k = 0; k < 64; ++k) wcol[k] = W[k * HID + lane];

    float sc = 0.f, sh = 0.f, bs = 0.f;
    if (PRE_BN) { sc = scale[lane]; sh = shift[lane]; }
    if (!ACCUM) bs = bias[lane];

    const int gw = blockIdx.x * 4 + w;
    const int stride = gridDim.x * 4;
    for (int r = gw; r < nrows; r += stride) {
        float v = in[(size_t)r * HID + lane];
        if (PRE_BN) v = fmaxf(fmaf(sc, v, sh), 0.f);
        float acc = ACCUM ? out[(size_t)r * HID + lane] : bs;
#pragma unroll
        for (int k = 0; k < 64; ++k)
            acc = fmaf(bcastf(v, k), wcol[k], acc);
        if (POST_RELU) acc = fmaxf(acc, 0.f);
        out[(size_t)r * HID + lane] = acc;
    }
}

// ---------------- BN finalize: parallel reduce of partials ----------------
__global__ __launch_bounds__(1024) void bn_finalize_kernel(
        const float* __restrict__ stats_partial, int nblocks,
        const float* __restrict__ gamma, const float* __restrict__ beta,
        float* __restrict__ scale, float* __restrict__ shift) {
    __shared__ float red[2][1024];
    const int t = threadIdx.x;
    const int c = t & 63;
    const int chunk = t >> 6;        // 0..15
    float s = 0.f, q = 0.f;
    for (int b = chunk; b < nblocks; b += 16) {
        s += stats_partial[(size_t)b * 128 + c];
        q += stats_partial[(size_t)b * 128 + 64 + c];
    }
    red[0][t] = s;
    red[1][t] = q;
    __syncthreads();
    if (chunk == 0) {
        float ss = 0.f, qq = 0.f;
#pragma unroll
        for (int k = 0; k < 16; ++k) {
            ss += red[0][k * 64 + c];
            qq += red[1][k * 64 + c];
        }
        float mean = ss / (float)N_NODES;
        float var  = qq / (float)N_NODES - mean * mean;
        float scl  = gamma[c] * rsqrtf(var + BN_EPS);
        scale[c] = scl;
        shift[c] = beta[c] - mean * scl;
    }
}

extern "C" void kernel_launch(void* const* d_in, const int* in_sizes, int n_in,
                              void* d_out, int out_size, void* d_ws, size_t ws_size,
                              hipStream_t stream) {
    const float* x    = (const float*)d_in[0];
    const int*   ei   = (const int*)d_in[1];
    const int*   src  = ei;
    const int*   dst  = ei + N_EDGES;
    const float* W1_0 = (const float*)d_in[3];
    const float* b1_0 = (const float*)d_in[4];
    const float* g_0  = (const float*)d_in[5];
    const float* be_0 = (const float*)d_in[6];
    const float* W2_0 = (const float*)d_in[7];
    const float* b2_0 = (const float*)d_in[8];
    const float* W1_1 = (const float*)d_in[9];
    const float* b1_1 = (const float*)d_in[10];
    const float* g_1  = (const float*)d_in[11];
    const float* be_1 = (const float*)d_in[12];
    const float* W2_1 = (const float*)d_in[13];
    const float* b2_1 = (const float*)d_in[14];
    const float* Wjk  = (const float*)d_in[15];
    const float* bjk  = (const float*)d_in[16];

    const size_t FEAT = (size_t)N_NODES * HID;

    float* tmp   = (float*)d_ws;                       // FEAT (pre-BN h, then h2 in-place)
    float* h1    = tmp + FEAT;                         // FEAT; aliased by `bucketed` during CSR build
    float* stats = h1 + FEAT;                          // GATHER_BLOCKS * 128
    float* scale = stats + (size_t)GATHER_BLOCKS * 128;
    float* shift = scale + 64;
    int*   off   = (int*)(shift + 64);                 // N_NODES + 1 (pad 2)
    int*   eidx  = off + N_NODES + 2;                  // N_EDGES
    int*   cnt   = eidx + N_EDGES;                     // MS_CNT
    int*   psum  = cnt + MS_CNT;                       // MS_CNT + 1 (pad 2)
    int*   bsums = psum + MS_CNT + 2;                  // 256
    int2*  bucketed = (int2*)h1;                       // 12.8 MB, only live during CSR build
    float* out   = (float*)d_out;

    // ---------------- CSR build via two-level multi-split ----------------
    msplit_hist_kernel<<<MS_BLOCKS, 256, 0, stream>>>(dst, cnt);
    scan_partial_g<<<GS_BLOCKS, 256, 0, stream>>>(cnt, psum, bsums, MS_CNT);
    scan_bsums_kernel<<<1, 256, 0, stream>>>(bsums, GS_BLOCKS);
    scan_addback_g<<<GS_BLOCKS, 256, 0, stream>>>(psum, bsums, MS_CNT, N_EDGES);
    msplit_scatter_kernel<<<MS_BLOCKS, 256, 0, stream>>>(src, dst, psum, bucketed);
    bucket_csr_kernel<<<NB, 256, 0, stream>>>(bucketed, psum, off, eidx);

    // ---------------- layer 0 ----------------
    gin_gather_gemm_kernel<<<GATHER_BLOCKS, 256, 0, stream>>>(
        x, off, eidx, W1_0, b1_0, tmp, stats);
    bn_finalize_kernel<<<1, 1024, 0, stream>>>(stats, GATHER_BLOCKS, g_0, be_0, scale, shift);
    fused_gemm_kernel<true, true, false><<<GEMM_BLOCKS, 256, 0, stream>>>(
        tmp, W2_0, b2_0, scale, shift, h1, N_NODES);

    // ---------------- layer 1 ----------------
    gin_gather_gemm_kernel<<<GATHER_BLOCKS, 256, 0, stream>>>(
        h1, off, eidx, W1_1, b1_1, tmp, stats);
    bn_finalize_kernel<<<1, 1024, 0, stream>>>(stats, GATHER_BLOCKS, g_1, be_1, scale, shift);
    fused_gemm_kernel<true, true, false><<<GEMM_BLOCKS, 256, 0, stream>>>(
        tmp, W2_1, b2_1, scale, shift, tmp, N_NODES);   // in-place: tmp becomes h2

    // ---------------- jump head: out = [x|h1|h2] @ Wjk + bjk ----------------
    fused_gemm_kernel<false, false, false><<<GEMM_BLOCKS, 256, 0, stream>>>(
        x, Wjk, bjk, nullptr, nullptr, out, N_NODES);
    fused_gemm_kernel<false, false, true><<<GEMM_BLOCKS, 256, 0, stream>>>(
        h1, Wjk + (size_t)64 * HID, nullptr, nullptr, nullptr, out, N_NODES);
    fused_gemm_kernel<false, false, true><<<GEMM_BLOCKS, 256, 0, stream>>>(
        tmp, Wjk + (size_t)128 * HID, nullptr, nullptr, nullptr, out, N_NODES);
}

// Round 6
// 483.292 us; speedup vs baseline: 1.4294x; 1.0332x over previous
//
#include <hip/hip_runtime.h>

#define N_NODES 100000
#define N_EDGES 1600000
#define HID 64
#define BN_EPS 1e-5f

#define GEMM_BLOCKS 1024     // 256 threads = 4 waves each
#define GATHER_BLOCKS 2048

// ---- multi-split CSR build parameters ----
#define NB 196                              // coarse buckets of 512 nodes (dst>>9)
#define MS_BLOCKS 128
#define MS_EPB (N_EDGES / MS_BLOCKS)        // 12500 edges per block
#define MS_CNT (NB * MS_BLOCKS)             // 25088 segment counters
#define GS_CHUNK 512
#define GS_BLOCKS ((MS_CNT + GS_CHUNK - 1) / GS_CHUNK)   // 49

__device__ __forceinline__ float bcastf(float v, int k) {
    return __int_as_float(__builtin_amdgcn_readlane(__float_as_int(v), k));
}
__device__ __forceinline__ float bf2f(unsigned short u) {
    return __uint_as_float(((unsigned)u) << 16);
}
__device__ __forceinline__ unsigned short f2bf_rne(float f) {
    unsigned u = __float_as_uint(f);
    u += 0x7FFFu + ((u >> 16) & 1u);
    return (unsigned short)(u >> 16);
}

// ---------------- fp32 -> bf16 conversion (8 elems/thread) ----------------
__global__ __launch_bounds__(256) void cvt_bf16_kernel(
        const float* __restrict__ in, unsigned short* __restrict__ out) {
    size_t i = ((size_t)blockIdx.x * 256 + threadIdx.x) * 8;
    if (i >= (size_t)N_NODES * HID) return;
    float4 a = *reinterpret_cast<const float4*>(in + i);
    float4 b = *reinterpret_cast<const float4*>(in + i + 4);
    ushort4 w0 = make_ushort4(f2bf_rne(a.x), f2bf_rne(a.y), f2bf_rne(a.z), f2bf_rne(a.w));
    ushort4 w1 = make_ushort4(f2bf_rne(b.x), f2bf_rne(b.y), f2bf_rne(b.z), f2bf_rne(b.w));
    *reinterpret_cast<ushort4*>(out + i) = w0;
    *reinterpret_cast<ushort4*>(out + i + 4) = w1;
}

// ---------------- multi-split phase A: per-(block,bucket) histogram ----------------
__global__ __launch_bounds__(256) void msplit_hist_kernel(
        const int* __restrict__ dst, int* __restrict__ cnt) {
    __shared__ int h[NB];
    for (int i = threadIdx.x; i < NB; i += 256) h[i] = 0;
    __syncthreads();
    const int e0 = blockIdx.x * MS_EPB;
    for (int e = e0 + threadIdx.x; e < e0 + MS_EPB; e += 256)
        atomicAdd(&h[dst[e] >> 9], 1);
    __syncthreads();
    for (int i = threadIdx.x; i < NB; i += 256)
        cnt[i * MS_BLOCKS + blockIdx.x] = h[i];   // j-major: segments land bucket-contiguous
}

// ---------------- generic exclusive scan (3 kernels) ----------------
__global__ __launch_bounds__(256) void scan_partial_g(
        const int* __restrict__ in, int* __restrict__ out,
        int* __restrict__ bsums, int n) {
    __shared__ int sd[256];
    int t = threadIdx.x;
    int base = blockIdx.x * GS_CHUNK;
    int i0 = base + 2 * t, i1 = i0 + 1;
    int d0 = (i0 < n) ? in[i0] : 0;
    int d1 = (i1 < n) ? in[i1] : 0;
    sd[t] = d0 + d1;
    __syncthreads();
    for (int o = 1; o < 256; o <<= 1) {
        int v = (t >= o) ? sd[t - o] : 0;
        __syncthreads();
        sd[t] += v;
        __syncthreads();
    }
    int excl = sd[t] - (d0 + d1);
    if (i0 < n) out[i0] = excl;
    if (i1 < n) out[i1] = excl + d0;
    if (t == 255) bsums[blockIdx.x] = sd[255];
}

__global__ __launch_bounds__(256) void scan_bsums_kernel(int* __restrict__ bsums, int nb) {
    __shared__ int sd[256];
    int t = threadIdx.x;
    int v = (t < nb) ? bsums[t] : 0;
    sd[t] = v;
    __syncthreads();
    for (int o = 1; o < 256; o <<= 1) {
        int u = (t >= o) ? sd[t - o] : 0;
        __syncthreads();
        sd[t] += u;
        __syncthreads();
    }
    if (t < nb) bsums[t] = sd[t] - v;   // exclusive
}

__global__ __launch_bounds__(256) void scan_addback_g(
        int* __restrict__ out, const int* __restrict__ bsums, int n, int total) {
    int t = threadIdx.x;
    int b = bsums[blockIdx.x];
    int base = blockIdx.x * GS_CHUNK;
    int i0 = base + 2 * t, i1 = i0 + 1;
    if (i0 < n) out[i0] += b;
    if (i1 < n) out[i1] += b;
    if (blockIdx.x == 0 && t == 0) out[n] = total;   // sentinel
}

// ---------------- multi-split phase B: scatter into bucket-ordered edge array ----------------
__global__ __launch_bounds__(256) void msplit_scatter_kernel(
        const int* __restrict__ src, const int* __restrict__ dst,
        const int* __restrict__ psum, int2* __restrict__ bucketed) {
    __shared__ int cur[NB];
    for (int i = threadIdx.x; i < NB; i += 256)
        cur[i] = psum[i * MS_BLOCKS + blockIdx.x];
    __syncthreads();
    const int e0 = blockIdx.x * MS_EPB;
    for (int e = e0 + threadIdx.x; e < e0 + MS_EPB; e += 256) {
        int d = dst[e];
        int p = atomicAdd(&cur[d >> 9], 1);
        bucketed[p] = make_int2(src[e], d);
    }
}

// ---------------- per-bucket local CSR: off + eidx, all writes block-local ----------------
__global__ __launch_bounds__(256) void bucket_csr_kernel(
        const int2* __restrict__ bucketed, const int* __restrict__ psum,
        int* __restrict__ off, int* __restrict__ eidx) {
    const int j = blockIdx.x;
    const int t = threadIdx.x;
    __shared__ int deg[512];
    __shared__ int sd[256];
    __shared__ int base_s, size_s;
    if (t == 0) {
        int b = psum[j * MS_BLOCKS];
        int nxt = (j == NB - 1) ? N_EDGES : psum[(j + 1) * MS_BLOCKS];
        base_s = b; size_s = nxt - b;
    }
    deg[t] = 0; deg[t + 256] = 0;
    __syncthreads();
    const int base = base_s, size = size_s;
    const int nlo = j << 9;
    for (int i = t; i < size; i += 256)
        atomicAdd(&deg[bucketed[base + i].y - nlo], 1);
    __syncthreads();
    // exclusive scan over 512 local degrees
    int d0 = deg[2 * t], d1 = deg[2 * t + 1];
    sd[t] = d0 + d1;
    __syncthreads();
    for (int o = 1; o < 256; o <<= 1) {
        int v = (t >= o) ? sd[t - o] : 0;
        __syncthreads();
        sd[t] += v;
        __syncthreads();
    }
    int excl = sd[t] - (d0 + d1);
    int g0 = nlo + 2 * t, g1 = g0 + 1;
    if (g0 <= N_NODES) off[g0] = base + excl;
    if (g1 <= N_NODES) off[g1] = base + excl + d0;
    __syncthreads();          // everyone done reading deg before cursor re-init
    deg[2 * t] = excl;
    deg[2 * t + 1] = excl + d0;
    __syncthreads();
    for (int i = t; i < size; i += 256) {
        int2 e = bucketed[base + i];
        int p = atomicAdd(&deg[e.y - nlo], 1);
        eidx[base + p] = e.x;
    }
}

// ---------------- fused gather(bf16 in) + GEMM1(fp32) + BN stats ----------------
__global__ __launch_bounds__(256) void gin_gather_gemm_kernel(
        const unsigned short* __restrict__ xb, const int* __restrict__ off,
        const int* __restrict__ eidx, const float* __restrict__ W,
        const float* __restrict__ bias, float* __restrict__ h,
        float* __restrict__ stats_partial) {
    const int lane = threadIdx.x & 63;
    const int w    = threadIdx.x >> 6;

    float wcol[64];
#pragma unroll
    for (int k = 0; k < 64; ++k) wcol[k] = W[k * HID + lane];
    const float bs = bias[lane];

    float ssum = 0.f, ssumsq = 0.f;
    const int gw = blockIdx.x * 4 + w;
    const int stride = gridDim.x * 4;
    for (int n = gw; n < N_NODES; n += stride) {
        float v = bf2f(xb[(size_t)n * HID + lane]);   // (1+eps)*x self term
        int beg = off[n], end = off[n + 1];
        int j = beg;
        for (; j + 8 <= end; j += 8) {
            int s0 = eidx[j],     s1 = eidx[j + 1], s2 = eidx[j + 2], s3 = eidx[j + 3];
            int s4 = eidx[j + 4], s5 = eidx[j + 5], s6 = eidx[j + 6], s7 = eidx[j + 7];
            float v0 = bf2f(xb[(size_t)s0 * HID + lane]);
            float v1 = bf2f(xb[(size_t)s1 * HID + lane]);
            float v2 = bf2f(xb[(size_t)s2 * HID + lane]);
            float v3 = bf2f(xb[(size_t)s3 * HID + lane]);
            float v4 = bf2f(xb[(size_t)s4 * HID + lane]);
            float v5 = bf2f(xb[(size_t)s5 * HID + lane]);
            float v6 = bf2f(xb[(size_t)s6 * HID + lane]);
            float v7 = bf2f(xb[(size_t)s7 * HID + lane]);
            v += ((v0 + v1) + (v2 + v3)) + ((v4 + v5) + (v6 + v7));
        }
        if (j + 4 <= end) {
            int s0 = eidx[j], s1 = eidx[j + 1], s2 = eidx[j + 2], s3 = eidx[j + 3];
            float v0 = bf2f(xb[(size_t)s0 * HID + lane]);
            float v1 = bf2f(xb[(size_t)s1 * HID + lane]);
            float v2 = bf2f(xb[(size_t)s2 * HID + lane]);
            float v3 = bf2f(xb[(size_t)s3 * HID + lane]);
            v += (v0 + v1) + (v2 + v3);
            j += 4;
        }
        for (; j < end; ++j) v += bf2f(xb[(size_t)eidx[j] * HID + lane]);

        float acc = bs;
#pragma unroll
        for (int k = 0; k < 64; ++k)
            acc = fmaf(bcastf(v, k), wcol[k], acc);
        h[(size_t)n * HID + lane] = acc;
        ssum += acc; ssumsq += acc * acc;
    }

    __shared__ float red[2][256];
    red[0][threadIdx.x] = ssum;
    red[1][threadIdx.x] = ssumsq;
    __syncthreads();
    if (w == 0) {
        float s = red[0][lane] + red[0][64 + lane] + red[0][128 + lane] + red[0][192 + lane];
        float q = red[1][lane] + red[1][64 + lane] + red[1][128 + lane] + red[1][192 + lane];
        stats_partial[(size_t)blockIdx.x * 128 + lane]      = s;
        stats_partial[(size_t)blockIdx.x * 128 + 64 + lane] = q;
    }
}

// ---------------- fused BN-apply + ReLU + GEMM2 + ReLU, bf16 out ----------------
__global__ __launch_bounds__(256) void fused_bn_gemm_kernel(
        const float* __restrict__ in, const float* __restrict__ W,
        const float* __restrict__ bias, const float* __restrict__ scale,
        const float* __restrict__ shift, unsigned short* __restrict__ out) {
    const int lane = threadIdx.x & 63;
    const int w    = threadIdx.x >> 6;

    float wcol[64];
#pragma unroll
    for (int k = 0; k < 64; ++k) wcol[k] = W[k * HID + lane];
    const float sc = scale[lane], sh = shift[lane], bs = bias[lane];

    const int gw = blockIdx.x * 4 + w;
    const int stride = gridDim.x * 4;
    for (int r = gw; r < N_NODES; r += stride) {
        float v = fmaxf(fmaf(sc, in[(size_t)r * HID + lane], sh), 0.f);
        float acc = bs;
#pragma unroll
        for (int k = 0; k < 64; ++k)
            acc = fmaf(bcastf(v, k), wcol[k], acc);
        out[(size_t)r * HID + lane] = f2bf_rne(fmaxf(acc, 0.f));
    }
}

// ---------------- fused jump head: out = [x|h1|h2] @ Wjk + bjk ----------------
__global__ __launch_bounds__(256) void jumphead_kernel(
        const unsigned short* __restrict__ xb, const unsigned short* __restrict__ h1b,
        const unsigned short* __restrict__ h2b, const float* __restrict__ Wjk,
        const float* __restrict__ bjk, float* __restrict__ out) {
    const int lane = threadIdx.x & 63;
    const int w    = threadIdx.x >> 6;

    float wa[64], wb[64], wc[64];
#pragma unroll
    for (int k = 0; k < 64; ++k) {
        wa[k] = Wjk[(size_t)k * HID + lane];
        wb[k] = Wjk[(size_t)(64 + k) * HID + lane];
        wc[k] = Wjk[(size_t)(128 + k) * HID + lane];
    }
    const float bs = bjk[lane];

    const int stride = gridDim.x * 4;
    int r = blockIdx.x * 4 + w;
    if (r >= N_NODES) return;
    unsigned short ua = xb[(size_t)r * HID + lane];
    unsigned short ub = h1b[(size_t)r * HID + lane];
    unsigned short uc = h2b[(size_t)r * HID + lane];
    while (r < N_NODES) {
        int rn = r + stride;
        unsigned short na = 0, nb = 0, nc = 0;
        if (rn < N_NODES) {                       // prefetch next row (hides latency)
            na = xb[(size_t)rn * HID + lane];
            nb = h1b[(size_t)rn * HID + lane];
            nc = h2b[(size_t)rn * HID + lane];
        }
        float va = bf2f(ua), vb = bf2f(ub), vc = bf2f(uc);
        float acc = bs;
#pragma unroll
        for (int k = 0; k < 64; ++k) acc = fmaf(bcastf(va, k), wa[k], acc);
#pragma unroll
        for (int k = 0; k < 64; ++k) acc = fmaf(bcastf(vb, k), wb[k], acc);
#pragma unroll
        for (int k = 0; k < 64; ++k) acc = fmaf(bcastf(vc, k), wc[k], acc);
        out[(size_t)r * HID + lane] = acc;
        ua = na; ub = nb; uc = nc;
        r = rn;
    }
}

// ---------------- BN finalize: parallel reduce of partials ----------------
__global__ __launch_bounds__(1024) void bn_finalize_kernel(
        const float* __restrict__ stats_partial, int nblocks,
        const float* __restrict__ gamma, const float* __restrict__ beta,
        float* __restrict__ scale, float* __restrict__ shift) {
    __shared__ float red[2][1024];
    const int t = threadIdx.x;
    const int c = t & 63;
    const int chunk = t >> 6;        // 0..15
    float s = 0.f, q = 0.f;
    for (int b = chunk; b < nblocks; b += 16) {
        s += stats_partial[(size_t)b * 128 + c];
        q += stats_partial[(size_t)b * 128 + 64 + c];
    }
    red[0][t] = s;
    red[1][t] = q;
    __syncthreads();
    if (chunk == 0) {
        float ss = 0.f, qq = 0.f;
#pragma unroll
        for (int k = 0; k < 16; ++k) {
            ss += red[0][k * 64 + c];
            qq += red[1][k * 64 + c];
        }
        float mean = ss / (float)N_NODES;
        float var  = qq / (float)N_NODES - mean * mean;
        float scl  = gamma[c] * rsqrtf(var + BN_EPS);
        scale[c] = scl;
        shift[c] = beta[c] - mean * scl;
    }
}

extern "C" void kernel_launch(void* const* d_in, const int* in_sizes, int n_in,
                              void* d_out, int out_size, void* d_ws, size_t ws_size,
                              hipStream_t stream) {
    const float* x    = (const float*)d_in[0];
    const int*   ei   = (const int*)d_in[1];
    const int*   src  = ei;
    const int*   dst  = ei + N_EDGES;
    const float* W1_0 = (const float*)d_in[3];
    const float* b1_0 = (const float*)d_in[4];
    const float* g_0  = (const float*)d_in[5];
    const float* be_0 = (const float*)d_in[6];
    const float* W2_0 = (const float*)d_in[7];
    const float* b2_0 = (const float*)d_in[8];
    const float* W1_1 = (const float*)d_in[9];
    const float* b1_1 = (const float*)d_in[10];
    const float* g_1  = (const float*)d_in[11];
    const float* be_1 = (const float*)d_in[12];
    const float* W2_1 = (const float*)d_in[13];
    const float* b2_1 = (const float*)d_in[14];
    const float* Wjk  = (const float*)d_in[15];
    const float* bjk  = (const float*)d_in[16];

    const size_t FEAT = (size_t)N_NODES * HID;

    float*          tmp  = (float*)d_ws;               // FEAT f32 (pre-BN h)
    unsigned short* xb   = (unsigned short*)(tmp + FEAT);  // FEAT bf16
    unsigned short* h1b  = xb + FEAT;                   // FEAT bf16
    unsigned short* h2b  = h1b + FEAT;                  // FEAT bf16; aliases `bucketed`
    float* stats = (float*)(h2b + FEAT);                // GATHER_BLOCKS * 128
    float* scale = stats + (size_t)GATHER_BLOCKS * 128;
    float* shift = scale + 64;
    int*   off   = (int*)(shift + 64);                  // N_NODES + 1 (pad 2)
    int*   eidx  = off + N_NODES + 2;                   // N_EDGES
    int*   cnt   = eidx + N_EDGES;                      // MS_CNT
    int*   psum  = cnt + MS_CNT;                        // MS_CNT + 1 (pad 2)
    int*   bsums = psum + MS_CNT + 2;                   // 256
    int2*  bucketed = (int2*)h2b;                       // 12.8 MB, dead before h2b written
    float* out   = (float*)d_out;

    // ---------------- x -> bf16 ----------------
    cvt_bf16_kernel<<<(int)(FEAT / 8 / 256), 256, 0, stream>>>(x, xb);

    // ---------------- CSR build via two-level multi-split ----------------
    msplit_hist_kernel<<<MS_BLOCKS, 256, 0, stream>>>(dst, cnt);
    scan_partial_g<<<GS_BLOCKS, 256, 0, stream>>>(cnt, psum, bsums, MS_CNT);
    scan_bsums_kernel<<<1, 256, 0, stream>>>(bsums, GS_BLOCKS);
    scan_addback_g<<<GS_BLOCKS, 256, 0, stream>>>(psum, bsums, MS_CNT, N_EDGES);
    msplit_scatter_kernel<<<MS_BLOCKS, 256, 0, stream>>>(src, dst, psum, bucketed);
    bucket_csr_kernel<<<NB, 256, 0, stream>>>(bucketed, psum, off, eidx);

    // ---------------- layer 0 ----------------
    gin_gather_gemm_kernel<<<GATHER_BLOCKS, 256, 0, stream>>>(
        xb, off, eidx, W1_0, b1_0, tmp, stats);
    bn_finalize_kernel<<<1, 1024, 0, stream>>>(stats, GATHER_BLOCKS, g_0, be_0, scale, shift);
    fused_bn_gemm_kernel<<<GEMM_BLOCKS, 256, 0, stream>>>(
        tmp, W2_0, b2_0, scale, shift, h1b);

    // ---------------- layer 1 ----------------
    gin_gather_gemm_kernel<<<GATHER_BLOCKS, 256, 0, stream>>>(
        h1b, off, eidx, W1_1, b1_1, tmp, stats);
    bn_finalize_kernel<<<1, 1024, 0, stream>>>(stats, GATHER_BLOCKS, g_1, be_1, scale, shift);
    fused_bn_gemm_kernel<<<GEMM_BLOCKS, 256, 0, stream>>>(
        tmp, W2_1, b2_1, scale, shift, h2b);

    // ---------------- fused jump head ----------------
    jumphead_kernel<<<GEMM_BLOCKS, 256, 0, stream>>>(xb, h1b, h2b, Wjk, bjk, out);
}

// Round 7
// 395.700 us; speedup vs baseline: 1.7458x; 1.2214x over previous
//
#include <hip/hip_runtime.h>

#define N_NODES 100000
#define N_EDGES 1600000
#define HID 64
#define BN_EPS 1e-5f

#define GATHER_BLOCKS 2048

// ---- MFMA tiling: 16-row tiles, one per wave ----
#define ROW_TILES ((N_NODES + 15) / 16)              // 6250
#define MFMA_BLOCKS ((ROW_TILES + 3) / 4)            // 1563

// ---- multi-split CSR build parameters ----
#define NB 196                              // coarse buckets of 512 nodes (dst>>9)
#define MS_BLOCKS 128
#define MS_EPB (N_EDGES / MS_BLOCKS)        // 12500 edges per block
#define MS_CNT (NB * MS_BLOCKS)             // 25088 segment counters
#define GS_CHUNK 512
#define GS_BLOCKS ((MS_CNT + GS_CHUNK - 1) / GS_CHUNK)   // 49

typedef __bf16 bf16x8 __attribute__((ext_vector_type(8)));
typedef float  f32x4  __attribute__((ext_vector_type(4)));

__device__ __forceinline__ float bcastf(float v, int k) {
    return __int_as_float(__builtin_amdgcn_readlane(__float_as_int(v), k));
}
__device__ __forceinline__ float bf2f(unsigned short u) {
    return __uint_as_float(((unsigned)u) << 16);
}
__device__ __forceinline__ unsigned short f2bf_rne(float f) {
    unsigned u = __float_as_uint(f);
    u += 0x7FFFu + ((u >> 16) & 1u);
    return (unsigned short)(u >> 16);
}

// ---------------- fp32 -> bf16 conversion (8 elems/thread) ----------------
__global__ __launch_bounds__(256) void cvt_bf16_kernel(
        const float* __restrict__ in, unsigned short* __restrict__ out) {
    size_t i = ((size_t)blockIdx.x * 256 + threadIdx.x) * 8;
    if (i >= (size_t)N_NODES * HID) return;
    float4 a = *reinterpret_cast<const float4*>(in + i);
    float4 b = *reinterpret_cast<const float4*>(in + i + 4);
    ushort4 w0 = make_ushort4(f2bf_rne(a.x), f2bf_rne(a.y), f2bf_rne(a.z), f2bf_rne(a.w));
    ushort4 w1 = make_ushort4(f2bf_rne(b.x), f2bf_rne(b.y), f2bf_rne(b.z), f2bf_rne(b.w));
    *reinterpret_cast<ushort4*>(out + i) = w0;
    *reinterpret_cast<ushort4*>(out + i + 4) = w1;
}

// ---------------- weight transpose+convert: Wt[c][k] = bf16(W[k][c]) ----------------
__global__ __launch_bounds__(256) void wtrans_kernel(
        const float* __restrict__ W, unsigned short* __restrict__ Wt, int K) {
    int i = blockIdx.x * 256 + threadIdx.x;
    if (i >= 64 * K) return;
    int c = i / K, k = i - c * K;
    Wt[i] = f2bf_rne(W[k * 64 + c]);
}

// ---------------- multi-split phase A: per-(block,bucket) histogram ----------------
__global__ __launch_bounds__(256) void msplit_hist_kernel(
        const int* __restrict__ dst, int* __restrict__ cnt) {
    __shared__ int h[NB];
    for (int i = threadIdx.x; i < NB; i += 256) h[i] = 0;
    __syncthreads();
    const int e0 = blockIdx.x * MS_EPB;
    for (int e = e0 + threadIdx.x; e < e0 + MS_EPB; e += 256)
        atomicAdd(&h[dst[e] >> 9], 1);
    __syncthreads();
    for (int i = threadIdx.x; i < NB; i += 256)
        cnt[i * MS_BLOCKS + blockIdx.x] = h[i];   // j-major: segments land bucket-contiguous
}

// ---------------- generic exclusive scan (3 kernels) ----------------
__global__ __launch_bounds__(256) void scan_partial_g(
        const int* __restrict__ in, int* __restrict__ out,
        int* __restrict__ bsums, int n) {
    __shared__ int sd[256];
    int t = threadIdx.x;
    int base = blockIdx.x * GS_CHUNK;
    int i0 = base + 2 * t, i1 = i0 + 1;
    int d0 = (i0 < n) ? in[i0] : 0;
    int d1 = (i1 < n) ? in[i1] : 0;
    sd[t] = d0 + d1;
    __syncthreads();
    for (int o = 1; o < 256; o <<= 1) {
        int v = (t >= o) ? sd[t - o] : 0;
        __syncthreads();
        sd[t] += v;
        __syncthreads();
    }
    int excl = sd[t] - (d0 + d1);
    if (i0 < n) out[i0] = excl;
    if (i1 < n) out[i1] = excl + d0;
    if (t == 255) bsums[blockIdx.x] = sd[255];
}

__global__ __launch_bounds__(256) void scan_bsums_kernel(int* __restrict__ bsums, int nb) {
    __shared__ int sd[256];
    int t = threadIdx.x;
    int v = (t < nb) ? bsums[t] : 0;
    sd[t] = v;
    __syncthreads();
    for (int o = 1; o < 256; o <<= 1) {
        int u = (t >= o) ? sd[t - o] : 0;
        __syncthreads();
        sd[t] += u;
        __syncthreads();
    }
    if (t < nb) bsums[t] = sd[t] - v;   // exclusive
}

__global__ __launch_bounds__(256) void scan_addback_g(
        int* __restrict__ out, const int* __restrict__ bsums, int n, int total) {
    int t = threadIdx.x;
    int b = bsums[blockIdx.x];
    int base = blockIdx.x * GS_CHUNK;
    int i0 = base + 2 * t, i1 = i0 + 1;
    if (i0 < n) out[i0] += b;
    if (i1 < n) out[i1] += b;
    if (blockIdx.x == 0 && t == 0) out[n] = total;   // sentinel
}

// ---------------- multi-split phase B: scatter into bucket-ordered edge array ----------------
__global__ __launch_bounds__(256) void msplit_scatter_kernel(
        const int* __restrict__ src, const int* __restrict__ dst,
        const int* __restrict__ psum, int2* __restrict__ bucketed) {
    __shared__ int cur[NB];
    for (int i = threadIdx.x; i < NB; i += 256)
        cur[i] = psum[i * MS_BLOCKS + blockIdx.x];
    __syncthreads();
    const int e0 = blockIdx.x * MS_EPB;
    for (int e = e0 + threadIdx.x; e < e0 + MS_EPB; e += 256) {
        int d = dst[e];
        int p = atomicAdd(&cur[d >> 9], 1);
        bucketed[p] = make_int2(src[e], d);
    }
}

// ---------------- per-bucket local CSR: off + eidx, all writes block-local ----------------
__global__ __launch_bounds__(256) void bucket_csr_kernel(
        const int2* __restrict__ bucketed, const int* __restrict__ psum,
        int* __restrict__ off, int* __restrict__ eidx) {
    const int j = blockIdx.x;
    const int t = threadIdx.x;
    __shared__ int deg[512];
    __shared__ int sd[256];
    __shared__ int base_s, size_s;
    if (t == 0) {
        int b = psum[j * MS_BLOCKS];
        int nxt = (j == NB - 1) ? N_EDGES : psum[(j + 1) * MS_BLOCKS];
        base_s = b; size_s = nxt - b;
    }
    deg[t] = 0; deg[t + 256] = 0;
    __syncthreads();
    const int base = base_s, size = size_s;
    const int nlo = j << 9;
    for (int i = t; i < size; i += 256)
        atomicAdd(&deg[bucketed[base + i].y - nlo], 1);
    __syncthreads();
    // exclusive scan over 512 local degrees
    int d0 = deg[2 * t], d1 = deg[2 * t + 1];
    sd[t] = d0 + d1;
    __syncthreads();
    for (int o = 1; o < 256; o <<= 1) {
        int v = (t >= o) ? sd[t - o] : 0;
        __syncthreads();
        sd[t] += v;
        __syncthreads();
    }
    int excl = sd[t] - (d0 + d1);
    int g0 = nlo + 2 * t, g1 = g0 + 1;
    if (g0 <= N_NODES) off[g0] = base + excl;
    if (g1 <= N_NODES) off[g1] = base + excl + d0;
    __syncthreads();          // everyone done reading deg before cursor re-init
    deg[2 * t] = excl;
    deg[2 * t + 1] = excl + d0;
    __syncthreads();
    for (int i = t; i < size; i += 256) {
        int2 e = bucketed[base + i];
        int p = atomicAdd(&deg[e.y - nlo], 1);
        eidx[base + p] = e.x;
    }
}

// ---------------- fused gather(bf16 in) + GEMM1(fp32) + BN stats ----------------
__global__ __launch_bounds__(256) void gin_gather_gemm_kernel(
        const unsigned short* __restrict__ xb, const int* __restrict__ off,
        const int* __restrict__ eidx, const float* __restrict__ W,
        const float* __restrict__ bias, float* __restrict__ h,
        float* __restrict__ stats_partial) {
    const int lane = threadIdx.x & 63;
    const int w    = threadIdx.x >> 6;

    float wcol[64];
#pragma unroll
    for (int k = 0; k < 64; ++k) wcol[k] = W[k * HID + lane];
    const float bs = bias[lane];

    float ssum = 0.f, ssumsq = 0.f;
    const int gw = blockIdx.x * 4 + w;
    const int stride = gridDim.x * 4;
    for (int n = gw; n < N_NODES; n += stride) {
        float v = bf2f(xb[(size_t)n * HID + lane]);   // (1+eps)*x self term
        int beg = off[n], end = off[n + 1];
        int j = beg;
        for (; j + 8 <= end; j += 8) {
            int s0 = eidx[j],     s1 = eidx[j + 1], s2 = eidx[j + 2], s3 = eidx[j + 3];
            int s4 = eidx[j + 4], s5 = eidx[j + 5], s6 = eidx[j + 6], s7 = eidx[j + 7];
            float v0 = bf2f(xb[(size_t)s0 * HID + lane]);
            float v1 = bf2f(xb[(size_t)s1 * HID + lane]);
            float v2 = bf2f(xb[(size_t)s2 * HID + lane]);
            float v3 = bf2f(xb[(size_t)s3 * HID + lane]);
            float v4 = bf2f(xb[(size_t)s4 * HID + lane]);
            float v5 = bf2f(xb[(size_t)s5 * HID + lane]);
            float v6 = bf2f(xb[(size_t)s6 * HID + lane]);
            float v7 = bf2f(xb[(size_t)s7 * HID + lane]);
            v += ((v0 + v1) + (v2 + v3)) + ((v4 + v5) + (v6 + v7));
        }
        if (j + 4 <= end) {
            int s0 = eidx[j], s1 = eidx[j + 1], s2 = eidx[j + 2], s3 = eidx[j + 3];
            float v0 = bf2f(xb[(size_t)s0 * HID + lane]);
            float v1 = bf2f(xb[(size_t)s1 * HID + lane]);
            float v2 = bf2f(xb[(size_t)s2 * HID + lane]);
            float v3 = bf2f(xb[(size_t)s3 * HID + lane]);
            v += (v0 + v1) + (v2 + v3);
            j += 4;
        }
        for (; j < end; ++j) v += bf2f(xb[(size_t)eidx[j] * HID + lane]);

        float acc = bs;
#pragma unroll
        for (int k = 0; k < 64; ++k)
            acc = fmaf(bcastf(v, k), wcol[k], acc);
        h[(size_t)n * HID + lane] = acc;
        ssum += acc; ssumsq += acc * acc;
    }

    __shared__ float red[2][256];
    red[0][threadIdx.x] = ssum;
    red[1][threadIdx.x] = ssumsq;
    __syncthreads();
    if (w == 0) {
        float s = red[0][lane] + red[0][64 + lane] + red[0][128 + lane] + red[0][192 + lane];
        float q = red[1][lane] + red[1][64 + lane] + red[1][128 + lane] + red[1][192 + lane];
        stats_partial[(size_t)blockIdx.x * 128 + lane]      = s;
        stats_partial[(size_t)blockIdx.x * 128 + 64 + lane] = q;
    }
}

// ---------------- MFMA: BN-apply + ReLU + GEMM2 + ReLU -> bf16 ----------------
// One 16-row tile per wave. A = relu(bn(tmp)) cast bf16; B = W2t[c][k] bf16.
__global__ __launch_bounds__(256) void bn_gemm_mfma_kernel(
        const float* __restrict__ tmp, const unsigned short* __restrict__ W2t,
        const float* __restrict__ bias, const float* __restrict__ scale,
        const float* __restrict__ shift, unsigned short* __restrict__ outb) {
    const int lane = threadIdx.x & 63;
    const int l15 = lane & 15, lhi = lane >> 4;
    const int tile = blockIdx.x * 4 + (threadIdx.x >> 6);
    if (tile >= ROW_TILES) return;
    const int r0 = tile * 16;

    // B fragments: 2 K-steps x 4 col-frags
    bf16x8 bfrag[2][4];
#pragma unroll
    for (int f = 0; f < 4; ++f) {
        const unsigned short* wp = W2t + (size_t)(f * 16 + l15) * 64 + lhi * 8;
#pragma unroll
        for (int t = 0; t < 2; ++t)
            bfrag[t][f] = *reinterpret_cast<const bf16x8*>(wp + t * 32);
    }
    // per-lane BN constants for its 8 k-slots per K-step
    float sc[2][8], sh[2][8];
#pragma unroll
    for (int t = 0; t < 2; ++t)
#pragma unroll
        for (int j = 0; j < 8; ++j) {
            int k = t * 32 + lhi * 8 + j;
            sc[t][j] = scale[k];
            sh[t][j] = shift[k];
        }

    f32x4 acc[4];
#pragma unroll
    for (int f = 0; f < 4; ++f) {
        float b = bias[f * 16 + l15];
        acc[f] = (f32x4){b, b, b, b};
    }

#pragma unroll
    for (int t = 0; t < 2; ++t) {
        const float* ap = tmp + (size_t)(r0 + l15) * 64 + t * 32 + lhi * 8;
        float4 v0 = *reinterpret_cast<const float4*>(ap);
        float4 v1 = *reinterpret_cast<const float4*>(ap + 4);
        bf16x8 a;
        a[0] = (__bf16)fmaxf(fmaf(sc[t][0], v0.x, sh[t][0]), 0.f);
        a[1] = (__bf16)fmaxf(fmaf(sc[t][1], v0.y, sh[t][1]), 0.f);
        a[2] = (__bf16)fmaxf(fmaf(sc[t][2], v0.z, sh[t][2]), 0.f);
        a[3] = (__bf16)fmaxf(fmaf(sc[t][3], v0.w, sh[t][3]), 0.f);
        a[4] = (__bf16)fmaxf(fmaf(sc[t][4], v1.x, sh[t][4]), 0.f);
        a[5] = (__bf16)fmaxf(fmaf(sc[t][5], v1.y, sh[t][5]), 0.f);
        a[6] = (__bf16)fmaxf(fmaf(sc[t][6], v1.z, sh[t][6]), 0.f);
        a[7] = (__bf16)fmaxf(fmaf(sc[t][7], v1.w, sh[t][7]), 0.f);
#pragma unroll
        for (int f = 0; f < 4; ++f)
            acc[f] = __builtin_amdgcn_mfma_f32_16x16x32_bf16(a, bfrag[t][f], acc[f], 0, 0, 0);
    }

#pragma unroll
    for (int f = 0; f < 4; ++f)
#pragma unroll
        for (int i = 0; i < 4; ++i)
            outb[(size_t)(r0 + lhi * 4 + i) * 64 + f * 16 + l15] =
                f2bf_rne(fmaxf(acc[f][i], 0.f));
}

// ---------------- MFMA jump head: out = [x|h1|h2] @ Wjk + bjk ----------------
// A rows are the bf16 concat (K=192 over three 64-wide sources); B = Wt[c][k].
__global__ __launch_bounds__(256) void jumphead_mfma_kernel(
        const unsigned short* __restrict__ xb, const unsigned short* __restrict__ h1b,
        const unsigned short* __restrict__ h2b, const unsigned short* __restrict__ Wt,
        const float* __restrict__ bjk, float* __restrict__ out) {
    const int lane = threadIdx.x & 63;
    const int l15 = lane & 15, lhi = lane >> 4;
    const int tile = blockIdx.x * 4 + (threadIdx.x >> 6);
    if (tile >= ROW_TILES) return;
    const int r0 = tile * 16;

    // B fragments: 6 K-steps x 4 col-frags (96 VGPRs)
    bf16x8 bfrag[6][4];
#pragma unroll
    for (int f = 0; f < 4; ++f) {
        const unsigned short* wp = Wt + (size_t)(f * 16 + l15) * 192 + lhi * 8;
#pragma unroll
        for (int t = 0; t < 6; ++t)
            bfrag[t][f] = *reinterpret_cast<const bf16x8*>(wp + t * 32);
    }

    const size_t arow = (size_t)(r0 + l15) * 64 + lhi * 8;
    bf16x8 a0 = *reinterpret_cast<const bf16x8*>(xb + arow);
    bf16x8 a1 = *reinterpret_cast<const bf16x8*>(xb + arow + 32);
    bf16x8 a2 = *reinterpret_cast<const bf16x8*>(h1b + arow);
    bf16x8 a3 = *reinterpret_cast<const bf16x8*>(h1b + arow + 32);
    bf16x8 a4 = *reinterpret_cast<const bf16x8*>(h2b + arow);
    bf16x8 a5 = *reinterpret_cast<const bf16x8*>(h2b + arow + 32);

    f32x4 acc[4];
#pragma unroll
    for (int f = 0; f < 4; ++f) {
        float b = bjk[f * 16 + l15];
        acc[f] = (f32x4){b, b, b, b};
    }
#pragma unroll
    for (int f = 0; f < 4; ++f) {
        acc[f] = __builtin_amdgcn_mfma_f32_16x16x32_bf16(a0, bfrag[0][f], acc[f], 0, 0, 0);
        acc[f] = __builtin_amdgcn_mfma_f32_16x16x32_bf16(a1, bfrag[1][f], acc[f], 0, 0, 0);
        acc[f] = __builtin_amdgcn_mfma_f32_16x16x32_bf16(a2, bfrag[2][f], acc[f], 0, 0, 0);
        acc[f] = __builtin_amdgcn_mfma_f32_16x16x32_bf16(a3, bfrag[3][f], acc[f], 0, 0, 0);
        acc[f] = __builtin_amdgcn_mfma_f32_16x16x32_bf16(a4, bfrag[4][f], acc[f], 0, 0, 0);
        acc[f] = __builtin_amdgcn_mfma_f32_16x16x32_bf16(a5, bfrag[5][f], acc[f], 0, 0, 0);
    }

#pragma unroll
    for (int f = 0; f < 4; ++f)
#pragma unroll
        for (int i = 0; i < 4; ++i)
            out[(size_t)(r0 + lhi * 4 + i) * 64 + f * 16 + l15] = acc[f][i];
}

// ---------------- BN finalize: parallel reduce of partials ----------------
__global__ __launch_bounds__(1024) void bn_finalize_kernel(
        const float* __restrict__ stats_partial, int nblocks,
        const float* __restrict__ gamma, const float* __restrict__ beta,
        float* __restrict__ scale, float* __restrict__ shift) {
    __shared__ float red[2][1024];
    const int t = threadIdx.x;
    const int c = t & 63;
    const int chunk = t >> 6;        // 0..15
    float s = 0.f, q = 0.f;
    for (int b = chunk; b < nblocks; b += 16) {
        s += stats_partial[(size_t)b * 128 + c];
        q += stats_partial[(size_t)b * 128 + 64 + c];
    }
    red[0][t] = s;
    red[1][t] = q;
    __syncthreads();
    if (chunk == 0) {
        float ss = 0.f, qq = 0.f;
#pragma unroll
        for (int k = 0; k < 16; ++k) {
            ss += red[0][k * 64 + c];
            qq += red[1][k * 64 + c];
        }
        float mean = ss / (float)N_NODES;
        float var  = qq / (float)N_NODES - mean * mean;
        float scl  = gamma[c] * rsqrtf(var + BN_EPS);
        scale[c] = scl;
        shift[c] = beta[c] - mean * scl;
    }
}

extern "C" void kernel_launch(void* const* d_in, const int* in_sizes, int n_in,
                              void* d_out, int out_size, void* d_ws, size_t ws_size,
                              hipStream_t stream) {
    const float* x    = (const float*)d_in[0];
    const int*   ei   = (const int*)d_in[1];
    const int*   src  = ei;
    const int*   dst  = ei + N_EDGES;
    const float* W1_0 = (const float*)d_in[3];
    const float* b1_0 = (const float*)d_in[4];
    const float* g_0  = (const float*)d_in[5];
    const float* be_0 = (const float*)d_in[6];
    const float* W2_0 = (const float*)d_in[7];
    const float* b2_0 = (const float*)d_in[8];
    const float* W1_1 = (const float*)d_in[9];
    const float* b1_1 = (const float*)d_in[10];
    const float* g_1  = (const float*)d_in[11];
    const float* be_1 = (const float*)d_in[12];
    const float* W2_1 = (const float*)d_in[13];
    const float* b2_1 = (const float*)d_in[14];
    const float* Wjk  = (const float*)d_in[15];
    const float* bjk  = (const float*)d_in[16];

    const size_t FEAT = (size_t)N_NODES * HID;

    float*          tmp  = (float*)d_ws;                   // FEAT f32 (pre-BN h)
    unsigned short* xb   = (unsigned short*)(tmp + FEAT);  // FEAT bf16
    unsigned short* h1b  = xb + FEAT;                      // FEAT bf16
    unsigned short* h2b  = h1b + FEAT;                     // FEAT bf16; aliases `bucketed`
    float* stats = (float*)(h2b + FEAT);                   // GATHER_BLOCKS * 128
    float* scale = stats + (size_t)GATHER_BLOCKS * 128;
    float* shift = scale + 64;
    int*   off   = (int*)(shift + 64);                     // N_NODES + 1 (pad 2)
    int*   eidx  = off + N_NODES + 2;                      // N_EDGES
    int*   cnt   = eidx + N_EDGES;                         // MS_CNT
    int*   psum  = cnt + MS_CNT;                           // MS_CNT + 1 (pad 2)
    int*   bsums = psum + MS_CNT + 2;                      // 256
    unsigned short* wjk_t = (unsigned short*)(bsums + 256);// 64*192
    unsigned short* w2t_0 = wjk_t + 64 * 192;              // 64*64
    unsigned short* w2t_1 = w2t_0 + 64 * 64;               // 64*64
    int2*  bucketed = (int2*)h2b;                          // 12.8 MB, dead before h2b written
    float* out   = (float*)d_out;

    // ---------------- x -> bf16; weight transposes ----------------
    cvt_bf16_kernel<<<(int)(FEAT / 8 / 256), 256, 0, stream>>>(x, xb);
    wtrans_kernel<<<(64 * 192 + 255) / 256, 256, 0, stream>>>(Wjk, wjk_t, 192);
    wtrans_kernel<<<(64 * 64 + 255) / 256, 256, 0, stream>>>(W2_0, w2t_0, 64);
    wtrans_kernel<<<(64 * 64 + 255) / 256, 256, 0, stream>>>(W2_1, w2t_1, 64);

    // ---------------- CSR build via two-level multi-split ----------------
    msplit_hist_kernel<<<MS_BLOCKS, 256, 0, stream>>>(dst, cnt);
    scan_partial_g<<<GS_BLOCKS, 256, 0, stream>>>(cnt, psum, bsums, MS_CNT);
    scan_bsums_kernel<<<1, 256, 0, stream>>>(bsums, GS_BLOCKS);
    scan_addback_g<<<GS_BLOCKS, 256, 0, stream>>>(psum, bsums, MS_CNT, N_EDGES);
    msplit_scatter_kernel<<<MS_BLOCKS, 256, 0, stream>>>(src, dst, psum, bucketed);
    bucket_csr_kernel<<<NB, 256, 0, stream>>>(bucketed, psum, off, eidx);

    // ---------------- layer 0 ----------------
    gin_gather_gemm_kernel<<<GATHER_BLOCKS, 256, 0, stream>>>(
        xb, off, eidx, W1_0, b1_0, tmp, stats);
    bn_finalize_kernel<<<1, 1024, 0, stream>>>(stats, GATHER_BLOCKS, g_0, be_0, scale, shift);
    bn_gemm_mfma_kernel<<<MFMA_BLOCKS, 256, 0, stream>>>(
        tmp, w2t_0, b2_0, scale, shift, h1b);

    // ---------------- layer 1 ----------------
    gin_gather_gemm_kernel<<<GATHER_BLOCKS, 256, 0, stream>>>(
        h1b, off, eidx, W1_1, b1_1, tmp, stats);
    bn_finalize_kernel<<<1, 1024, 0, stream>>>(stats, GATHER_BLOCKS, g_1, be_1, scale, shift);
    bn_gemm_mfma_kernel<<<MFMA_BLOCKS, 256, 0, stream>>>(
        tmp, w2t_1, b2_1, scale, shift, h2b);

    // ---------------- fused jump head (MFMA) ----------------
    jumphead_mfma_kernel<<<MFMA_BLOCKS, 256, 0, stream>>>(
        xb, h1b, h2b, wjk_t, bjk, out);
}

// Round 8
// 319.451 us; speedup vs baseline: 2.1625x; 1.2387x over previous
//
#include <hip/hip_runtime.h>

#define N_NODES 100000
#define N_EDGES 1600000
#define HID 64
#define BN_EPS 1e-5f

#define GATHER_BLOCKS 2048

// ---- MFMA tiling: 16-row tiles, one per wave ----
#define ROW_TILES ((N_NODES + 15) / 16)              // 6250
#define MFMA_BLOCKS ((ROW_TILES + 3) / 4)            // 1563

// ---- multi-split CSR build parameters ----
#define NB 196                              // coarse buckets of 512 nodes (dst>>9)
#define MS_BLOCKS 128
#define MS_EPB (N_EDGES / MS_BLOCKS)        // 12500 edges per block
#define MS_CNT (NB * MS_BLOCKS)             // 25088 segment counters
#define GS_CHUNK 512
#define GS_BLOCKS ((MS_CNT + GS_CHUNK - 1) / GS_CHUNK)   // 49

typedef __bf16 bf16x8 __attribute__((ext_vector_type(8)));
typedef float  f32x4  __attribute__((ext_vector_type(4)));

__device__ __forceinline__ float bf2f(unsigned short u) {
    return __uint_as_float(((unsigned)u) << 16);
}
__device__ __forceinline__ unsigned short f2bf_rne(float f) {
    unsigned u = __float_as_uint(f);
    u += 0x7FFFu + ((u >> 16) & 1u);
    return (unsigned short)(u >> 16);
}

// ---------------- fp32 -> bf16 conversion (8 elems/thread) ----------------
__global__ __launch_bounds__(256) void cvt_bf16_kernel(
        const float* __restrict__ in, unsigned short* __restrict__ out) {
    size_t i = ((size_t)blockIdx.x * 256 + threadIdx.x) * 8;
    if (i >= (size_t)N_NODES * HID) return;
    float4 a = *reinterpret_cast<const float4*>(in + i);
    float4 b = *reinterpret_cast<const float4*>(in + i + 4);
    ushort4 w0 = make_ushort4(f2bf_rne(a.x), f2bf_rne(a.y), f2bf_rne(a.z), f2bf_rne(a.w));
    ushort4 w1 = make_ushort4(f2bf_rne(b.x), f2bf_rne(b.y), f2bf_rne(b.z), f2bf_rne(b.w));
    *reinterpret_cast<ushort4*>(out + i) = w0;
    *reinterpret_cast<ushort4*>(out + i + 4) = w1;
}

// ---------------- weight transpose+convert: Wt[c][k] = bf16(W[k][c]) ----------------
__global__ __launch_bounds__(256) void wtrans_kernel(
        const float* __restrict__ W, unsigned short* __restrict__ Wt, int K) {
    int i = blockIdx.x * 256 + threadIdx.x;
    if (i >= 64 * K) return;
    int c = i / K, k = i - c * K;
    Wt[i] = f2bf_rne(W[k * 64 + c]);
}

// ---------------- multi-split phase A: per-(block,bucket) histogram ----------------
__global__ __launch_bounds__(256) void msplit_hist_kernel(
        const int* __restrict__ dst, int* __restrict__ cnt) {
    __shared__ int h[NB];
    for (int i = threadIdx.x; i < NB; i += 256) h[i] = 0;
    __syncthreads();
    const int e0 = blockIdx.x * MS_EPB;
    for (int e = e0 + threadIdx.x; e < e0 + MS_EPB; e += 256)
        atomicAdd(&h[dst[e] >> 9], 1);
    __syncthreads();
    for (int i = threadIdx.x; i < NB; i += 256)
        cnt[i * MS_BLOCKS + blockIdx.x] = h[i];   // j-major: segments land bucket-contiguous
}

// ---------------- generic exclusive scan (3 kernels) ----------------
__global__ __launch_bounds__(256) void scan_partial_g(
        const int* __restrict__ in, int* __restrict__ out,
        int* __restrict__ bsums, int n) {
    __shared__ int sd[256];
    int t = threadIdx.x;
    int base = blockIdx.x * GS_CHUNK;
    int i0 = base + 2 * t, i1 = i0 + 1;
    int d0 = (i0 < n) ? in[i0] : 0;
    int d1 = (i1 < n) ? in[i1] : 0;
    sd[t] = d0 + d1;
    __syncthreads();
    for (int o = 1; o < 256; o <<= 1) {
        int v = (t >= o) ? sd[t - o] : 0;
        __syncthreads();
        sd[t] += v;
        __syncthreads();
    }
    int excl = sd[t] - (d0 + d1);
    if (i0 < n) out[i0] = excl;
    if (i1 < n) out[i1] = excl + d0;
    if (t == 255) bsums[blockIdx.x] = sd[255];
}

__global__ __launch_bounds__(256) void scan_bsums_kernel(int* __restrict__ bsums, int nb) {
    __shared__ int sd[256];
    int t = threadIdx.x;
    int v = (t < nb) ? bsums[t] : 0;
    sd[t] = v;
    __syncthreads();
    for (int o = 1; o < 256; o <<= 1) {
        int u = (t >= o) ? sd[t - o] : 0;
        __syncthreads();
        sd[t] += u;
        __syncthreads();
    }
    if (t < nb) bsums[t] = sd[t] - v;   // exclusive
}

__global__ __launch_bounds__(256) void scan_addback_g(
        int* __restrict__ out, const int* __restrict__ bsums, int n, int total) {
    int t = threadIdx.x;
    int b = bsums[blockIdx.x];
    int base = blockIdx.x * GS_CHUNK;
    int i0 = base + 2 * t, i1 = i0 + 1;
    if (i0 < n) out[i0] += b;
    if (i1 < n) out[i1] += b;
    if (blockIdx.x == 0 && t == 0) out[n] = total;   // sentinel
}

// ---------------- multi-split phase B: scatter into bucket-ordered edge array ----------------
__global__ __launch_bounds__(256) void msplit_scatter_kernel(
        const int* __restrict__ src, const int* __restrict__ dst,
        const int* __restrict__ psum, int2* __restrict__ bucketed) {
    __shared__ int cur[NB];
    for (int i = threadIdx.x; i < NB; i += 256)
        cur[i] = psum[i * MS_BLOCKS + blockIdx.x];
    __syncthreads();
    const int e0 = blockIdx.x * MS_EPB;
    for (int e = e0 + threadIdx.x; e < e0 + MS_EPB; e += 256) {
        int d = dst[e];
        int p = atomicAdd(&cur[d >> 9], 1);
        bucketed[p] = make_int2(src[e], d);
    }
}

// ---------------- per-bucket local CSR: off + eidx, all writes block-local ----------------
__global__ __launch_bounds__(256) void bucket_csr_kernel(
        const int2* __restrict__ bucketed, const int* __restrict__ psum,
        int* __restrict__ off, int* __restrict__ eidx) {
    const int j = blockIdx.x;
    const int t = threadIdx.x;
    __shared__ int deg[512];
    __shared__ int sd[256];
    __shared__ int base_s, size_s;
    if (t == 0) {
        int b = psum[j * MS_BLOCKS];
        int nxt = (j == NB - 1) ? N_EDGES : psum[(j + 1) * MS_BLOCKS];
        base_s = b; size_s = nxt - b;
    }
    deg[t] = 0; deg[t + 256] = 0;
    __syncthreads();
    const int base = base_s, size = size_s;
    const int nlo = j << 9;
    for (int i = t; i < size; i += 256)
        atomicAdd(&deg[bucketed[base + i].y - nlo], 1);
    __syncthreads();
    // exclusive scan over 512 local degrees
    int d0 = deg[2 * t], d1 = deg[2 * t + 1];
    sd[t] = d0 + d1;
    __syncthreads();
    for (int o = 1; o < 256; o <<= 1) {
        int v = (t >= o) ? sd[t - o] : 0;
        __syncthreads();
        sd[t] += v;
        __syncthreads();
    }
    int excl = sd[t] - (d0 + d1);
    int g0 = nlo + 2 * t, g1 = g0 + 1;
    if (g0 <= N_NODES) off[g0] = base + excl;
    if (g1 <= N_NODES) off[g1] = base + excl + d0;
    __syncthreads();          // everyone done reading deg before cursor re-init
    deg[2 * t] = excl;
    deg[2 * t + 1] = excl + d0;
    __syncthreads();
    for (int i = t; i < size; i += 256) {
        int2 e = bucketed[base + i];
        int p = atomicAdd(&deg[e.y - nlo], 1);
        eidx[base + p] = e.x;
    }
}

// ---------------- pure gather: aggb[n] = xin[n] + sum_{j} xin[src_j] (bf16 io) ----------------
__global__ __launch_bounds__(256) void gather_kernel(
        const unsigned short* __restrict__ xb, const int* __restrict__ off,
        const int* __restrict__ eidx, unsigned short* __restrict__ aggb) {
    const int lane = threadIdx.x & 63;
    const int w    = threadIdx.x >> 6;
    const int gw = blockIdx.x * 4 + w;
    const int stride = gridDim.x * 4;
    for (int n = gw; n < N_NODES; n += stride) {
        float v = bf2f(xb[(size_t)n * HID + lane]);   // (1+eps)*x self term
        int beg = off[n], end = off[n + 1];
        int j = beg;
        for (; j + 8 <= end; j += 8) {
            int s0 = eidx[j],     s1 = eidx[j + 1], s2 = eidx[j + 2], s3 = eidx[j + 3];
            int s4 = eidx[j + 4], s5 = eidx[j + 5], s6 = eidx[j + 6], s7 = eidx[j + 7];
            float v0 = bf2f(xb[(size_t)s0 * HID + lane]);
            float v1 = bf2f(xb[(size_t)s1 * HID + lane]);
            float v2 = bf2f(xb[(size_t)s2 * HID + lane]);
            float v3 = bf2f(xb[(size_t)s3 * HID + lane]);
            float v4 = bf2f(xb[(size_t)s4 * HID + lane]);
            float v5 = bf2f(xb[(size_t)s5 * HID + lane]);
            float v6 = bf2f(xb[(size_t)s6 * HID + lane]);
            float v7 = bf2f(xb[(size_t)s7 * HID + lane]);
            v += ((v0 + v1) + (v2 + v3)) + ((v4 + v5) + (v6 + v7));
        }
        if (j + 4 <= end) {
            int s0 = eidx[j], s1 = eidx[j + 1], s2 = eidx[j + 2], s3 = eidx[j + 3];
            float v0 = bf2f(xb[(size_t)s0 * HID + lane]);
            float v1 = bf2f(xb[(size_t)s1 * HID + lane]);
            float v2 = bf2f(xb[(size_t)s2 * HID + lane]);
            float v3 = bf2f(xb[(size_t)s3 * HID + lane]);
            v += (v0 + v1) + (v2 + v3);
            j += 4;
        }
        for (; j < end; ++j) v += bf2f(xb[(size_t)eidx[j] * HID + lane]);
        aggb[(size_t)n * HID + lane] = f2bf_rne(v);
    }
}

// ---------------- MFMA GEMM1: hb = aggb @ W1 + b1 (bf16 out) + BN partials ----------------
__global__ __launch_bounds__(256) void gemm1_mfma_kernel(
        const unsigned short* __restrict__ aggb, const unsigned short* __restrict__ W1t,
        const float* __restrict__ bias, unsigned short* __restrict__ hb,
        float* __restrict__ stats_partial) {
    const int lane = threadIdx.x & 63;
    const int l15 = lane & 15, lhi = lane >> 4;
    const int tile = blockIdx.x * 4 + (threadIdx.x >> 6);
    const bool active = tile < ROW_TILES;
    const int r0 = tile * 16;

    f32x4 acc[4];
#pragma unroll
    for (int f = 0; f < 4; ++f) {
        float b = active ? bias[f * 16 + l15] : 0.f;
        acc[f] = (f32x4){b, b, b, b};
    }
    if (active) {
        bf16x8 bfrag[2][4];
#pragma unroll
        for (int f = 0; f < 4; ++f) {
            const unsigned short* wp = W1t + (size_t)(f * 16 + l15) * 64 + lhi * 8;
#pragma unroll
            for (int t = 0; t < 2; ++t)
                bfrag[t][f] = *reinterpret_cast<const bf16x8*>(wp + t * 32);
        }
        const size_t arow = (size_t)(r0 + l15) * 64 + lhi * 8;
        bf16x8 a0 = *reinterpret_cast<const bf16x8*>(aggb + arow);
        bf16x8 a1 = *reinterpret_cast<const bf16x8*>(aggb + arow + 32);
#pragma unroll
        for (int f = 0; f < 4; ++f) {
            acc[f] = __builtin_amdgcn_mfma_f32_16x16x32_bf16(a0, bfrag[0][f], acc[f], 0, 0, 0);
            acc[f] = __builtin_amdgcn_mfma_f32_16x16x32_bf16(a1, bfrag[1][f], acc[f], 0, 0, 0);
        }
#pragma unroll
        for (int f = 0; f < 4; ++f)
#pragma unroll
            for (int i = 0; i < 4; ++i)
                hb[(size_t)(r0 + lhi * 4 + i) * 64 + f * 16 + l15] = f2bf_rne(acc[f][i]);
    }

    // BN partial stats from f32 accumulators
    __shared__ float red[2][4][256];
#pragma unroll
    for (int f = 0; f < 4; ++f) {
        float s = 0.f, q = 0.f;
        if (active) {
#pragma unroll
            for (int i = 0; i < 4; ++i) { s += acc[f][i]; q += acc[f][i] * acc[f][i]; }
        }
        red[0][f][threadIdx.x] = s;
        red[1][f][threadIdx.x] = q;
    }
    __syncthreads();
    if (threadIdx.x < 64) {
        int c = threadIdx.x, f = c >> 4, p = c & 15;
        float s = 0.f, q = 0.f;
#pragma unroll
        for (int u = 0; u < 16; ++u) {             // u = wave*4 + lhi
            int t = (u >> 2) * 64 + (u & 3) * 16 + p;
            s += red[0][f][t];
            q += red[1][f][t];
        }
        stats_partial[(size_t)blockIdx.x * 128 + c]      = s;
        stats_partial[(size_t)blockIdx.x * 128 + 64 + c] = q;
    }
}

// ---------------- MFMA: BN-apply + ReLU + GEMM2 + ReLU -> bf16 (bf16 in) ----------------
__global__ __launch_bounds__(256) void bn_gemm_mfma_kernel(
        const unsigned short* __restrict__ hb, const unsigned short* __restrict__ W2t,
        const float* __restrict__ bias, const float* __restrict__ scale,
        const float* __restrict__ shift, unsigned short* __restrict__ outb) {
    const int lane = threadIdx.x & 63;
    const int l15 = lane & 15, lhi = lane >> 4;
    const int tile = blockIdx.x * 4 + (threadIdx.x >> 6);
    if (tile >= ROW_TILES) return;
    const int r0 = tile * 16;

    bf16x8 bfrag[2][4];
#pragma unroll
    for (int f = 0; f < 4; ++f) {
        const unsigned short* wp = W2t + (size_t)(f * 16 + l15) * 64 + lhi * 8;
#pragma unroll
        for (int t = 0; t < 2; ++t)
            bfrag[t][f] = *reinterpret_cast<const bf16x8*>(wp + t * 32);
    }
    float sc[2][8], sh[2][8];
#pragma unroll
    for (int t = 0; t < 2; ++t)
#pragma unroll
        for (int j = 0; j < 8; ++j) {
            int k = t * 32 + lhi * 8 + j;
            sc[t][j] = scale[k];
            sh[t][j] = shift[k];
        }

    f32x4 acc[4];
#pragma unroll
    for (int f = 0; f < 4; ++f) {
        float b = bias[f * 16 + l15];
        acc[f] = (f32x4){b, b, b, b};
    }

#pragma unroll
    for (int t = 0; t < 2; ++t) {
        const unsigned short* hp = hb + (size_t)(r0 + l15) * 64 + t * 32 + lhi * 8;
        bf16x8 raw = *reinterpret_cast<const bf16x8*>(hp);
        bf16x8 a;
#pragma unroll
        for (int j = 0; j < 8; ++j)
            a[j] = (__bf16)fmaxf(fmaf(sc[t][j], (float)raw[j], sh[t][j]), 0.f);
#pragma unroll
        for (int f = 0; f < 4; ++f)
            acc[f] = __builtin_amdgcn_mfma_f32_16x16x32_bf16(a, bfrag[t][f], acc[f], 0, 0, 0);
    }

#pragma unroll
    for (int f = 0; f < 4; ++f)
#pragma unroll
        for (int i = 0; i < 4; ++i)
            outb[(size_t)(r0 + lhi * 4 + i) * 64 + f * 16 + l15] =
                f2bf_rne(fmaxf(acc[f][i], 0.f));
}

// ---------------- MFMA jump head: out = [x|h1|h2] @ Wjk + bjk ----------------
__global__ __launch_bounds__(256) void jumphead_mfma_kernel(
        const unsigned short* __restrict__ xb, const unsigned short* __restrict__ h1b,
        const unsigned short* __restrict__ h2b, const unsigned short* __restrict__ Wt,
        const float* __restrict__ bjk, float* __restrict__ out) {
    const int lane = threadIdx.x & 63;
    const int l15 = lane & 15, lhi = lane >> 4;
    const int tile = blockIdx.x * 4 + (threadIdx.x >> 6);
    if (tile >= ROW_TILES) return;
    const int r0 = tile * 16;

    bf16x8 bfrag[6][4];
#pragma unroll
    for (int f = 0; f < 4; ++f) {
        const unsigned short* wp = Wt + (size_t)(f * 16 + l15) * 192 + lhi * 8;
#pragma unroll
        for (int t = 0; t < 6; ++t)
            bfrag[t][f] = *reinterpret_cast<const bf16x8*>(wp + t * 32);
    }

    const size_t arow = (size_t)(r0 + l15) * 64 + lhi * 8;
    bf16x8 a0 = *reinterpret_cast<const bf16x8*>(xb + arow);
    bf16x8 a1 = *reinterpret_cast<const bf16x8*>(xb + arow + 32);
    bf16x8 a2 = *reinterpret_cast<const bf16x8*>(h1b + arow);
    bf16x8 a3 = *reinterpret_cast<const bf16x8*>(h1b + arow + 32);
    bf16x8 a4 = *reinterpret_cast<const bf16x8*>(h2b + arow);
    bf16x8 a5 = *reinterpret_cast<const bf16x8*>(h2b + arow + 32);

    f32x4 acc[4];
#pragma unroll
    for (int f = 0; f < 4; ++f) {
        float b = bjk[f * 16 + l15];
        acc[f] = (f32x4){b, b, b, b};
    }
#pragma unroll
    for (int f = 0; f < 4; ++f) {
        acc[f] = __builtin_amdgcn_mfma_f32_16x16x32_bf16(a0, bfrag[0][f], acc[f], 0, 0, 0);
        acc[f] = __builtin_amdgcn_mfma_f32_16x16x32_bf16(a1, bfrag[1][f], acc[f], 0, 0, 0);
        acc[f] = __builtin_amdgcn_mfma_f32_16x16x32_bf16(a2, bfrag[2][f], acc[f], 0, 0, 0);
        acc[f] = __builtin_amdgcn_mfma_f32_16x16x32_bf16(a3, bfrag[3][f], acc[f], 0, 0, 0);
        acc[f] = __builtin_amdgcn_mfma_f32_16x16x32_bf16(a4, bfrag[4][f], acc[f], 0, 0, 0);
        acc[f] = __builtin_amdgcn_mfma_f32_16x16x32_bf16(a5, bfrag[5][f], acc[f], 0, 0, 0);
    }

#pragma unroll
    for (int f = 0; f < 4; ++f)
#pragma unroll
        for (int i = 0; i < 4; ++i)
            out[(size_t)(r0 + lhi * 4 + i) * 64 + f * 16 + l15] = acc[f][i];
}

// ---------------- BN finalize: parallel reduce of partials ----------------
__global__ __launch_bounds__(1024) void bn_finalize_kernel(
        const float* __restrict__ stats_partial, int nblocks,
        const float* __restrict__ gamma, const float* __restrict__ beta,
        float* __restrict__ scale, float* __restrict__ shift) {
    __shared__ float red[2][1024];
    const int t = threadIdx.x;
    const int c = t & 63;
    const int chunk = t >> 6;        // 0..15
    float s = 0.f, q = 0.f;
    for (int b = chunk; b < nblocks; b += 16) {
        s += stats_partial[(size_t)b * 128 + c];
        q += stats_partial[(size_t)b * 128 + 64 + c];
    }
    red[0][t] = s;
    red[1][t] = q;
    __syncthreads();
    if (chunk == 0) {
        float ss = 0.f, qq = 0.f;
#pragma unroll
        for (int k = 0; k < 16; ++k) {
            ss += red[0][k * 64 + c];
            qq += red[1][k * 64 + c];
        }
        float mean = ss / (float)N_NODES;
        float var  = qq / (float)N_NODES - mean * mean;
        float scl  = gamma[c] * rsqrtf(var + BN_EPS);
        scale[c] = scl;
        shift[c] = beta[c] - mean * scl;
    }
}

extern "C" void kernel_launch(void* const* d_in, const int* in_sizes, int n_in,
                              void* d_out, int out_size, void* d_ws, size_t ws_size,
                              hipStream_t stream) {
    const float* x    = (const float*)d_in[0];
    const int*   ei   = (const int*)d_in[1];
    const int*   src  = ei;
    const int*   dst  = ei + N_EDGES;
    const float* W1_0 = (const float*)d_in[3];
    const float* b1_0 = (const float*)d_in[4];
    const float* g_0  = (const float*)d_in[5];
    const float* be_0 = (const float*)d_in[6];
    const float* W2_0 = (const float*)d_in[7];
    const float* b2_0 = (const float*)d_in[8];
    const float* W1_1 = (const float*)d_in[9];
    const float* b1_1 = (const float*)d_in[10];
    const float* g_1  = (const float*)d_in[11];
    const float* be_1 = (const float*)d_in[12];
    const float* W2_1 = (const float*)d_in[13];
    const float* b2_1 = (const float*)d_in[14];
    const float* Wjk  = (const float*)d_in[15];
    const float* bjk  = (const float*)d_in[16];

    const size_t FEAT = (size_t)N_NODES * HID;

    unsigned short* aggb = (unsigned short*)d_ws;          // FEAT bf16
    unsigned short* hb   = aggb + FEAT;                    // FEAT bf16
    unsigned short* xb   = hb + FEAT;                      // FEAT bf16
    unsigned short* h1b  = xb + FEAT;                      // FEAT bf16
    unsigned short* h2b  = h1b + FEAT;                     // FEAT bf16; aliases `bucketed`
    float* stats = (float*)(h2b + FEAT);                   // MFMA_BLOCKS * 128
    float* scale = stats + (size_t)MFMA_BLOCKS * 128;
    float* shift = scale + 64;
    int*   off   = (int*)(shift + 64);                     // N_NODES + 1 (pad 2)
    int*   eidx  = off + N_NODES + 2;                      // N_EDGES
    int*   cnt   = eidx + N_EDGES;                         // MS_CNT
    int*   psum  = cnt + MS_CNT;                           // MS_CNT + 1 (pad 2)
    int*   bsums = psum + MS_CNT + 2;                      // 256
    unsigned short* wjk_t = (unsigned short*)(bsums + 256);// 64*192
    unsigned short* w2t_0 = wjk_t + 64 * 192;              // 64*64
    unsigned short* w2t_1 = w2t_0 + 64 * 64;               // 64*64
    unsigned short* w1t_0 = w2t_1 + 64 * 64;               // 64*64
    unsigned short* w1t_1 = w1t_0 + 64 * 64;               // 64*64
    int2*  bucketed = (int2*)h2b;                          // 12.8 MB, dead before h2b written
    float* out   = (float*)d_out;

    // ---------------- x -> bf16; weight transposes ----------------
    cvt_bf16_kernel<<<(int)(FEAT / 8 / 256), 256, 0, stream>>>(x, xb);
    wtrans_kernel<<<(64 * 192 + 255) / 256, 256, 0, stream>>>(Wjk, wjk_t, 192);
    wtrans_kernel<<<(64 * 64 + 255) / 256, 256, 0, stream>>>(W2_0, w2t_0, 64);
    wtrans_kernel<<<(64 * 64 + 255) / 256, 256, 0, stream>>>(W2_1, w2t_1, 64);
    wtrans_kernel<<<(64 * 64 + 255) / 256, 256, 0, stream>>>(W1_0, w1t_0, 64);
    wtrans_kernel<<<(64 * 64 + 255) / 256, 256, 0, stream>>>(W1_1, w1t_1, 64);

    // ---------------- CSR build via two-level multi-split ----------------
    msplit_hist_kernel<<<MS_BLOCKS, 256, 0, stream>>>(dst, cnt);
    scan_partial_g<<<GS_BLOCKS, 256, 0, stream>>>(cnt, psum, bsums, MS_CNT);
    scan_bsums_kernel<<<1, 256, 0, stream>>>(bsums, GS_BLOCKS);
    scan_addback_g<<<GS_BLOCKS, 256, 0, stream>>>(psum, bsums, MS_CNT, N_EDGES);
    msplit_scatter_kernel<<<MS_BLOCKS, 256, 0, stream>>>(src, dst, psum, bucketed);
    bucket_csr_kernel<<<NB, 256, 0, stream>>>(bucketed, psum, off, eidx);

    // ---------------- layer 0 ----------------
    gather_kernel<<<GATHER_BLOCKS, 256, 0, stream>>>(xb, off, eidx, aggb);
    gemm1_mfma_kernel<<<MFMA_BLOCKS, 256, 0, stream>>>(aggb, w1t_0, b1_0, hb, stats);
    bn_finalize_kernel<<<1, 1024, 0, stream>>>(stats, MFMA_BLOCKS, g_0, be_0, scale, shift);
    bn_gemm_mfma_kernel<<<MFMA_BLOCKS, 256, 0, stream>>>(hb, w2t_0, b2_0, scale, shift, h1b);

    // ---------------- layer 1 ----------------
    gather_kernel<<<GATHER_BLOCKS, 256, 0, stream>>>(h1b, off, eidx, aggb);
    gemm1_mfma_kernel<<<MFMA_BLOCKS, 256, 0, stream>>>(aggb, w1t_1, b1_1, hb, stats);
    bn_finalize_kernel<<<1, 1024, 0, stream>>>(stats, MFMA_BLOCKS, g_1, be_1, scale, shift);
    bn_gemm_mfma_kernel<<<MFMA_BLOCKS, 256, 0, stream>>>(hb, w2t_1, b2_1, scale, shift, h2b);

    // ---------------- fused jump head (MFMA) ----------------
    jumphead_mfma_kernel<<<MFMA_BLOCKS, 256, 0, stream>>>(
        xb, h1b, h2b, wjk_t, bjk, out);
}

// Round 9
// 244.532 us; speedup vs baseline: 2.8250x; 1.3064x over previous
//
#include <hip/hip_runtime.h>

#define N_NODES 100000
#define N_EDGES 1600000
#define HID 64
#define BN_EPS 1e-5f

#define GATHER_BLOCKS 2048

// ---- MFMA tiling: 16-row tiles ----
#define ROW_TILES (N_NODES / 16)                     // 6250 (exact)
#define TPW1 4                                       // tiles/wave, gemm1
#define G1_BLOCKS ((ROW_TILES + 4*TPW1 - 1) / (4*TPW1))   // 391
#define TPW2 2                                       // tiles/wave, bn_gemm & jumphead
#define G2_BLOCKS ((ROW_TILES + 4*TPW2 - 1) / (4*TPW2))   // 782

// ---- multi-split CSR build parameters ----
#define NB 196                              // coarse buckets of 512 nodes (dst>>9)
#define MS_BLOCKS 128
#define MS_EPB (N_EDGES / MS_BLOCKS)        // 12500 edges per block
#define MS_CNT (NB * MS_BLOCKS)             // 25088 segment counters
#define GS_CHUNK 512
#define GS_BLOCKS ((MS_CNT + GS_CHUNK - 1) / GS_CHUNK)   // 49

typedef __bf16 bf16x8 __attribute__((ext_vector_type(8)));
typedef float  f32x4  __attribute__((ext_vector_type(4)));
typedef unsigned short u16x8 __attribute__((ext_vector_type(8)));

__device__ __forceinline__ float bf2f(unsigned short u) {
    return __uint_as_float(((unsigned)u) << 16);
}
__device__ __forceinline__ unsigned short f2bf_rne(float f) {
    unsigned u = __float_as_uint(f);
    u += 0x7FFFu + ((u >> 16) & 1u);
    return (unsigned short)(u >> 16);
}

// ---------------- fp32 -> bf16 conversion (8 elems/thread) ----------------
__global__ __launch_bounds__(256) void cvt_bf16_kernel(
        const float* __restrict__ in, unsigned short* __restrict__ out) {
    size_t i = ((size_t)blockIdx.x * 256 + threadIdx.x) * 8;
    if (i >= (size_t)N_NODES * HID) return;
    float4 a = *reinterpret_cast<const float4*>(in + i);
    float4 b = *reinterpret_cast<const float4*>(in + i + 4);
    ushort4 w0 = make_ushort4(f2bf_rne(a.x), f2bf_rne(a.y), f2bf_rne(a.z), f2bf_rne(a.w));
    ushort4 w1 = make_ushort4(f2bf_rne(b.x), f2bf_rne(b.y), f2bf_rne(b.z), f2bf_rne(b.w));
    *reinterpret_cast<ushort4*>(out + i) = w0;
    *reinterpret_cast<ushort4*>(out + i + 4) = w1;
}

// ---------------- all weight transposes in one launch ----------------
// Wt[c][k] = bf16(W[k][c]); ranges: [0,12288)=Wjk(K=192), then 4x4096 (K=64).
__global__ __launch_bounds__(256) void wtrans_all_kernel(
        const float* __restrict__ Wjk,
        const float* __restrict__ W1_0, const float* __restrict__ W2_0,
        const float* __restrict__ W1_1, const float* __restrict__ W2_1,
        unsigned short* __restrict__ wjk_t,
        unsigned short* __restrict__ w1t_0, unsigned short* __restrict__ w2t_0,
        unsigned short* __restrict__ w1t_1, unsigned short* __restrict__ w2t_1) {
    int i = blockIdx.x * 256 + threadIdx.x;
    if (i < 12288) {
        int c = i / 192, k = i - c * 192;
        wjk_t[i] = f2bf_rne(Wjk[k * 64 + c]);
    } else if (i < 12288 + 16384) {
        int r = i - 12288;
        int which = r >> 12, rem = r & 4095;
        int c = rem >> 6, k = rem & 63;
        const float* W = (which == 0) ? W1_0 : (which == 1) ? W2_0
                       : (which == 2) ? W1_1 : W2_1;
        unsigned short* Wt = (which == 0) ? w1t_0 : (which == 1) ? w2t_0
                           : (which == 2) ? w1t_1 : w2t_1;
        Wt[rem] = f2bf_rne(W[k * 64 + c]);
    }
}

// ---------------- multi-split phase A: per-(block,bucket) histogram ----------------
__global__ __launch_bounds__(256) void msplit_hist_kernel(
        const int* __restrict__ dst, int* __restrict__ cnt) {
    __shared__ int h[NB];
    for (int i = threadIdx.x; i < NB; i += 256) h[i] = 0;
    __syncthreads();
    const int e0 = blockIdx.x * MS_EPB;
    for (int e = e0 + threadIdx.x; e < e0 + MS_EPB; e += 256)
        atomicAdd(&h[dst[e] >> 9], 1);
    __syncthreads();
    for (int i = threadIdx.x; i < NB; i += 256)
        cnt[i * MS_BLOCKS + blockIdx.x] = h[i];   // j-major: segments land bucket-contiguous
}

// ---------------- generic exclusive scan (3 kernels) ----------------
__global__ __launch_bounds__(256) void scan_partial_g(
        const int* __restrict__ in, int* __restrict__ out,
        int* __restrict__ bsums, int n) {
    __shared__ int sd[256];
    int t = threadIdx.x;
    int base = blockIdx.x * GS_CHUNK;
    int i0 = base + 2 * t, i1 = i0 + 1;
    int d0 = (i0 < n) ? in[i0] : 0;
    int d1 = (i1 < n) ? in[i1] : 0;
    sd[t] = d0 + d1;
    __syncthreads();
    for (int o = 1; o < 256; o <<= 1) {
        int v = (t >= o) ? sd[t - o] : 0;
        __syncthreads();
        sd[t] += v;
        __syncthreads();
    }
    int excl = sd[t] - (d0 + d1);
    if (i0 < n) out[i0] = excl;
    if (i1 < n) out[i1] = excl + d0;
    if (t == 255) bsums[blockIdx.x] = sd[255];
}

__global__ __launch_bounds__(256) void scan_bsums_kernel(int* __restrict__ bsums, int nb) {
    __shared__ int sd[256];
    int t = threadIdx.x;
    int v = (t < nb) ? bsums[t] : 0;
    sd[t] = v;
    __syncthreads();
    for (int o = 1; o < 256; o <<= 1) {
        int u = (t >= o) ? sd[t - o] : 0;
        __syncthreads();
        sd[t] += u;
        __syncthreads();
    }
    if (t < nb) bsums[t] = sd[t] - v;   // exclusive
}

__global__ __launch_bounds__(256) void scan_addback_g(
        int* __restrict__ out, const int* __restrict__ bsums, int n, int total) {
    int t = threadIdx.x;
    int b = bsums[blockIdx.x];
    int base = blockIdx.x * GS_CHUNK;
    int i0 = base + 2 * t, i1 = i0 + 1;
    if (i0 < n) out[i0] += b;
    if (i1 < n) out[i1] += b;
    if (blockIdx.x == 0 && t == 0) out[n] = total;   // sentinel
}

// ---------------- multi-split phase B: scatter packed (src<<9|dlocal) ----------------
__global__ __launch_bounds__(256) void msplit_scatter_kernel(
        const int* __restrict__ src, const int* __restrict__ dst,
        const int* __restrict__ psum, int* __restrict__ bucketed) {
    __shared__ int cur[NB];
    for (int i = threadIdx.x; i < NB; i += 256)
        cur[i] = psum[i * MS_BLOCKS + blockIdx.x];
    __syncthreads();
    const int e0 = blockIdx.x * MS_EPB;
    for (int e = e0 + threadIdx.x; e < e0 + MS_EPB; e += 256) {
        int d = dst[e];
        int p = atomicAdd(&cur[d >> 9], 1);
        bucketed[p] = (src[e] << 9) | (d & 511);
    }
}

// ---------------- per-bucket local CSR: off + eidx, all writes block-local ----------------
__global__ __launch_bounds__(256) void bucket_csr_kernel(
        const int* __restrict__ bucketed, const int* __restrict__ psum,
        int* __restrict__ off, int* __restrict__ eidx) {
    const int j = blockIdx.x;
    const int t = threadIdx.x;
    __shared__ int deg[512];
    __shared__ int sd[256];
    __shared__ int base_s, size_s;
    if (t == 0) {
        int b = psum[j * MS_BLOCKS];
        int nxt = (j == NB - 1) ? N_EDGES : psum[(j + 1) * MS_BLOCKS];
        base_s = b; size_s = nxt - b;
    }
    deg[t] = 0; deg[t + 256] = 0;
    __syncthreads();
    const int base = base_s, size = size_s;
    const int nlo = j << 9;
    for (int i = t; i < size; i += 256)
        atomicAdd(&deg[(unsigned)bucketed[base + i] & 511u], 1);
    __syncthreads();
    int d0 = deg[2 * t], d1 = deg[2 * t + 1];
    sd[t] = d0 + d1;
    __syncthreads();
    for (int o = 1; o < 256; o <<= 1) {
        int v = (t >= o) ? sd[t - o] : 0;
        __syncthreads();
        sd[t] += v;
        __syncthreads();
    }
    int excl = sd[t] - (d0 + d1);
    int g0 = nlo + 2 * t, g1 = g0 + 1;
    if (g0 <= N_NODES) off[g0] = base + excl;
    if (g1 <= N_NODES) off[g1] = base + excl + d0;
    __syncthreads();
    deg[2 * t] = excl;
    deg[2 * t + 1] = excl + d0;
    __syncthreads();
    for (int i = t; i < size; i += 256) {
        unsigned e = (unsigned)bucketed[base + i];
        int p = atomicAdd(&deg[e & 511u], 1);
        eidx[base + p] = (int)(e >> 9);
    }
}

// ---------------- vectorized gather: 8 edges per wave-instruction ----------------
// lane = (sub = lane>>3 edge group, col = (lane&7)*8 column slice of 8 bf16).
// Each lane loads 16B; a wave gathers 8 src rows per instruction. Butterfly
// __shfl_xor over groups merges partial sums; self term added after reduce.
__global__ __launch_bounds__(256) void gather_kernel(
        const unsigned short* __restrict__ xb, const int* __restrict__ off,
        const int* __restrict__ eidx, unsigned short* __restrict__ aggb) {
    const int lane = threadIdx.x & 63;
    const int sub  = lane >> 3;
    const int col  = (lane & 7) << 3;
    const int w    = threadIdx.x >> 6;
    const int gw = blockIdx.x * 4 + w;
    const int stride = gridDim.x * 4;
    for (int n = gw; n < N_NODES; n += stride) {
        const int beg = off[n], end = off[n + 1];
        float acc[8];
#pragma unroll
        for (int i = 0; i < 8; ++i) acc[i] = 0.f;
        for (int j = beg + sub; j < end; j += 8) {
            int s = eidx[j];
            bf16x8 r = *reinterpret_cast<const bf16x8*>(xb + (size_t)s * HID + col);
#pragma unroll
            for (int i = 0; i < 8; ++i) acc[i] += (float)r[i];
        }
#pragma unroll
        for (int m = 8; m <= 32; m <<= 1)
#pragma unroll
            for (int i = 0; i < 8; ++i) acc[i] += __shfl_xor(acc[i], m, 64);
        if (sub == 0) {
            bf16x8 s8 = *reinterpret_cast<const bf16x8*>(xb + (size_t)n * HID + col);
            u16x8 o;
#pragma unroll
            for (int i = 0; i < 8; ++i) o[i] = f2bf_rne(acc[i] + (float)s8[i]);
            *reinterpret_cast<u16x8*>(aggb + (size_t)n * HID + col) = o;
        }
    }
}

// ---------------- MFMA GEMM1: hb = aggb @ W1 + b1 (bf16 out) + BN partials ----------------
__global__ __launch_bounds__(256) void gemm1_mfma_kernel(
        const unsigned short* __restrict__ aggb, const unsigned short* __restrict__ W1t,
        const float* __restrict__ bias, unsigned short* __restrict__ hb,
        float* __restrict__ stats_partial) {
    const int lane = threadIdx.x & 63;
    const int l15 = lane & 15, lhi = lane >> 4;
    const int w = threadIdx.x >> 6;

    bf16x8 bfrag[2][4];
    float bs[4];
#pragma unroll
    for (int f = 0; f < 4; ++f) {
        const unsigned short* wp = W1t + (size_t)(f * 16 + l15) * 64 + lhi * 8;
        bfrag[0][f] = *reinterpret_cast<const bf16x8*>(wp);
        bfrag[1][f] = *reinterpret_cast<const bf16x8*>(wp + 32);
        bs[f] = bias[f * 16 + l15];
    }

    float ssum[4] = {0.f, 0.f, 0.f, 0.f}, ssq[4] = {0.f, 0.f, 0.f, 0.f};

    const int tile0 = (blockIdx.x * 4 + w) * TPW1;
#pragma unroll
    for (int tt = 0; tt < TPW1; ++tt) {
        const int tile = tile0 + tt;
        if (tile < ROW_TILES) {
            const int r0 = tile * 16;
            const size_t arow = (size_t)(r0 + l15) * 64 + lhi * 8;
            bf16x8 a0 = *reinterpret_cast<const bf16x8*>(aggb + arow);
            bf16x8 a1 = *reinterpret_cast<const bf16x8*>(aggb + arow + 32);
            f32x4 acc[4];
#pragma unroll
            for (int f = 0; f < 4; ++f) acc[f] = (f32x4){bs[f], bs[f], bs[f], bs[f]};
#pragma unroll
            for (int f = 0; f < 4; ++f) {
                acc[f] = __builtin_amdgcn_mfma_f32_16x16x32_bf16(a0, bfrag[0][f], acc[f], 0, 0, 0);
                acc[f] = __builtin_amdgcn_mfma_f32_16x16x32_bf16(a1, bfrag[1][f], acc[f], 0, 0, 0);
            }
#pragma unroll
            for (int f = 0; f < 4; ++f)
#pragma unroll
                for (int i = 0; i < 4; ++i) {
                    hb[(size_t)(r0 + lhi * 4 + i) * 64 + f * 16 + l15] = f2bf_rne(acc[f][i]);
                    ssum[f] += acc[f][i];
                    ssq[f]  += acc[f][i] * acc[f][i];
                }
        }
    }

    __shared__ float red[2][4][256];
#pragma unroll
    for (int f = 0; f < 4; ++f) {
        red[0][f][threadIdx.x] = ssum[f];
        red[1][f][threadIdx.x] = ssq[f];
    }
    __syncthreads();
    if (threadIdx.x < 64) {
        int c = threadIdx.x, f = c >> 4, p = c & 15;
        float s = 0.f, q = 0.f;
#pragma unroll
        for (int u = 0; u < 16; ++u) {
            int t = (u >> 2) * 64 + (u & 3) * 16 + p;
            s += red[0][f][t];
            q += red[1][f][t];
        }
        stats_partial[(size_t)blockIdx.x * 128 + c]      = s;
        stats_partial[(size_t)blockIdx.x * 128 + 64 + c] = q;
    }
}

// ---------------- MFMA: BN-apply + ReLU + GEMM2 + ReLU -> bf16 (bf16 in) ----------------
__global__ __launch_bounds__(256) void bn_gemm_mfma_kernel(
        const unsigned short* __restrict__ hb, const unsigned short* __restrict__ W2t,
        const float* __restrict__ bias, const float* __restrict__ scale,
        const float* __restrict__ shift, unsigned short* __restrict__ outb) {
    const int lane = threadIdx.x & 63;
    const int l15 = lane & 15, lhi = lane >> 4;
    const int w = threadIdx.x >> 6;

    bf16x8 bfrag[2][4];
    float bs[4];
#pragma unroll
    for (int f = 0; f < 4; ++f) {
        const unsigned short* wp = W2t + (size_t)(f * 16 + l15) * 64 + lhi * 8;
        bfrag[0][f] = *reinterpret_cast<const bf16x8*>(wp);
        bfrag[1][f] = *reinterpret_cast<const bf16x8*>(wp + 32);
        bs[f] = bias[f * 16 + l15];
    }
    float sc[2][8], sh[2][8];
#pragma unroll
    for (int t = 0; t < 2; ++t)
#pragma unroll
        for (int j = 0; j < 8; ++j) {
            int k = t * 32 + lhi * 8 + j;
            sc[t][j] = scale[k];
            sh[t][j] = shift[k];
        }

    const int tile0 = (blockIdx.x * 4 + w) * TPW2;
#pragma unroll
    for (int tt = 0; tt < TPW2; ++tt) {
        const int tile = tile0 + tt;
        if (tile >= ROW_TILES) return;
        const int r0 = tile * 16;
        f32x4 acc[4];
#pragma unroll
        for (int f = 0; f < 4; ++f) acc[f] = (f32x4){bs[f], bs[f], bs[f], bs[f]};
#pragma unroll
        for (int t = 0; t < 2; ++t) {
            const unsigned short* hp = hb + (size_t)(r0 + l15) * 64 + t * 32 + lhi * 8;
            bf16x8 raw = *reinterpret_cast<const bf16x8*>(hp);
            bf16x8 a;
#pragma unroll
            for (int j = 0; j < 8; ++j)
                a[j] = (__bf16)fmaxf(fmaf(sc[t][j], (float)raw[j], sh[t][j]), 0.f);
#pragma unroll
            for (int f = 0; f < 4; ++f)
                acc[f] = __builtin_amdgcn_mfma_f32_16x16x32_bf16(a, bfrag[t][f], acc[f], 0, 0, 0);
        }
#pragma unroll
        for (int f = 0; f < 4; ++f)
#pragma unroll
            for (int i = 0; i < 4; ++i)
                outb[(size_t)(r0 + lhi * 4 + i) * 64 + f * 16 + l15] =
                    f2bf_rne(fmaxf(acc[f][i], 0.f));
    }
}

// ---------------- MFMA jump head: out = [x|h1|h2] @ Wjk + bjk ----------------
__global__ __launch_bounds__(256) void jumphead_mfma_kernel(
        const unsigned short* __restrict__ xb, const unsigned short* __restrict__ h1b,
        const unsigned short* __restrict__ h2b, const unsigned short* __restrict__ Wt,
        const float* __restrict__ bjk, float* __restrict__ out) {
    const int lane = threadIdx.x & 63;
    const int l15 = lane & 15, lhi = lane >> 4;
    const int w = threadIdx.x >> 6;

    bf16x8 bfrag[6][4];
    float bs[4];
#pragma unroll
    for (int f = 0; f < 4; ++f) {
        const unsigned short* wp = Wt + (size_t)(f * 16 + l15) * 192 + lhi * 8;
#pragma unroll
        for (int t = 0; t < 6; ++t)
            bfrag[t][f] = *reinterpret_cast<const bf16x8*>(wp + t * 32);
        bs[f] = bjk[f * 16 + l15];
    }

    const int tile0 = (blockIdx.x * 4 + w) * TPW2;
#pragma unroll
    for (int tt = 0; tt < TPW2; ++tt) {
        const int tile = tile0 + tt;
        if (tile >= ROW_TILES) return;
        const int r0 = tile * 16;
        const size_t arow = (size_t)(r0 + l15) * 64 + lhi * 8;
        bf16x8 a0 = *reinterpret_cast<const bf16x8*>(xb + arow);
        bf16x8 a1 = *reinterpret_cast<const bf16x8*>(xb + arow + 32);
        bf16x8 a2 = *reinterpret_cast<const bf16x8*>(h1b + arow);
        bf16x8 a3 = *reinterpret_cast<const bf16x8*>(h1b + arow + 32);
        bf16x8 a4 = *reinterpret_cast<const bf16x8*>(h2b + arow);
        bf16x8 a5 = *reinterpret_cast<const bf16x8*>(h2b + arow + 32);
        f32x4 acc[4];
#pragma unroll
        for (int f = 0; f < 4; ++f) acc[f] = (f32x4){bs[f], bs[f], bs[f], bs[f]};
#pragma unroll
        for (int f = 0; f < 4; ++f) {
            acc[f] = __builtin_amdgcn_mfma_f32_16x16x32_bf16(a0, bfrag[0][f], acc[f], 0, 0, 0);
            acc[f] = __builtin_amdgcn_mfma_f32_16x16x32_bf16(a1, bfrag[1][f], acc[f], 0, 0, 0);
            acc[f] = __builtin_amdgcn_mfma_f32_16x16x32_bf16(a2, bfrag[2][f], acc[f], 0, 0, 0);
            acc[f] = __builtin_amdgcn_mfma_f32_16x16x32_bf16(a3, bfrag[3][f], acc[f], 0, 0, 0);
            acc[f] = __builtin_amdgcn_mfma_f32_16x16x32_bf16(a4, bfrag[4][f], acc[f], 0, 0, 0);
            acc[f] = __builtin_amdgcn_mfma_f32_16x16x32_bf16(a5, bfrag[5][f], acc[f], 0, 0, 0);
        }
#pragma unroll
        for (int f = 0; f < 4; ++f)
#pragma unroll
            for (int i = 0; i < 4; ++i)
                out[(size_t)(r0 + lhi * 4 + i) * 64 + f * 16 + l15] = acc[f][i];
    }
}

// ---------------- BN finalize: parallel reduce of partials ----------------
__global__ __launch_bounds__(1024) void bn_finalize_kernel(
        const float* __restrict__ stats_partial, int nblocks,
        const float* __restrict__ gamma, const float* __restrict__ beta,
        float* __restrict__ scale, float* __restrict__ shift) {
    __shared__ float red[2][1024];
    const int t = threadIdx.x;
    const int c = t & 63;
    const int chunk = t >> 6;        // 0..15
    float s = 0.f, q = 0.f;
    for (int b = chunk; b < nblocks; b += 16) {
        s += stats_partial[(size_t)b * 128 + c];
        q += stats_partial[(size_t)b * 128 + 64 + c];
    }
    red[0][t] = s;
    red[1][t] = q;
    __syncthreads();
    if (chunk == 0) {
        float ss = 0.f, qq = 0.f;
#pragma unroll
        for (int k = 0; k < 16; ++k) {
            ss += red[0][k * 64 + c];
            qq += red[1][k * 64 + c];
        }
        float mean = ss / (float)N_NODES;
        float var  = qq / (float)N_NODES - mean * mean;
        float scl  = gamma[c] * rsqrtf(var + BN_EPS);
        scale[c] = scl;
        shift[c] = beta[c] - mean * scl;
    }
}

extern "C" void kernel_launch(void* const* d_in, const int* in_sizes, int n_in,
                              void* d_out, int out_size, void* d_ws, size_t ws_size,
                              hipStream_t stream) {
    const float* x    = (const float*)d_in[0];
    const int*   ei   = (const int*)d_in[1];
    const int*   src  = ei;
    const int*   dst  = ei + N_EDGES;
    const float* W1_0 = (const float*)d_in[3];
    const float* b1_0 = (const float*)d_in[4];
    const float* g_0  = (const float*)d_in[5];
    const float* be_0 = (const float*)d_in[6];
    const float* W2_0 = (const float*)d_in[7];
    const float* b2_0 = (const float*)d_in[8];
    const float* W1_1 = (const float*)d_in[9];
    const float* b1_1 = (const float*)d_in[10];
    const float* g_1  = (const float*)d_in[11];
    const float* be_1 = (const float*)d_in[12];
    const float* W2_1 = (const float*)d_in[13];
    const float* b2_1 = (const float*)d_in[14];
    const float* Wjk  = (const float*)d_in[15];
    const float* bjk  = (const float*)d_in[16];

    const size_t FEAT = (size_t)N_NODES * HID;

    unsigned short* aggb = (unsigned short*)d_ws;          // FEAT bf16
    unsigned short* hb   = aggb + FEAT;                    // FEAT bf16
    unsigned short* xb   = hb + FEAT;                      // FEAT bf16
    unsigned short* h1b  = xb + FEAT;                      // FEAT bf16
    unsigned short* h2b  = h1b + FEAT;                     // FEAT bf16; aliases `bucketed`
    float* stats = (float*)(h2b + FEAT);                   // G1_BLOCKS * 128
    float* scale = stats + (size_t)G1_BLOCKS * 128;
    float* shift = scale + 64;
    int*   off   = (int*)(shift + 64);                     // N_NODES + 1 (pad 2)
    int*   eidx  = off + N_NODES + 2;                      // N_EDGES
    int*   cnt   = eidx + N_EDGES;                         // MS_CNT
    int*   psum  = cnt + MS_CNT;                           // MS_CNT + 1 (pad 2)
    int*   bsums = psum + MS_CNT + 2;                      // 256
    unsigned short* wjk_t = (unsigned short*)(bsums + 256);// 64*192
    unsigned short* w2t_0 = wjk_t + 64 * 192;              // 64*64
    unsigned short* w2t_1 = w2t_0 + 64 * 64;               // 64*64
    unsigned short* w1t_0 = w2t_1 + 64 * 64;               // 64*64
    unsigned short* w1t_1 = w1t_0 + 64 * 64;               // 64*64
    int*   bucketed = (int*)h2b;                           // 6.4 MB, dead before h2b written
    float* out   = (float*)d_out;

    // ---------------- x -> bf16; all weight transposes (1 launch) ----------------
    cvt_bf16_kernel<<<(int)(FEAT / 8 / 256), 256, 0, stream>>>(x, xb);
    wtrans_all_kernel<<<(12288 + 16384 + 255) / 256, 256, 0, stream>>>(
        Wjk, W1_0, W2_0, W1_1, W2_1, wjk_t, w1t_0, w2t_0, w1t_1, w2t_1);

    // ---------------- CSR build via two-level multi-split ----------------
    msplit_hist_kernel<<<MS_BLOCKS, 256, 0, stream>>>(dst, cnt);
    scan_partial_g<<<GS_BLOCKS, 256, 0, stream>>>(cnt, psum, bsums, MS_CNT);
    scan_bsums_kernel<<<1, 256, 0, stream>>>(bsums, GS_BLOCKS);
    scan_addback_g<<<GS_BLOCKS, 256, 0, stream>>>(psum, bsums, MS_CNT, N_EDGES);
    msplit_scatter_kernel<<<MS_BLOCKS, 256, 0, stream>>>(src, dst, psum, bucketed);
    bucket_csr_kernel<<<NB, 256, 0, stream>>>(bucketed, psum, off, eidx);

    // ---------------- layer 0 ----------------
    gather_kernel<<<GATHER_BLOCKS, 256, 0, stream>>>(xb, off, eidx, aggb);
    gemm1_mfma_kernel<<<G1_BLOCKS, 256, 0, stream>>>(aggb, w1t_0, b1_0, hb, stats);
    bn_finalize_kernel<<<1, 1024, 0, stream>>>(stats, G1_BLOCKS, g_0, be_0, scale, shift);
    bn_gemm_mfma_kernel<<<G2_BLOCKS, 256, 0, stream>>>(hb, w2t_0, b2_0, scale, shift, h1b);

    // ---------------- layer 1 ----------------
    gather_kernel<<<GATHER_BLOCKS, 256, 0, stream>>>(h1b, off, eidx, aggb);
    gemm1_mfma_kernel<<<G1_BLOCKS, 256, 0, stream>>>(aggb, w1t_1, b1_1, hb, stats);
    bn_finalize_kernel<<<1, 1024, 0, stream>>>(stats, G1_BLOCKS, g_1, be_1, scale, shift);
    bn_gemm_mfma_kernel<<<G2_BLOCKS, 256, 0, stream>>>(hb, w2t_1, b2_1, scale, shift, h2b);

    // ---------------- fused jump head (MFMA) ----------------
    jumphead_mfma_kernel<<<G2_BLOCKS, 256, 0, stream>>>(
        xb, h1b, h2b, wjk_t, bjk, out);
}

// Round 10
// 220.049 us; speedup vs baseline: 3.1393x; 1.1113x over previous
//
#include <hip/hip_runtime.h>

#define N_NODES 100000
#define N_EDGES 1600000
#define HID 64
#define BN_EPS 1e-5f

#define GATHER_BLOCKS 2048

// ---- MFMA tiling: 16-row tiles ----
#define ROW_TILES (N_NODES / 16)                     // 6250 (exact)
#define TPW1 4                                       // tiles/wave, gemm1
#define G1_BLOCKS ((ROW_TILES + 4*TPW1 - 1) / (4*TPW1))   // 391
#define TPW2 2                                       // tiles/wave, bn_gemm & jumphead
#define G2_BLOCKS ((ROW_TILES + 4*TPW2 - 1) / (4*TPW2))   // 782

// ---- multi-split CSR build parameters ----
#define NB 196                              // coarse buckets of 512 nodes (dst>>9)
#define MS_BLOCKS 512
#define MS_EPB (N_EDGES / MS_BLOCKS)        // 3125 edges per block
#define MS_CNT (NB * MS_BLOCKS)             // 100352 segment counters
#define GS_CHUNK 512
#define GS_BLOCKS ((MS_CNT + GS_CHUNK - 1) / GS_CHUNK)   // 196

typedef __bf16 bf16x8 __attribute__((ext_vector_type(8)));
typedef float  f32x4  __attribute__((ext_vector_type(4)));
typedef unsigned short u16x8 __attribute__((ext_vector_type(8)));

__device__ __forceinline__ float bf2f(unsigned short u) {
    return __uint_as_float(((unsigned)u) << 16);
}
__device__ __forceinline__ unsigned short f2bf_rne(float f) {
    unsigned u = __float_as_uint(f);
    u += 0x7FFFu + ((u >> 16) & 1u);
    return (unsigned short)(u >> 16);
}

// ---------------- fp32 -> bf16 conversion (8 elems/thread) ----------------
__global__ __launch_bounds__(256) void cvt_bf16_kernel(
        const float* __restrict__ in, unsigned short* __restrict__ out) {
    size_t i = ((size_t)blockIdx.x * 256 + threadIdx.x) * 8;
    if (i >= (size_t)N_NODES * HID) return;
    float4 a = *reinterpret_cast<const float4*>(in + i);
    float4 b = *reinterpret_cast<const float4*>(in + i + 4);
    ushort4 w0 = make_ushort4(f2bf_rne(a.x), f2bf_rne(a.y), f2bf_rne(a.z), f2bf_rne(a.w));
    ushort4 w1 = make_ushort4(f2bf_rne(b.x), f2bf_rne(b.y), f2bf_rne(b.z), f2bf_rne(b.w));
    *reinterpret_cast<ushort4*>(out + i) = w0;
    *reinterpret_cast<ushort4*>(out + i + 4) = w1;
}

// ---------------- all weight transposes in one launch ----------------
__global__ __launch_bounds__(256) void wtrans_all_kernel(
        const float* __restrict__ Wjk,
        const float* __restrict__ W1_0, const float* __restrict__ W2_0,
        const float* __restrict__ W1_1, const float* __restrict__ W2_1,
        unsigned short* __restrict__ wjk_t,
        unsigned short* __restrict__ w1t_0, unsigned short* __restrict__ w2t_0,
        unsigned short* __restrict__ w1t_1, unsigned short* __restrict__ w2t_1) {
    int i = blockIdx.x * 256 + threadIdx.x;
    if (i < 12288) {
        int c = i / 192, k = i - c * 192;
        wjk_t[i] = f2bf_rne(Wjk[k * 64 + c]);
    } else if (i < 12288 + 16384) {
        int r = i - 12288;
        int which = r >> 12, rem = r & 4095;
        int c = rem >> 6, k = rem & 63;
        const float* W = (which == 0) ? W1_0 : (which == 1) ? W2_0
                       : (which == 2) ? W1_1 : W2_1;
        unsigned short* Wt = (which == 0) ? w1t_0 : (which == 1) ? w2t_0
                           : (which == 2) ? w1t_1 : w2t_1;
        Wt[rem] = f2bf_rne(W[k * 64 + c]);
    }
}

// ---------------- multi-split phase A: per-(block,bucket) histogram ----------------
__global__ __launch_bounds__(256) void msplit_hist_kernel(
        const int* __restrict__ dst, int* __restrict__ cnt) {
    __shared__ int h[NB];
    for (int i = threadIdx.x; i < NB; i += 256) h[i] = 0;
    __syncthreads();
    const int e0 = blockIdx.x * MS_EPB;
    for (int e = e0 + threadIdx.x; e < e0 + MS_EPB; e += 256)
        atomicAdd(&h[dst[e] >> 9], 1);
    __syncthreads();
    for (int i = threadIdx.x; i < NB; i += 256)
        cnt[i * MS_BLOCKS + blockIdx.x] = h[i];   // j-major: segments land bucket-contiguous
}

// ---------------- generic exclusive scan (3 kernels) ----------------
__global__ __launch_bounds__(256) void scan_partial_g(
        const int* __restrict__ in, int* __restrict__ out,
        int* __restrict__ bsums, int n) {
    __shared__ int sd[256];
    int t = threadIdx.x;
    int base = blockIdx.x * GS_CHUNK;
    int i0 = base + 2 * t, i1 = i0 + 1;
    int d0 = (i0 < n) ? in[i0] : 0;
    int d1 = (i1 < n) ? in[i1] : 0;
    sd[t] = d0 + d1;
    __syncthreads();
    for (int o = 1; o < 256; o <<= 1) {
        int v = (t >= o) ? sd[t - o] : 0;
        __syncthreads();
        sd[t] += v;
        __syncthreads();
    }
    int excl = sd[t] - (d0 + d1);
    if (i0 < n) out[i0] = excl;
    if (i1 < n) out[i1] = excl + d0;
    if (t == 255) bsums[blockIdx.x] = sd[255];
}

__global__ __launch_bounds__(256) void scan_bsums_kernel(int* __restrict__ bsums, int nb) {
    __shared__ int sd[256];
    int t = threadIdx.x;
    int v = (t < nb) ? bsums[t] : 0;
    sd[t] = v;
    __syncthreads();
    for (int o = 1; o < 256; o <<= 1) {
        int u = (t >= o) ? sd[t - o] : 0;
        __syncthreads();
        sd[t] += u;
        __syncthreads();
    }
    if (t < nb) bsums[t] = sd[t] - v;   // exclusive
}

__global__ __launch_bounds__(256) void scan_addback_g(
        int* __restrict__ out, const int* __restrict__ bsums, int n, int total) {
    int t = threadIdx.x;
    int b = bsums[blockIdx.x];
    int base = blockIdx.x * GS_CHUNK;
    int i0 = base + 2 * t, i1 = i0 + 1;
    if (i0 < n) out[i0] += b;
    if (i1 < n) out[i1] += b;
    if (blockIdx.x == 0 && t == 0) out[n] = total;   // sentinel
}

// ---------------- multi-split phase B: scatter packed (src<<9|dlocal) ----------------
__global__ __launch_bounds__(256) void msplit_scatter_kernel(
        const int* __restrict__ src, const int* __restrict__ dst,
        const int* __restrict__ psum, int* __restrict__ bucketed) {
    __shared__ int cur[NB];
    for (int i = threadIdx.x; i < NB; i += 256)
        cur[i] = psum[i * MS_BLOCKS + blockIdx.x];
    __syncthreads();
    const int e0 = blockIdx.x * MS_EPB;
    for (int e = e0 + threadIdx.x; e < e0 + MS_EPB; e += 256) {
        int d = dst[e];
        int p = atomicAdd(&cur[d >> 9], 1);
        bucketed[p] = (src[e] << 9) | (d & 511);
    }
}

// ---------------- per-bucket local CSR: off + eidx, all writes block-local ----------------
__global__ __launch_bounds__(256) void bucket_csr_kernel(
        const int* __restrict__ bucketed, const int* __restrict__ psum,
        int* __restrict__ off, int* __restrict__ eidx) {
    const int j = blockIdx.x;
    const int t = threadIdx.x;
    __shared__ int deg[512];
    __shared__ int sd[256];
    __shared__ int base_s, size_s;
    if (t == 0) {
        int b = psum[j * MS_BLOCKS];
        int nxt = (j == NB - 1) ? N_EDGES : psum[(j + 1) * MS_BLOCKS];
        base_s = b; size_s = nxt - b;
    }
    deg[t] = 0; deg[t + 256] = 0;
    __syncthreads();
    const int base = base_s, size = size_s;
    const int nlo = j << 9;
    for (int i = t; i < size; i += 256)
        atomicAdd(&deg[(unsigned)bucketed[base + i] & 511u], 1);
    __syncthreads();
    int d0 = deg[2 * t], d1 = deg[2 * t + 1];
    sd[t] = d0 + d1;
    __syncthreads();
    for (int o = 1; o < 256; o <<= 1) {
        int v = (t >= o) ? sd[t - o] : 0;
        __syncthreads();
        sd[t] += v;
        __syncthreads();
    }
    int excl = sd[t] - (d0 + d1);
    int g0 = nlo + 2 * t, g1 = g0 + 1;
    if (g0 <= N_NODES) off[g0] = base + excl;
    if (g1 <= N_NODES) off[g1] = base + excl + d0;
    __syncthreads();
    deg[2 * t] = excl;
    deg[2 * t + 1] = excl + d0;
    __syncthreads();
    for (int i = t; i < size; i += 256) {
        unsigned e = (unsigned)bucketed[base + i];
        int p = atomicAdd(&deg[e & 511u], 1);
        eidx[base + p] = (int)(e >> 9);
    }
}

// ---------------- vectorized gather: 8 edges per wave-instruction ----------------
__global__ __launch_bounds__(256) void gather_kernel(
        const unsigned short* __restrict__ xb, const int* __restrict__ off,
        const int* __restrict__ eidx, unsigned short* __restrict__ aggb) {
    const int lane = threadIdx.x & 63;
    const int sub  = lane >> 3;
    const int col  = (lane & 7) << 3;
    const int w    = threadIdx.x >> 6;
    const int gw = blockIdx.x * 4 + w;
    const int stride = gridDim.x * 4;
    for (int n = gw; n < N_NODES; n += stride) {
        const int beg = off[n], end = off[n + 1];
        float acc[8];
#pragma unroll
        for (int i = 0; i < 8; ++i) acc[i] = 0.f;
        for (int j = beg + sub; j < end; j += 8) {
            int s = eidx[j];
            bf16x8 r = *reinterpret_cast<const bf16x8*>(xb + (size_t)s * HID + col);
#pragma unroll
            for (int i = 0; i < 8; ++i) acc[i] += (float)r[i];
        }
#pragma unroll
        for (int m = 8; m <= 32; m <<= 1)
#pragma unroll
            for (int i = 0; i < 8; ++i) acc[i] += __shfl_xor(acc[i], m, 64);
        if (sub == 0) {
            bf16x8 s8 = *reinterpret_cast<const bf16x8*>(xb + (size_t)n * HID + col);
            u16x8 o;
#pragma unroll
            for (int i = 0; i < 8; ++i) o[i] = f2bf_rne(acc[i] + (float)s8[i]);
            *reinterpret_cast<u16x8*>(aggb + (size_t)n * HID + col) = o;
        }
    }
}

// ---------------- MFMA GEMM1: hb = aggb @ W1 + b1 (bf16 out) + BN partials ----------------
__global__ __launch_bounds__(256) void gemm1_mfma_kernel(
        const unsigned short* __restrict__ aggb, const unsigned short* __restrict__ W1t,
        const float* __restrict__ bias, unsigned short* __restrict__ hb,
        float* __restrict__ stats_partial) {
    const int lane = threadIdx.x & 63;
    const int l15 = lane & 15, lhi = lane >> 4;
    const int w = threadIdx.x >> 6;

    bf16x8 bfrag[2][4];
    float bs[4];
#pragma unroll
    for (int f = 0; f < 4; ++f) {
        const unsigned short* wp = W1t + (size_t)(f * 16 + l15) * 64 + lhi * 8;
        bfrag[0][f] = *reinterpret_cast<const bf16x8*>(wp);
        bfrag[1][f] = *reinterpret_cast<const bf16x8*>(wp + 32);
        bs[f] = bias[f * 16 + l15];
    }

    float ssum[4] = {0.f, 0.f, 0.f, 0.f}, ssq[4] = {0.f, 0.f, 0.f, 0.f};

    const int tile0 = (blockIdx.x * 4 + w) * TPW1;
#pragma unroll
    for (int tt = 0; tt < TPW1; ++tt) {
        const int tile = tile0 + tt;
        if (tile < ROW_TILES) {
            const int r0 = tile * 16;
            const size_t arow = (size_t)(r0 + l15) * 64 + lhi * 8;
            bf16x8 a0 = *reinterpret_cast<const bf16x8*>(aggb + arow);
            bf16x8 a1 = *reinterpret_cast<const bf16x8*>(aggb + arow + 32);
            f32x4 acc[4];
#pragma unroll
            for (int f = 0; f < 4; ++f) acc[f] = (f32x4){bs[f], bs[f], bs[f], bs[f]};
#pragma unroll
            for (int f = 0; f < 4; ++f) {
                acc[f] = __builtin_amdgcn_mfma_f32_16x16x32_bf16(a0, bfrag[0][f], acc[f], 0, 0, 0);
                acc[f] = __builtin_amdgcn_mfma_f32_16x16x32_bf16(a1, bfrag[1][f], acc[f], 0, 0, 0);
            }
#pragma unroll
            for (int f = 0; f < 4; ++f)
#pragma unroll
                for (int i = 0; i < 4; ++i) {
                    hb[(size_t)(r0 + lhi * 4 + i) * 64 + f * 16 + l15] = f2bf_rne(acc[f][i]);
                    ssum[f] += acc[f][i];
                    ssq[f]  += acc[f][i] * acc[f][i];
                }
        }
    }

    __shared__ float red[2][4][256];
#pragma unroll
    for (int f = 0; f < 4; ++f) {
        red[0][f][threadIdx.x] = ssum[f];
        red[1][f][threadIdx.x] = ssq[f];
    }
    __syncthreads();
    if (threadIdx.x < 64) {
        int c = threadIdx.x, f = c >> 4, p = c & 15;
        float s = 0.f, q = 0.f;
#pragma unroll
        for (int u = 0; u < 16; ++u) {
            int t = (u >> 2) * 64 + (u & 3) * 16 + p;
            s += red[0][f][t];
            q += red[1][f][t];
        }
        stats_partial[(size_t)blockIdx.x * 128 + c]      = s;
        stats_partial[(size_t)blockIdx.x * 128 + 64 + c] = q;
    }
}

// ---------------- MFMA: BN-apply + ReLU + GEMM2 + ReLU -> bf16 (bf16 in) ----------------
__global__ __launch_bounds__(256) void bn_gemm_mfma_kernel(
        const unsigned short* __restrict__ hb, const unsigned short* __restrict__ W2t,
        const float* __restrict__ bias, const float* __restrict__ scale,
        const float* __restrict__ shift, unsigned short* __restrict__ outb) {
    const int lane = threadIdx.x & 63;
    const int l15 = lane & 15, lhi = lane >> 4;
    const int w = threadIdx.x >> 6;

    bf16x8 bfrag[2][4];
    float bs[4];
#pragma unroll
    for (int f = 0; f < 4; ++f) {
        const unsigned short* wp = W2t + (size_t)(f * 16 + l15) * 64 + lhi * 8;
        bfrag[0][f] = *reinterpret_cast<const bf16x8*>(wp);
        bfrag[1][f] = *reinterpret_cast<const bf16x8*>(wp + 32);
        bs[f] = bias[f * 16 + l15];
    }
    float sc[2][8], sh[2][8];
#pragma unroll
    for (int t = 0; t < 2; ++t)
#pragma unroll
        for (int j = 0; j < 8; ++j) {
            int k = t * 32 + lhi * 8 + j;
            sc[t][j] = scale[k];
            sh[t][j] = shift[k];
        }

    const int tile0 = (blockIdx.x * 4 + w) * TPW2;
#pragma unroll
    for (int tt = 0; tt < TPW2; ++tt) {
        const int tile = tile0 + tt;
        if (tile >= ROW_TILES) return;
        const int r0 = tile * 16;
        f32x4 acc[4];
#pragma unroll
        for (int f = 0; f < 4; ++f) acc[f] = (f32x4){bs[f], bs[f], bs[f], bs[f]};
#pragma unroll
        for (int t = 0; t < 2; ++t) {
            const unsigned short* hp = hb + (size_t)(r0 + l15) * 64 + t * 32 + lhi * 8;
            bf16x8 raw = *reinterpret_cast<const bf16x8*>(hp);
            bf16x8 a;
#pragma unroll
            for (int j = 0; j < 8; ++j)
                a[j] = (__bf16)fmaxf(fmaf(sc[t][j], (float)raw[j], sh[t][j]), 0.f);
#pragma unroll
            for (int f = 0; f < 4; ++f)
                acc[f] = __builtin_amdgcn_mfma_f32_16x16x32_bf16(a, bfrag[t][f], acc[f], 0, 0, 0);
        }
#pragma unroll
        for (int f = 0; f < 4; ++f)
#pragma unroll
            for (int i = 0; i < 4; ++i)
                outb[(size_t)(r0 + lhi * 4 + i) * 64 + f * 16 + l15] =
                    f2bf_rne(fmaxf(acc[f][i], 0.f));
    }
}

// ---------------- MFMA jump head: out = [x|h1|h2] @ Wjk + bjk ----------------
__global__ __launch_bounds__(256) void jumphead_mfma_kernel(
        const unsigned short* __restrict__ xb, const unsigned short* __restrict__ h1b,
        const unsigned short* __restrict__ h2b, const unsigned short* __restrict__ Wt,
        const float* __restrict__ bjk, float* __restrict__ out) {
    const int lane = threadIdx.x & 63;
    const int l15 = lane & 15, lhi = lane >> 4;
    const int w = threadIdx.x >> 6;

    bf16x8 bfrag[6][4];
    float bs[4];
#pragma unroll
    for (int f = 0; f < 4; ++f) {
        const unsigned short* wp = Wt + (size_t)(f * 16 + l15) * 192 + lhi * 8;
#pragma unroll
        for (int t = 0; t < 6; ++t)
            bfrag[t][f] = *reinterpret_cast<const bf16x8*>(wp + t * 32);
        bs[f] = bjk[f * 16 + l15];
    }

    const int tile0 = (blockIdx.x * 4 + w) * TPW2;
#pragma unroll
    for (int tt = 0; tt < TPW2; ++tt) {
        const int tile = tile0 + tt;
        if (tile >= ROW_TILES) return;
        const int r0 = tile * 16;
        const size_t arow = (size_t)(r0 + l15) * 64 + lhi * 8;
        bf16x8 a0 = *reinterpret_cast<const bf16x8*>(xb + arow);
        bf16x8 a1 = *reinterpret_cast<const bf16x8*>(xb + arow + 32);
        bf16x8 a2 = *reinterpret_cast<const bf16x8*>(h1b + arow);
        bf16x8 a3 = *reinterpret_cast<const bf16x8*>(h1b + arow + 32);
        bf16x8 a4 = *reinterpret_cast<const bf16x8*>(h2b + arow);
        bf16x8 a5 = *reinterpret_cast<const bf16x8*>(h2b + arow + 32);
        f32x4 acc[4];
#pragma unroll
        for (int f = 0; f < 4; ++f) acc[f] = (f32x4){bs[f], bs[f], bs[f], bs[f]};
#pragma unroll
        for (int f = 0; f < 4; ++f) {
            acc[f] = __builtin_amdgcn_mfma_f32_16x16x32_bf16(a0, bfrag[0][f], acc[f], 0, 0, 0);
            acc[f] = __builtin_amdgcn_mfma_f32_16x16x32_bf16(a1, bfrag[1][f], acc[f], 0, 0, 0);
            acc[f] = __builtin_amdgcn_mfma_f32_16x16x32_bf16(a2, bfrag[2][f], acc[f], 0, 0, 0);
            acc[f] = __builtin_amdgcn_mfma_f32_16x16x32_bf16(a3, bfrag[3][f], acc[f], 0, 0, 0);
            acc[f] = __builtin_amdgcn_mfma_f32_16x16x32_bf16(a4, bfrag[4][f], acc[f], 0, 0, 0);
            acc[f] = __builtin_amdgcn_mfma_f32_16x16x32_bf16(a5, bfrag[5][f], acc[f], 0, 0, 0);
        }
#pragma unroll
        for (int f = 0; f < 4; ++f)
#pragma unroll
            for (int i = 0; i < 4; ++i)
                out[(size_t)(r0 + lhi * 4 + i) * 64 + f * 16 + l15] = acc[f][i];
    }
}

// ---------------- BN finalize: parallel reduce of partials ----------------
__global__ __launch_bounds__(1024) void bn_finalize_kernel(
        const float* __restrict__ stats_partial, int nblocks,
        const float* __restrict__ gamma, const float* __restrict__ beta,
        float* __restrict__ scale, float* __restrict__ shift) {
    __shared__ float red[2][1024];
    const int t = threadIdx.x;
    const int c = t & 63;
    const int chunk = t >> 6;        // 0..15
    float s = 0.f, q = 0.f;
    for (int b = chunk; b < nblocks; b += 16) {
        s += stats_partial[(size_t)b * 128 + c];
        q += stats_partial[(size_t)b * 128 + 64 + c];
    }
    red[0][t] = s;
    red[1][t] = q;
    __syncthreads();
    if (chunk == 0) {
        float ss = 0.f, qq = 0.f;
#pragma unroll
        for (int k = 0; k < 16; ++k) {
            ss += red[0][k * 64 + c];
            qq += red[1][k * 64 + c];
        }
        float mean = ss / (float)N_NODES;
        float var  = qq / (float)N_NODES - mean * mean;
        float scl  = gamma[c] * rsqrtf(var + BN_EPS);
        scale[c] = scl;
        shift[c] = beta[c] - mean * scl;
    }
}

extern "C" void kernel_launch(void* const* d_in, const int* in_sizes, int n_in,
                              void* d_out, int out_size, void* d_ws, size_t ws_size,
                              hipStream_t stream) {
    const float* x    = (const float*)d_in[0];
    const int*   ei   = (const int*)d_in[1];
    const int*   src  = ei;
    const int*   dst  = ei + N_EDGES;
    const float* W1_0 = (const float*)d_in[3];
    const float* b1_0 = (const float*)d_in[4];
    const float* g_0  = (const float*)d_in[5];
    const float* be_0 = (const float*)d_in[6];
    const float* W2_0 = (const float*)d_in[7];
    const float* b2_0 = (const float*)d_in[8];
    const float* W1_1 = (const float*)d_in[9];
    const float* b1_1 = (const float*)d_in[10];
    const float* g_1  = (const float*)d_in[11];
    const float* be_1 = (const float*)d_in[12];
    const float* W2_1 = (const float*)d_in[13];
    const float* b2_1 = (const float*)d_in[14];
    const float* Wjk  = (const float*)d_in[15];
    const float* bjk  = (const float*)d_in[16];

    const size_t FEAT = (size_t)N_NODES * HID;

    unsigned short* aggb = (unsigned short*)d_ws;          // FEAT bf16
    unsigned short* hb   = aggb + FEAT;                    // FEAT bf16
    unsigned short* xb   = hb + FEAT;                      // FEAT bf16
    unsigned short* h1b  = xb + FEAT;                      // FEAT bf16
    unsigned short* h2b  = h1b + FEAT;                     // FEAT bf16; aliases `bucketed`
    float* stats = (float*)(h2b + FEAT);                   // G1_BLOCKS * 128
    float* scale = stats + (size_t)G1_BLOCKS * 128;
    float* shift = scale + 64;
    int*   off   = (int*)(shift + 64);                     // N_NODES + 1 (pad 2)
    int*   eidx  = off + N_NODES + 2;                      // N_EDGES
    int*   cnt   = eidx + N_EDGES;                         // MS_CNT
    int*   psum  = cnt + MS_CNT;                           // MS_CNT + 1 (pad 2)
    int*   bsums = psum + MS_CNT + 2;                      // 256
    unsigned short* wjk_t = (unsigned short*)(bsums + 256);// 64*192
    unsigned short* w2t_0 = wjk_t + 64 * 192;              // 64*64
    unsigned short* w2t_1 = w2t_0 + 64 * 64;               // 64*64
    unsigned short* w1t_0 = w2t_1 + 64 * 64;               // 64*64
    unsigned short* w1t_1 = w1t_0 + 64 * 64;               // 64*64
    int*   bucketed = (int*)h2b;                           // 6.4 MB, dead before h2b written
    float* out   = (float*)d_out;

    // ---------------- x -> bf16; all weight transposes (1 launch) ----------------
    cvt_bf16_kernel<<<(int)(FEAT / 8 / 256), 256, 0, stream>>>(x, xb);
    wtrans_all_kernel<<<(12288 + 16384 + 255) / 256, 256, 0, stream>>>(
        Wjk, W1_0, W2_0, W1_1, W2_1, wjk_t, w1t_0, w2t_0, w1t_1, w2t_1);

    // ---------------- CSR build via two-level multi-split ----------------
    msplit_hist_kernel<<<MS_BLOCKS, 256, 0, stream>>>(dst, cnt);
    scan_partial_g<<<GS_BLOCKS, 256, 0, stream>>>(cnt, psum, bsums, MS_CNT);
    scan_bsums_kernel<<<1, 256, 0, stream>>>(bsums, GS_BLOCKS);
    scan_addback_g<<<GS_BLOCKS, 256, 0, stream>>>(psum, bsums, MS_CNT, N_EDGES);
    msplit_scatter_kernel<<<MS_BLOCKS, 256, 0, stream>>>(src, dst, psum, bucketed);
    bucket_csr_kernel<<<NB, 256, 0, stream>>>(bucketed, psum, off, eidx);

    // ---------------- layer 0 ----------------
    gather_kernel<<<GATHER_BLOCKS, 256, 0, stream>>>(xb, off, eidx, aggb);
    gemm1_mfma_kernel<<<G1_BLOCKS, 256, 0, stream>>>(aggb, w1t_0, b1_0, hb, stats);
    bn_finalize_kernel<<<1, 1024, 0, stream>>>(stats, G1_BLOCKS, g_0, be_0, scale, shift);
    bn_gemm_mfma_kernel<<<G2_BLOCKS, 256, 0, stream>>>(hb, w2t_0, b2_0, scale, shift, h1b);

    // ---------------- layer 1 ----------------
    gather_kernel<<<GATHER_BLOCKS, 256, 0, stream>>>(h1b, off, eidx, aggb);
    gemm1_mfma_kernel<<<G1_BLOCKS, 256, 0, stream>>>(aggb, w1t_1, b1_1, hb, stats);
    bn_finalize_kernel<<<1, 1024, 0, stream>>>(stats, G1_BLOCKS, g_1, be_1, scale, shift);
    bn_gemm_mfma_kernel<<<G2_BLOCKS, 256, 0, stream>>>(hb, w2t_1, b2_1, scale, shift, h2b);

    // ---------------- fused jump head (MFMA) ----------------
    jumphead_mfma_kernel<<<G2_BLOCKS, 256, 0, stream>>>(
        xb, h1b, h2b, wjk_t, bjk, out);
}

// Round 11
// 203.999 us; speedup vs baseline: 3.3863x; 1.0787x over previous
//
#include <hip/hip_runtime.h>

#define N_NODES 100000
#define N_EDGES 1600000
#define HID 64
#define BN_EPS 1e-5f

// ---- gather: 8 nodes/wave, 32 nodes/block ----
#define GATHER_BLOCKS (N_NODES / 32)                 // 3125 (exact)

// ---- MFMA tiling: 16-row tiles ----
#define ROW_TILES (N_NODES / 16)                     // 6250 (exact)
#define TPW1 4                                       // tiles/wave, gemm1
#define G1_BLOCKS ((ROW_TILES + 4*TPW1 - 1) / (4*TPW1))   // 391
#define TPW2 2                                       // tiles/wave, bn_gemm & jumphead
#define G2_BLOCKS ((ROW_TILES + 4*TPW2 - 1) / (4*TPW2))   // 782

// ---- multi-split CSR build parameters ----
#define NB 391                              // coarse buckets of 256 nodes (dst>>8)
#define MS_BLOCKS 1000
#define MS_EPB (N_EDGES / MS_BLOCKS)        // 1600 edges per block
#define MS_CNT (NB * MS_BLOCKS)             // 391000 segment counters
#define GS_CHUNK 512
#define GS_BLOCKS ((MS_CNT + GS_CHUNK - 1) / GS_CHUNK)   // 764

typedef __bf16 bf16x8 __attribute__((ext_vector_type(8)));
typedef float  f32x4  __attribute__((ext_vector_type(4)));
typedef unsigned short u16x8 __attribute__((ext_vector_type(8)));

__device__ __forceinline__ float bf2f(unsigned short u) {
    return __uint_as_float(((unsigned)u) << 16);
}
__device__ __forceinline__ unsigned short f2bf_rne(float f) {
    unsigned u = __float_as_uint(f);
    u += 0x7FFFu + ((u >> 16) & 1u);
    return (unsigned short)(u >> 16);
}

// ---------------- fp32 -> bf16 conversion (8 elems/thread) ----------------
__global__ __launch_bounds__(256) void cvt_bf16_kernel(
        const float* __restrict__ in, unsigned short* __restrict__ out) {
    size_t i = ((size_t)blockIdx.x * 256 + threadIdx.x) * 8;
    if (i >= (size_t)N_NODES * HID) return;
    float4 a = *reinterpret_cast<const float4*>(in + i);
    float4 b = *reinterpret_cast<const float4*>(in + i + 4);
    ushort4 w0 = make_ushort4(f2bf_rne(a.x), f2bf_rne(a.y), f2bf_rne(a.z), f2bf_rne(a.w));
    ushort4 w1 = make_ushort4(f2bf_rne(b.x), f2bf_rne(b.y), f2bf_rne(b.z), f2bf_rne(b.w));
    *reinterpret_cast<ushort4*>(out + i) = w0;
    *reinterpret_cast<ushort4*>(out + i + 4) = w1;
}

// ---------------- all weight transposes in one launch ----------------
__global__ __launch_bounds__(256) void wtrans_all_kernel(
        const float* __restrict__ Wjk,
        const float* __restrict__ W1_0, const float* __restrict__ W2_0,
        const float* __restrict__ W1_1, const float* __restrict__ W2_1,
        unsigned short* __restrict__ wjk_t,
        unsigned short* __restrict__ w1t_0, unsigned short* __restrict__ w2t_0,
        unsigned short* __restrict__ w1t_1, unsigned short* __restrict__ w2t_1) {
    int i = blockIdx.x * 256 + threadIdx.x;
    if (i < 12288) {
        int c = i / 192, k = i - c * 192;
        wjk_t[i] = f2bf_rne(Wjk[k * 64 + c]);
    } else if (i < 12288 + 16384) {
        int r = i - 12288;
        int which = r >> 12, rem = r & 4095;
        int c = rem >> 6, k = rem & 63;
        const float* W = (which == 0) ? W1_0 : (which == 1) ? W2_0
                       : (which == 2) ? W1_1 : W2_1;
        unsigned short* Wt = (which == 0) ? w1t_0 : (which == 1) ? w2t_0
                           : (which == 2) ? w1t_1 : w2t_1;
        Wt[rem] = f2bf_rne(W[k * 64 + c]);
    }
}

// ---------------- multi-split phase A: per-(block,bucket) histogram ----------------
__global__ __launch_bounds__(256) void msplit_hist_kernel(
        const int* __restrict__ dst, int* __restrict__ cnt) {
    __shared__ int h[NB];
    for (int i = threadIdx.x; i < NB; i += 256) h[i] = 0;
    __syncthreads();
    const int e0 = blockIdx.x * MS_EPB;
    for (int e = e0 + threadIdx.x; e < e0 + MS_EPB; e += 256)
        atomicAdd(&h[dst[e] >> 8], 1);
    __syncthreads();
    for (int i = threadIdx.x; i < NB; i += 256)
        cnt[i * MS_BLOCKS + blockIdx.x] = h[i];   // j-major: segments land bucket-contiguous
}

// ---------------- generic exclusive scan (3 kernels) ----------------
__global__ __launch_bounds__(256) void scan_partial_g(
        const int* __restrict__ in, int* __restrict__ out,
        int* __restrict__ bsums, int n) {
    __shared__ int sd[256];
    int t = threadIdx.x;
    int base = blockIdx.x * GS_CHUNK;
    int i0 = base + 2 * t, i1 = i0 + 1;
    int d0 = (i0 < n) ? in[i0] : 0;
    int d1 = (i1 < n) ? in[i1] : 0;
    sd[t] = d0 + d1;
    __syncthreads();
    for (int o = 1; o < 256; o <<= 1) {
        int v = (t >= o) ? sd[t - o] : 0;
        __syncthreads();
        sd[t] += v;
        __syncthreads();
    }
    int excl = sd[t] - (d0 + d1);
    if (i0 < n) out[i0] = excl;
    if (i1 < n) out[i1] = excl + d0;
    if (t == 255) bsums[blockIdx.x] = sd[255];
}

// single-block scan of up to 1024 block-sums (4 per thread)
__global__ __launch_bounds__(256) void scan_bsums_kernel(int* __restrict__ bsums, int nb) {
    __shared__ int sd[256];
    int t = threadIdx.x;
    int v[4]; int s = 0;
#pragma unroll
    for (int k = 0; k < 4; ++k) {
        int i = t * 4 + k;
        v[k] = (i < nb) ? bsums[i] : 0;
        s += v[k];
    }
    sd[t] = s;
    __syncthreads();
    for (int o = 1; o < 256; o <<= 1) {
        int u = (t >= o) ? sd[t - o] : 0;
        __syncthreads();
        sd[t] += u;
        __syncthreads();
    }
    int run = sd[t] - s;   // exclusive over this thread's chunk
#pragma unroll
    for (int k = 0; k < 4; ++k) {
        int i = t * 4 + k;
        if (i < nb) bsums[i] = run;
        run += v[k];
    }
}

__global__ __launch_bounds__(256) void scan_addback_g(
        int* __restrict__ out, const int* __restrict__ bsums, int n, int total) {
    int t = threadIdx.x;
    int b = bsums[blockIdx.x];
    int base = blockIdx.x * GS_CHUNK;
    int i0 = base + 2 * t, i1 = i0 + 1;
    if (i0 < n) out[i0] += b;
    if (i1 < n) out[i1] += b;
    if (blockIdx.x == 0 && t == 0) out[n] = total;   // sentinel
}

// ---------------- multi-split phase B: scatter packed (src<<8|dlocal) ----------------
__global__ __launch_bounds__(256) void msplit_scatter_kernel(
        const int* __restrict__ src, const int* __restrict__ dst,
        const int* __restrict__ psum, int* __restrict__ bucketed) {
    __shared__ int cur[NB];
    for (int i = threadIdx.x; i < NB; i += 256)
        cur[i] = psum[i * MS_BLOCKS + blockIdx.x];
    __syncthreads();
    const int e0 = blockIdx.x * MS_EPB;
    for (int e = e0 + threadIdx.x; e < e0 + MS_EPB; e += 256) {
        int d = dst[e];
        int p = atomicAdd(&cur[d >> 8], 1);
        bucketed[p] = (src[e] << 8) | (d & 255);
    }
}

// ---------------- per-bucket local CSR (256-node buckets) ----------------
__global__ __launch_bounds__(256) void bucket_csr_kernel(
        const int* __restrict__ bucketed, const int* __restrict__ psum,
        int* __restrict__ off, int* __restrict__ eidx) {
    const int j = blockIdx.x;
    const int t = threadIdx.x;
    __shared__ int deg[256];
    __shared__ int sd[256];
    __shared__ int base_s, size_s;
    if (t == 0) {
        int b = psum[j * MS_BLOCKS];
        int nxt = (j == NB - 1) ? N_EDGES : psum[(j + 1) * MS_BLOCKS];
        base_s = b; size_s = nxt - b;
    }
    deg[t] = 0;
    __syncthreads();
    const int base = base_s, size = size_s;
    const int nlo = j << 8;
    for (int i = t; i < size; i += 256)
        atomicAdd(&deg[(unsigned)bucketed[base + i] & 255u], 1);
    __syncthreads();
    int d0 = deg[t];
    sd[t] = d0;
    __syncthreads();
    for (int o = 1; o < 256; o <<= 1) {
        int v = (t >= o) ? sd[t - o] : 0;
        __syncthreads();
        sd[t] += v;
        __syncthreads();
    }
    int excl = sd[t] - d0;
    int g0 = nlo + t;
    if (g0 <= N_NODES) off[g0] = base + excl;
    __syncthreads();
    deg[t] = excl;
    __syncthreads();
    for (int i = t; i < size; i += 256) {
        unsigned e = (unsigned)bucketed[base + i];
        int p = atomicAdd(&deg[e & 255u], 1);
        eidx[base + p] = (int)(e >> 8);
    }
}

// ---------------- gather: 8 nodes per wave, lane-private accumulators ----------------
// Group g = lane>>3 owns node n = block*32 + wave*8 + g; lane&7 holds a 16B
// column slice. Per iteration the wave gathers 8 scattered rows (1 KB); no
// cross-lane reduction needed. 3125 blocks x 32 nodes = exact cover.
__global__ __launch_bounds__(256) void gather_kernel(
        const unsigned short* __restrict__ xb, const int* __restrict__ off,
        const int* __restrict__ eidx, unsigned short* __restrict__ aggb) {
    const int lane = threadIdx.x & 63;
    const int g    = lane >> 3;
    const int col  = (lane & 7) << 3;
    const int w    = threadIdx.x >> 6;
    const int n = blockIdx.x * 32 + w * 8 + g;

    const int beg = off[n], end = off[n + 1];
    bf16x8 s8 = *reinterpret_cast<const bf16x8*>(xb + (size_t)n * HID + col);
    float acc[8];
#pragma unroll
    for (int i = 0; i < 8; ++i) acc[i] = (float)s8[i];   // (1+eps)*x self, eps=0

    int j = beg;
    for (; j + 2 <= end; j += 2) {
        int s0 = eidx[j], s1 = eidx[j + 1];
        bf16x8 r0 = *reinterpret_cast<const bf16x8*>(xb + (size_t)s0 * HID + col);
        bf16x8 r1 = *reinterpret_cast<const bf16x8*>(xb + (size_t)s1 * HID + col);
#pragma unroll
        for (int i = 0; i < 8; ++i) acc[i] += (float)r0[i] + (float)r1[i];
    }
    if (j < end) {
        int s0 = eidx[j];
        bf16x8 r0 = *reinterpret_cast<const bf16x8*>(xb + (size_t)s0 * HID + col);
#pragma unroll
        for (int i = 0; i < 8; ++i) acc[i] += (float)r0[i];
    }

    u16x8 o;
#pragma unroll
    for (int i = 0; i < 8; ++i) o[i] = f2bf_rne(acc[i]);
    *reinterpret_cast<u16x8*>(aggb + (size_t)n * HID + col) = o;
}

// ---------------- MFMA GEMM1: hb = aggb @ W1 + b1 (bf16 out) + BN partials ----------------
__global__ __launch_bounds__(256) void gemm1_mfma_kernel(
        const unsigned short* __restrict__ aggb, const unsigned short* __restrict__ W1t,
        const float* __restrict__ bias, unsigned short* __restrict__ hb,
        float* __restrict__ stats_partial) {
    const int lane = threadIdx.x & 63;
    const int l15 = lane & 15, lhi = lane >> 4;
    const int w = threadIdx.x >> 6;

    bf16x8 bfrag[2][4];
    float bs[4];
#pragma unroll
    for (int f = 0; f < 4; ++f) {
        const unsigned short* wp = W1t + (size_t)(f * 16 + l15) * 64 + lhi * 8;
        bfrag[0][f] = *reinterpret_cast<const bf16x8*>(wp);
        bfrag[1][f] = *reinterpret_cast<const bf16x8*>(wp + 32);
        bs[f] = bias[f * 16 + l15];
    }

    float ssum[4] = {0.f, 0.f, 0.f, 0.f}, ssq[4] = {0.f, 0.f, 0.f, 0.f};

    const int tile0 = (blockIdx.x * 4 + w) * TPW1;
#pragma unroll
    for (int tt = 0; tt < TPW1; ++tt) {
        const int tile = tile0 + tt;
        if (tile < ROW_TILES) {
            const int r0 = tile * 16;
            const size_t arow = (size_t)(r0 + l15) * 64 + lhi * 8;
            bf16x8 a0 = *reinterpret_cast<const bf16x8*>(aggb + arow);
            bf16x8 a1 = *reinterpret_cast<const bf16x8*>(aggb + arow + 32);
            f32x4 acc[4];
#pragma unroll
            for (int f = 0; f < 4; ++f) acc[f] = (f32x4){bs[f], bs[f], bs[f], bs[f]};
#pragma unroll
            for (int f = 0; f < 4; ++f) {
                acc[f] = __builtin_amdgcn_mfma_f32_16x16x32_bf16(a0, bfrag[0][f], acc[f], 0, 0, 0);
                acc[f] = __builtin_amdgcn_mfma_f32_16x16x32_bf16(a1, bfrag[1][f], acc[f], 0, 0, 0);
            }
#pragma unroll
            for (int f = 0; f < 4; ++f)
#pragma unroll
                for (int i = 0; i < 4; ++i) {
                    hb[(size_t)(r0 + lhi * 4 + i) * 64 + f * 16 + l15] = f2bf_rne(acc[f][i]);
                    ssum[f] += acc[f][i];
                    ssq[f]  += acc[f][i] * acc[f][i];
                }
        }
    }

    __shared__ float red[2][4][256];
#pragma unroll
    for (int f = 0; f < 4; ++f) {
        red[0][f][threadIdx.x] = ssum[f];
        red[1][f][threadIdx.x] = ssq[f];
    }
    __syncthreads();
    if (threadIdx.x < 64) {
        int c = threadIdx.x, f = c >> 4, p = c & 15;
        float s = 0.f, q = 0.f;
#pragma unroll
        for (int u = 0; u < 16; ++u) {
            int t = (u >> 2) * 64 + (u & 3) * 16 + p;
            s += red[0][f][t];
            q += red[1][f][t];
        }
        stats_partial[(size_t)blockIdx.x * 128 + c]      = s;
        stats_partial[(size_t)blockIdx.x * 128 + 64 + c] = q;
    }
}

// ---------------- MFMA: BN-apply + ReLU + GEMM2 + ReLU -> bf16 (bf16 in) ----------------
__global__ __launch_bounds__(256) void bn_gemm_mfma_kernel(
        const unsigned short* __restrict__ hb, const unsigned short* __restrict__ W2t,
        const float* __restrict__ bias, const float* __restrict__ scale,
        const float* __restrict__ shift, unsigned short* __restrict__ outb) {
    const int lane = threadIdx.x & 63;
    const int l15 = lane & 15, lhi = lane >> 4;
    const int w = threadIdx.x >> 6;

    bf16x8 bfrag[2][4];
    float bs[4];
#pragma unroll
    for (int f = 0; f < 4; ++f) {
        const unsigned short* wp = W2t + (size_t)(f * 16 + l15) * 64 + lhi * 8;
        bfrag[0][f] = *reinterpret_cast<const bf16x8*>(wp);
        bfrag[1][f] = *reinterpret_cast<const bf16x8*>(wp + 32);
        bs[f] = bias[f * 16 + l15];
    }
    float sc[2][8], sh[2][8];
#pragma unroll
    for (int t = 0; t < 2; ++t)
#pragma unroll
        for (int j = 0; j < 8; ++j) {
            int k = t * 32 + lhi * 8 + j;
            sc[t][j] = scale[k];
            sh[t][j] = shift[k];
        }

    const int tile0 = (blockIdx.x * 4 + w) * TPW2;
#pragma unroll
    for (int tt = 0; tt < TPW2; ++tt) {
        const int tile = tile0 + tt;
        if (tile >= ROW_TILES) return;
        const int r0 = tile * 16;
        f32x4 acc[4];
#pragma unroll
        for (int f = 0; f < 4; ++f) acc[f] = (f32x4){bs[f], bs[f], bs[f], bs[f]};
#pragma unroll
        for (int t = 0; t < 2; ++t) {
            const unsigned short* hp = hb + (size_t)(r0 + l15) * 64 + t * 32 + lhi * 8;
            bf16x8 raw = *reinterpret_cast<const bf16x8*>(hp);
            bf16x8 a;
#pragma unroll
            for (int j = 0; j < 8; ++j)
                a[j] = (__bf16)fmaxf(fmaf(sc[t][j], (float)raw[j], sh[t][j]), 0.f);
#pragma unroll
            for (int f = 0; f < 4; ++f)
                acc[f] = __builtin_amdgcn_mfma_f32_16x16x32_bf16(a, bfrag[t][f], acc[f], 0, 0, 0);
        }
#pragma unroll
        for (int f = 0; f < 4; ++f)
#pragma unroll
            for (int i = 0; i < 4; ++i)
                outb[(size_t)(r0 + lhi * 4 + i) * 64 + f * 16 + l15] =
                    f2bf_rne(fmaxf(acc[f][i], 0.f));
    }
}

// ---------------- MFMA jump head: out = [x|h1|h2] @ Wjk + bjk ----------------
__global__ __launch_bounds__(256) void jumphead_mfma_kernel(
        const unsigned short* __restrict__ xb, const unsigned short* __restrict__ h1b,
        const unsigned short* __restrict__ h2b, const unsigned short* __restrict__ Wt,
        const float* __restrict__ bjk, float* __restrict__ out) {
    const int lane = threadIdx.x & 63;
    const int l15 = lane & 15, lhi = lane >> 4;
    const int w = threadIdx.x >> 6;

    bf16x8 bfrag[6][4];
    float bs[4];
#pragma unroll
    for (int f = 0; f < 4; ++f) {
        const unsigned short* wp = Wt + (size_t)(f * 16 + l15) * 192 + lhi * 8;
#pragma unroll
        for (int t = 0; t < 6; ++t)
            bfrag[t][f] = *reinterpret_cast<const bf16x8*>(wp + t * 32);
        bs[f] = bjk[f * 16 + l15];
    }

    const int tile0 = (blockIdx.x * 4 + w) * TPW2;
#pragma unroll
    for (int tt = 0; tt < TPW2; ++tt) {
        const int tile = tile0 + tt;
        if (tile >= ROW_TILES) return;
        const int r0 = tile * 16;
        const size_t arow = (size_t)(r0 + l15) * 64 + lhi * 8;
        bf16x8 a0 = *reinterpret_cast<const bf16x8*>(xb + arow);
        bf16x8 a1 = *reinterpret_cast<const bf16x8*>(xb + arow + 32);
        bf16x8 a2 = *reinterpret_cast<const bf16x8*>(h1b + arow);
        bf16x8 a3 = *reinterpret_cast<const bf16x8*>(h1b + arow + 32);
        bf16x8 a4 = *reinterpret_cast<const bf16x8*>(h2b + arow);
        bf16x8 a5 = *reinterpret_cast<const bf16x8*>(h2b + arow + 32);
        f32x4 acc[4];
#pragma unroll
        for (int f = 0; f < 4; ++f) acc[f] = (f32x4){bs[f], bs[f], bs[f], bs[f]};
#pragma unroll
        for (int f = 0; f < 4; ++f) {
            acc[f] = __builtin_amdgcn_mfma_f32_16x16x32_bf16(a0, bfrag[0][f], acc[f], 0, 0, 0);
            acc[f] = __builtin_amdgcn_mfma_f32_16x16x32_bf16(a1, bfrag[1][f], acc[f], 0, 0, 0);
            acc[f] = __builtin_amdgcn_mfma_f32_16x16x32_bf16(a2, bfrag[2][f], acc[f], 0, 0, 0);
            acc[f] = __builtin_amdgcn_mfma_f32_16x16x32_bf16(a3, bfrag[3][f], acc[f], 0, 0, 0);
            acc[f] = __builtin_amdgcn_mfma_f32_16x16x32_bf16(a4, bfrag[4][f], acc[f], 0, 0, 0);
            acc[f] = __builtin_amdgcn_mfma_f32_16x16x32_bf16(a5, bfrag[5][f], acc[f], 0, 0, 0);
        }
#pragma unroll
        for (int f = 0; f < 4; ++f)
#pragma unroll
            for (int i = 0; i < 4; ++i)
                out[(size_t)(r0 + lhi * 4 + i) * 64 + f * 16 + l15] = acc[f][i];
    }
}

// ---------------- BN finalize: parallel reduce of partials ----------------
__global__ __launch_bounds__(1024) void bn_finalize_kernel(
        const float* __restrict__ stats_partial, int nblocks,
        const float* __restrict__ gamma, const float* __restrict__ beta,
        float* __restrict__ scale, float* __restrict__ shift) {
    __shared__ float red[2][1024];
    const int t = threadIdx.x;
    const int c = t & 63;
    const int chunk = t >> 6;        // 0..15
    float s = 0.f, q = 0.f;
    for (int b = chunk; b < nblocks; b += 16) {
        s += stats_partial[(size_t)b * 128 + c];
        q += stats_partial[(size_t)b * 128 + 64 + c];
    }
    red[0][t] = s;
    red[1][t] = q;
    __syncthreads();
    if (chunk == 0) {
        float ss = 0.f, qq = 0.f;
#pragma unroll
        for (int k = 0; k < 16; ++k) {
            ss += red[0][k * 64 + c];
            qq += red[1][k * 64 + c];
        }
        float mean = ss / (float)N_NODES;
        float var  = qq / (float)N_NODES - mean * mean;
        float scl  = gamma[c] * rsqrtf(var + BN_EPS);
        scale[c] = scl;
        shift[c] = beta[c] - mean * scl;
    }
}

extern "C" void kernel_launch(void* const* d_in, const int* in_sizes, int n_in,
                              void* d_out, int out_size, void* d_ws, size_t ws_size,
                              hipStream_t stream) {
    const float* x    = (const float*)d_in[0];
    const int*   ei   = (const int*)d_in[1];
    const int*   src  = ei;
    const int*   dst  = ei + N_EDGES;
    const float* W1_0 = (const float*)d_in[3];
    const float* b1_0 = (const float*)d_in[4];
    const float* g_0  = (const float*)d_in[5];
    const float* be_0 = (const float*)d_in[6];
    const float* W2_0 = (const float*)d_in[7];
    const float* b2_0 = (const float*)d_in[8];
    const float* W1_1 = (const float*)d_in[9];
    const float* b1_1 = (const float*)d_in[10];
    const float* g_1  = (const float*)d_in[11];
    const float* be_1 = (const float*)d_in[12];
    const float* W2_1 = (const float*)d_in[13];
    const float* b2_1 = (const float*)d_in[14];
    const float* Wjk  = (const float*)d_in[15];
    const float* bjk  = (const float*)d_in[16];

    const size_t FEAT = (size_t)N_NODES * HID;

    unsigned short* aggb = (unsigned short*)d_ws;          // FEAT bf16
    unsigned short* hb   = aggb + FEAT;                    // FEAT bf16
    unsigned short* xb   = hb + FEAT;                      // FEAT bf16
    unsigned short* h1b  = xb + FEAT;                      // FEAT bf16
    unsigned short* h2b  = h1b + FEAT;                     // FEAT bf16; aliases `bucketed`
    float* stats = (float*)(h2b + FEAT);                   // G1_BLOCKS * 128
    float* scale = stats + (size_t)G1_BLOCKS * 128;
    float* shift = scale + 64;
    int*   off   = (int*)(shift + 64);                     // N_NODES + 1 (pad 2)
    int*   eidx  = off + N_NODES + 2;                      // N_EDGES
    int*   cnt   = eidx + N_EDGES;                         // MS_CNT
    int*   psum  = cnt + MS_CNT;                           // MS_CNT + 1 (pad 2)
    int*   bsums = psum + MS_CNT + 2;                      // 1024
    unsigned short* wjk_t = (unsigned short*)(bsums + 1024);// 64*192
    unsigned short* w2t_0 = wjk_t + 64 * 192;              // 64*64
    unsigned short* w2t_1 = w2t_0 + 64 * 64;               // 64*64
    unsigned short* w1t_0 = w2t_1 + 64 * 64;               // 64*64
    unsigned short* w1t_1 = w1t_0 + 64 * 64;               // 64*64
    int*   bucketed = (int*)h2b;                           // 6.4 MB, dead before h2b written
    float* out   = (float*)d_out;

    // ---------------- x -> bf16; all weight transposes (1 launch) ----------------
    cvt_bf16_kernel<<<(int)(FEAT / 8 / 256), 256, 0, stream>>>(x, xb);
    wtrans_all_kernel<<<(12288 + 16384 + 255) / 256, 256, 0, stream>>>(
        Wjk, W1_0, W2_0, W1_1, W2_1, wjk_t, w1t_0, w2t_0, w1t_1, w2t_1);

    // ---------------- CSR build via two-level multi-split ----------------
    msplit_hist_kernel<<<MS_BLOCKS, 256, 0, stream>>>(dst, cnt);
    scan_partial_g<<<GS_BLOCKS, 256, 0, stream>>>(cnt, psum, bsums, MS_CNT);
    scan_bsums_kernel<<<1, 256, 0, stream>>>(bsums, GS_BLOCKS);
    scan_addback_g<<<GS_BLOCKS, 256, 0, stream>>>(psum, bsums, MS_CNT, N_EDGES);
    msplit_scatter_kernel<<<MS_BLOCKS, 256, 0, stream>>>(src, dst, psum, bucketed);
    bucket_csr_kernel<<<NB, 256, 0, stream>>>(bucketed, psum, off, eidx);

    // ---------------- layer 0 ----------------
    gather_kernel<<<GATHER_BLOCKS, 256, 0, stream>>>(xb, off, eidx, aggb);
    gemm1_mfma_kernel<<<G1_BLOCKS, 256, 0, stream>>>(aggb, w1t_0, b1_0, hb, stats);
    bn_finalize_kernel<<<1, 1024, 0, stream>>>(stats, G1_BLOCKS, g_0, be_0, scale, shift);
    bn_gemm_mfma_kernel<<<G2_BLOCKS, 256, 0, stream>>>(hb, w2t_0, b2_0, scale, shift, h1b);

    // ---------------- layer 1 ----------------
    gather_kernel<<<GATHER_BLOCKS, 256, 0, stream>>>(h1b, off, eidx, aggb);
    gemm1_mfma_kernel<<<G1_BLOCKS, 256, 0, stream>>>(aggb, w1t_1, b1_1, hb, stats);
    bn_finalize_kernel<<<1, 1024, 0, stream>>>(stats, G1_BLOCKS, g_1, be_1, scale, shift);
    bn_gemm_mfma_kernel<<<G2_BLOCKS, 256, 0, stream>>>(hb, w2t_1, b2_1, scale, shift, h2b);

    // ---------------- fused jump head (MFMA) ----------------
    jumphead_mfma_kernel<<<G2_BLOCKS, 256, 0, stream>>>(
        xb, h1b, h2b, wjk_t, bjk, out);
}

// Round 12
// 190.286 us; speedup vs baseline: 3.6304x; 1.0721x over previous
//
#include <hip/hip_runtime.h>

#define N_NODES 100000
#define N_EDGES 1600000
#define HID 64
#define BN_EPS 1e-5f

// ---- gather: 8 nodes/wave, 32 nodes/block ----
#define GATHER_BLOCKS (N_NODES / 32)                 // 3125 (exact)

// ---- MFMA tiling: 16-row tiles ----
#define ROW_TILES (N_NODES / 16)                     // 6250 (exact)
#define TPW1 4                                       // tiles/wave, gemm1
#define G1_BLOCKS ((ROW_TILES + 4*TPW1 - 1) / (4*TPW1))   // 391
#define TPW2 2                                       // tiles/wave, bn_gemm & fused jk
#define G2_BLOCKS ((ROW_TILES + 4*TPW2 - 1) / (4*TPW2))   // 782

// ---- multi-split CSR build parameters ----
#define NB 391                              // coarse buckets of 256 nodes (dst>>8)
#define MS_BLOCKS 1000
#define MS_EPB (N_EDGES / MS_BLOCKS)        // 1600 edges per block
#define MS_CNT (NB * MS_BLOCKS)             // 391000 segment counters
#define GS_CHUNK 512
#define GS_BLOCKS ((MS_CNT + GS_CHUNK - 1) / GS_CHUNK)   // 764

// ---- prep kernel block ranges ----
#define CVT_B 3125                          // FEAT/8/256
#define WT_B 112                            // (12288+16384)/256
#define PREP_BLOCKS (CVT_B + WT_B + MS_BLOCKS)

typedef __bf16 bf16x8 __attribute__((ext_vector_type(8)));
typedef float  f32x4  __attribute__((ext_vector_type(4)));
typedef unsigned short u16x8 __attribute__((ext_vector_type(8)));

__device__ __forceinline__ float bf2f(unsigned short u) {
    return __uint_as_float(((unsigned)u) << 16);
}
__device__ __forceinline__ unsigned short f2bf_rne(float f) {
    unsigned u = __float_as_uint(f);
    u += 0x7FFFu + ((u >> 16) & 1u);
    return (unsigned short)(u >> 16);
}

// ---------------- prep: x->bf16 cvt + weight transposes + msplit hist ----------------
__global__ __launch_bounds__(256) void prep_kernel(
        const float* __restrict__ x, unsigned short* __restrict__ xb,
        const float* __restrict__ Wjk,
        const float* __restrict__ W1_0, const float* __restrict__ W2_0,
        const float* __restrict__ W1_1, const float* __restrict__ W2_1,
        unsigned short* __restrict__ wjk_t,
        unsigned short* __restrict__ w1t_0, unsigned short* __restrict__ w2t_0,
        unsigned short* __restrict__ w1t_1, unsigned short* __restrict__ w2t_1,
        const int* __restrict__ dst, int* __restrict__ cnt) {
    __shared__ int h[NB];
    const int b = blockIdx.x;
    if (b < CVT_B) {
        size_t i = ((size_t)b * 256 + threadIdx.x) * 8;
        float4 a = *reinterpret_cast<const float4*>(x + i);
        float4 c = *reinterpret_cast<const float4*>(x + i + 4);
        ushort4 w0 = make_ushort4(f2bf_rne(a.x), f2bf_rne(a.y), f2bf_rne(a.z), f2bf_rne(a.w));
        ushort4 w1 = make_ushort4(f2bf_rne(c.x), f2bf_rne(c.y), f2bf_rne(c.z), f2bf_rne(c.w));
        *reinterpret_cast<ushort4*>(xb + i) = w0;
        *reinterpret_cast<ushort4*>(xb + i + 4) = w1;
    } else if (b < CVT_B + WT_B) {
        int i = (b - CVT_B) * 256 + threadIdx.x;
        if (i < 12288) {
            int c = i / 192, k = i - c * 192;
            wjk_t[i] = f2bf_rne(Wjk[k * 64 + c]);
        } else {
            int r = i - 12288;
            int which = r >> 12, rem = r & 4095;
            int c = rem >> 6, k = rem & 63;
            const float* W = (which == 0) ? W1_0 : (which == 1) ? W2_0
                           : (which == 2) ? W1_1 : W2_1;
            unsigned short* Wt = (which == 0) ? w1t_0 : (which == 1) ? w2t_0
                               : (which == 2) ? w1t_1 : w2t_1;
            Wt[rem] = f2bf_rne(W[k * 64 + c]);
        }
    } else {
        const int hb = b - CVT_B - WT_B;
        for (int i = threadIdx.x; i < NB; i += 256) h[i] = 0;
        __syncthreads();
        const int e0 = hb * MS_EPB;
        for (int e = e0 + threadIdx.x; e < e0 + MS_EPB; e += 256)
            atomicAdd(&h[dst[e] >> 8], 1);
        __syncthreads();
        for (int i = threadIdx.x; i < NB; i += 256)
            cnt[i * MS_BLOCKS + hb] = h[i];
    }
}

// ---------------- generic exclusive scan (3 kernels) ----------------
__global__ __launch_bounds__(256) void scan_partial_g(
        const int* __restrict__ in, int* __restrict__ out,
        int* __restrict__ bsums, int n) {
    __shared__ int sd[256];
    int t = threadIdx.x;
    int base = blockIdx.x * GS_CHUNK;
    int i0 = base + 2 * t, i1 = i0 + 1;
    int d0 = (i0 < n) ? in[i0] : 0;
    int d1 = (i1 < n) ? in[i1] : 0;
    sd[t] = d0 + d1;
    __syncthreads();
    for (int o = 1; o < 256; o <<= 1) {
        int v = (t >= o) ? sd[t - o] : 0;
        __syncthreads();
        sd[t] += v;
        __syncthreads();
    }
    int excl = sd[t] - (d0 + d1);
    if (i0 < n) out[i0] = excl;
    if (i1 < n) out[i1] = excl + d0;
    if (t == 255) bsums[blockIdx.x] = sd[255];
}

// single-block scan of up to 1024 block-sums (4 per thread)
__global__ __launch_bounds__(256) void scan_bsums_kernel(int* __restrict__ bsums, int nb) {
    __shared__ int sd[256];
    int t = threadIdx.x;
    int v[4]; int s = 0;
#pragma unroll
    for (int k = 0; k < 4; ++k) {
        int i = t * 4 + k;
        v[k] = (i < nb) ? bsums[i] : 0;
        s += v[k];
    }
    sd[t] = s;
    __syncthreads();
    for (int o = 1; o < 256; o <<= 1) {
        int u = (t >= o) ? sd[t - o] : 0;
        __syncthreads();
        sd[t] += u;
        __syncthreads();
    }
    int run = sd[t] - s;
#pragma unroll
    for (int k = 0; k < 4; ++k) {
        int i = t * 4 + k;
        if (i < nb) bsums[i] = run;
        run += v[k];
    }
}

__global__ __launch_bounds__(256) void scan_addback_g(
        int* __restrict__ out, const int* __restrict__ bsums, int n, int total) {
    int t = threadIdx.x;
    int b = bsums[blockIdx.x];
    int base = blockIdx.x * GS_CHUNK;
    int i0 = base + 2 * t, i1 = i0 + 1;
    if (i0 < n) out[i0] += b;
    if (i1 < n) out[i1] += b;
    if (blockIdx.x == 0 && t == 0) out[n] = total;   // sentinel
}

// ---------------- multi-split phase B: scatter packed (src<<8|dlocal) ----------------
__global__ __launch_bounds__(256) void msplit_scatter_kernel(
        const int* __restrict__ src, const int* __restrict__ dst,
        const int* __restrict__ psum, int* __restrict__ bucketed) {
    __shared__ int cur[NB];
    for (int i = threadIdx.x; i < NB; i += 256)
        cur[i] = psum[i * MS_BLOCKS + blockIdx.x];
    __syncthreads();
    const int e0 = blockIdx.x * MS_EPB;
    for (int e = e0 + threadIdx.x; e < e0 + MS_EPB; e += 256) {
        int d = dst[e];
        int p = atomicAdd(&cur[d >> 8], 1);
        bucketed[p] = (src[e] << 8) | (d & 255);
    }
}

// ---------------- per-bucket local CSR (256-node buckets) ----------------
__global__ __launch_bounds__(256) void bucket_csr_kernel(
        const int* __restrict__ bucketed, const int* __restrict__ psum,
        int* __restrict__ off, int* __restrict__ eidx) {
    const int j = blockIdx.x;
    const int t = threadIdx.x;
    __shared__ int deg[256];
    __shared__ int sd[256];
    __shared__ int base_s, size_s;
    if (t == 0) {
        int b = psum[j * MS_BLOCKS];
        int nxt = (j == NB - 1) ? N_EDGES : psum[(j + 1) * MS_BLOCKS];
        base_s = b; size_s = nxt - b;
    }
    deg[t] = 0;
    __syncthreads();
    const int base = base_s, size = size_s;
    const int nlo = j << 8;
    for (int i = t; i < size; i += 256)
        atomicAdd(&deg[(unsigned)bucketed[base + i] & 255u], 1);
    __syncthreads();
    int d0 = deg[t];
    sd[t] = d0;
    __syncthreads();
    for (int o = 1; o < 256; o <<= 1) {
        int v = (t >= o) ? sd[t - o] : 0;
        __syncthreads();
        sd[t] += v;
        __syncthreads();
    }
    int excl = sd[t] - d0;
    int g0 = nlo + t;
    if (g0 <= N_NODES) off[g0] = base + excl;
    __syncthreads();
    deg[t] = excl;
    __syncthreads();
    for (int i = t; i < size; i += 256) {
        unsigned e = (unsigned)bucketed[base + i];
        int p = atomicAdd(&deg[e & 255u], 1);
        eidx[base + p] = (int)(e >> 8);
    }
}

// ---------------- gather: 8 nodes per wave, lane-private accumulators ----------------
__global__ __launch_bounds__(256) void gather_kernel(
        const unsigned short* __restrict__ xb, const int* __restrict__ off,
        const int* __restrict__ eidx, unsigned short* __restrict__ aggb) {
    const int lane = threadIdx.x & 63;
    const int g    = lane >> 3;
    const int col  = (lane & 7) << 3;
    const int w    = threadIdx.x >> 6;
    const int n = blockIdx.x * 32 + w * 8 + g;

    const int beg = off[n], end = off[n + 1];
    bf16x8 s8 = *reinterpret_cast<const bf16x8*>(xb + (size_t)n * HID + col);
    float acc[8];
#pragma unroll
    for (int i = 0; i < 8; ++i) acc[i] = (float)s8[i];   // (1+eps)*x self, eps=0

    int j = beg;
    for (; j + 4 <= end; j += 4) {
        int s0 = eidx[j], s1 = eidx[j + 1], s2 = eidx[j + 2], s3 = eidx[j + 3];
        bf16x8 r0 = *reinterpret_cast<const bf16x8*>(xb + (size_t)s0 * HID + col);
        bf16x8 r1 = *reinterpret_cast<const bf16x8*>(xb + (size_t)s1 * HID + col);
        bf16x8 r2 = *reinterpret_cast<const bf16x8*>(xb + (size_t)s2 * HID + col);
        bf16x8 r3 = *reinterpret_cast<const bf16x8*>(xb + (size_t)s3 * HID + col);
#pragma unroll
        for (int i = 0; i < 8; ++i)
            acc[i] += ((float)r0[i] + (float)r1[i]) + ((float)r2[i] + (float)r3[i]);
    }
    for (; j < end; ++j) {
        int s0 = eidx[j];
        bf16x8 r0 = *reinterpret_cast<const bf16x8*>(xb + (size_t)s0 * HID + col);
#pragma unroll
        for (int i = 0; i < 8; ++i) acc[i] += (float)r0[i];
    }

    u16x8 o;
#pragma unroll
    for (int i = 0; i < 8; ++i) o[i] = f2bf_rne(acc[i]);
    *reinterpret_cast<u16x8*>(aggb + (size_t)n * HID + col) = o;
}

// ---------------- MFMA GEMM1: hb = aggb @ W1 + b1 (bf16 out) + BN partials ----------------
__global__ __launch_bounds__(256) void gemm1_mfma_kernel(
        const unsigned short* __restrict__ aggb, const unsigned short* __restrict__ W1t,
        const float* __restrict__ bias, unsigned short* __restrict__ hb,
        float* __restrict__ stats_partial) {
    const int lane = threadIdx.x & 63;
    const int l15 = lane & 15, lhi = lane >> 4;
    const int w = threadIdx.x >> 6;

    bf16x8 bfrag[2][4];
    float bs[4];
#pragma unroll
    for (int f = 0; f < 4; ++f) {
        const unsigned short* wp = W1t + (size_t)(f * 16 + l15) * 64 + lhi * 8;
        bfrag[0][f] = *reinterpret_cast<const bf16x8*>(wp);
        bfrag[1][f] = *reinterpret_cast<const bf16x8*>(wp + 32);
        bs[f] = bias[f * 16 + l15];
    }

    float ssum[4] = {0.f, 0.f, 0.f, 0.f}, ssq[4] = {0.f, 0.f, 0.f, 0.f};

    const int tile0 = (blockIdx.x * 4 + w) * TPW1;
#pragma unroll
    for (int tt = 0; tt < TPW1; ++tt) {
        const int tile = tile0 + tt;
        if (tile < ROW_TILES) {
            const int r0 = tile * 16;
            const size_t arow = (size_t)(r0 + l15) * 64 + lhi * 8;
            bf16x8 a0 = *reinterpret_cast<const bf16x8*>(aggb + arow);
            bf16x8 a1 = *reinterpret_cast<const bf16x8*>(aggb + arow + 32);
            f32x4 acc[4];
#pragma unroll
            for (int f = 0; f < 4; ++f) acc[f] = (f32x4){bs[f], bs[f], bs[f], bs[f]};
#pragma unroll
            for (int f = 0; f < 4; ++f) {
                acc[f] = __builtin_amdgcn_mfma_f32_16x16x32_bf16(a0, bfrag[0][f], acc[f], 0, 0, 0);
                acc[f] = __builtin_amdgcn_mfma_f32_16x16x32_bf16(a1, bfrag[1][f], acc[f], 0, 0, 0);
            }
#pragma unroll
            for (int f = 0; f < 4; ++f)
#pragma unroll
                for (int i = 0; i < 4; ++i) {
                    hb[(size_t)(r0 + lhi * 4 + i) * 64 + f * 16 + l15] = f2bf_rne(acc[f][i]);
                    ssum[f] += acc[f][i];
                    ssq[f]  += acc[f][i] * acc[f][i];
                }
        }
    }

    __shared__ float red[2][4][256];
#pragma unroll
    for (int f = 0; f < 4; ++f) {
        red[0][f][threadIdx.x] = ssum[f];
        red[1][f][threadIdx.x] = ssq[f];
    }
    __syncthreads();
    if (threadIdx.x < 64) {
        int c = threadIdx.x, f = c >> 4, p = c & 15;
        float s = 0.f, q = 0.f;
#pragma unroll
        for (int u = 0; u < 16; ++u) {
            int t = (u >> 2) * 64 + (u & 3) * 16 + p;
            s += red[0][f][t];
            q += red[1][f][t];
        }
        stats_partial[(size_t)blockIdx.x * 128 + c]      = s;
        stats_partial[(size_t)blockIdx.x * 128 + 64 + c] = q;
    }
}

// ---------------- MFMA: BN-apply + ReLU + GEMM2 + ReLU -> bf16 (layer 0) ----------------
__global__ __launch_bounds__(256) void bn_gemm_mfma_kernel(
        const unsigned short* __restrict__ hb, const unsigned short* __restrict__ W2t,
        const float* __restrict__ bias, const float* __restrict__ scale,
        const float* __restrict__ shift, unsigned short* __restrict__ outb) {
    const int lane = threadIdx.x & 63;
    const int l15 = lane & 15, lhi = lane >> 4;
    const int w = threadIdx.x >> 6;

    bf16x8 bfrag[2][4];
    float bs[4];
#pragma unroll
    for (int f = 0; f < 4; ++f) {
        const unsigned short* wp = W2t + (size_t)(f * 16 + l15) * 64 + lhi * 8;
        bfrag[0][f] = *reinterpret_cast<const bf16x8*>(wp);
        bfrag[1][f] = *reinterpret_cast<const bf16x8*>(wp + 32);
        bs[f] = bias[f * 16 + l15];
    }
    float sc[2][8], sh[2][8];
#pragma unroll
    for (int t = 0; t < 2; ++t)
#pragma unroll
        for (int j = 0; j < 8; ++j) {
            int k = t * 32 + lhi * 8 + j;
            sc[t][j] = scale[k];
            sh[t][j] = shift[k];
        }

    const int tile0 = (blockIdx.x * 4 + w) * TPW2;
#pragma unroll
    for (int tt = 0; tt < TPW2; ++tt) {
        const int tile = tile0 + tt;
        if (tile >= ROW_TILES) return;
        const int r0 = tile * 16;
        f32x4 acc[4];
#pragma unroll
        for (int f = 0; f < 4; ++f) acc[f] = (f32x4){bs[f], bs[f], bs[f], bs[f]};
#pragma unroll
        for (int t = 0; t < 2; ++t) {
            const unsigned short* hp = hb + (size_t)(r0 + l15) * 64 + t * 32 + lhi * 8;
            bf16x8 raw = *reinterpret_cast<const bf16x8*>(hp);
            bf16x8 a;
#pragma unroll
            for (int j = 0; j < 8; ++j)
                a[j] = (__bf16)fmaxf(fmaf(sc[t][j], (float)raw[j], sh[t][j]), 0.f);
#pragma unroll
            for (int f = 0; f < 4; ++f)
                acc[f] = __builtin_amdgcn_mfma_f32_16x16x32_bf16(a, bfrag[t][f], acc[f], 0, 0, 0);
        }
#pragma unroll
        for (int f = 0; f < 4; ++f)
#pragma unroll
            for (int i = 0; i < 4; ++i)
                outb[(size_t)(r0 + lhi * 4 + i) * 64 + f * 16 + l15] =
                    f2bf_rne(fmaxf(acc[f][i], 0.f));
    }
}

// ---------------- FUSED layer-1 BN+GEMM2+ReLU -> (LDS transpose) -> jump head ----------------
// h2 tile never touches global memory: GEMM2's C-layout output is staged
// through a per-wave LDS tile (stride 88 bf16, 16B-aligned reads) to become
// the jump head's third A-operand.
#define LT_STRIDE 88
__global__ __launch_bounds__(256) void bn_gemm_jumphead_kernel(
        const unsigned short* __restrict__ hb, const unsigned short* __restrict__ W2t,
        const float* __restrict__ bias2, const float* __restrict__ scale,
        const float* __restrict__ shift,
        const unsigned short* __restrict__ xb, const unsigned short* __restrict__ h1b,
        const unsigned short* __restrict__ Wt, const float* __restrict__ bjk,
        float* __restrict__ out) {
    __shared__ unsigned short lt[4][16 * LT_STRIDE];
    const int lane = threadIdx.x & 63;
    const int l15 = lane & 15, lhi = lane >> 4;
    const int w = threadIdx.x >> 6;

    // GEMM2 weights + BN constants
    bf16x8 b2frag[2][4];
    float bs2[4];
#pragma unroll
    for (int f = 0; f < 4; ++f) {
        const unsigned short* wp = W2t + (size_t)(f * 16 + l15) * 64 + lhi * 8;
        b2frag[0][f] = *reinterpret_cast<const bf16x8*>(wp);
        b2frag[1][f] = *reinterpret_cast<const bf16x8*>(wp + 32);
        bs2[f] = bias2[f * 16 + l15];
    }
    float sc[2][8], sh[2][8];
#pragma unroll
    for (int t = 0; t < 2; ++t)
#pragma unroll
        for (int j = 0; j < 8; ++j) {
            int k = t * 32 + lhi * 8 + j;
            sc[t][j] = scale[k];
            sh[t][j] = shift[k];
        }
    // jump head weights
    bf16x8 bjfrag[6][4];
    float bsj[4];
#pragma unroll
    for (int f = 0; f < 4; ++f) {
        const unsigned short* wp = Wt + (size_t)(f * 16 + l15) * 192 + lhi * 8;
#pragma unroll
        for (int t = 0; t < 6; ++t)
            bjfrag[t][f] = *reinterpret_cast<const bf16x8*>(wp + t * 32);
        bsj[f] = bjk[f * 16 + l15];
    }

    const int tile0 = (blockIdx.x * 4 + w) * TPW2;
#pragma unroll
    for (int tt = 0; tt < TPW2; ++tt) {
        const int tile = tile0 + tt;
        if (tile >= ROW_TILES) return;
        const int r0 = tile * 16;

        // ---- GEMM2 on BN(h)+ReLU ----
        f32x4 acc2[4];
#pragma unroll
        for (int f = 0; f < 4; ++f) acc2[f] = (f32x4){bs2[f], bs2[f], bs2[f], bs2[f]};
#pragma unroll
        for (int t = 0; t < 2; ++t) {
            const unsigned short* hp = hb + (size_t)(r0 + l15) * 64 + t * 32 + lhi * 8;
            bf16x8 raw = *reinterpret_cast<const bf16x8*>(hp);
            bf16x8 a;
#pragma unroll
            for (int j = 0; j < 8; ++j)
                a[j] = (__bf16)fmaxf(fmaf(sc[t][j], (float)raw[j], sh[t][j]), 0.f);
#pragma unroll
            for (int f = 0; f < 4; ++f)
                acc2[f] = __builtin_amdgcn_mfma_f32_16x16x32_bf16(a, b2frag[t][f], acc2[f], 0, 0, 0);
        }
        // ---- relu + C-layout -> LDS -> A-layout (per-wave, in-order DS pipe) ----
#pragma unroll
        for (int f = 0; f < 4; ++f)
#pragma unroll
            for (int i = 0; i < 4; ++i)
                lt[w][(lhi * 4 + i) * LT_STRIDE + f * 16 + l15] =
                    f2bf_rne(fmaxf(acc2[f][i], 0.f));
        bf16x8 a4 = *reinterpret_cast<const bf16x8*>(&lt[w][l15 * LT_STRIDE + lhi * 8]);
        bf16x8 a5 = *reinterpret_cast<const bf16x8*>(&lt[w][l15 * LT_STRIDE + 32 + lhi * 8]);

        // ---- jump head ----
        const size_t arow = (size_t)(r0 + l15) * 64 + lhi * 8;
        bf16x8 a0 = *reinterpret_cast<const bf16x8*>(xb + arow);
        bf16x8 a1 = *reinterpret_cast<const bf16x8*>(xb + arow + 32);
        bf16x8 a2 = *reinterpret_cast<const bf16x8*>(h1b + arow);
        bf16x8 a3 = *reinterpret_cast<const bf16x8*>(h1b + arow + 32);
        f32x4 accj[4];
#pragma unroll
        for (int f = 0; f < 4; ++f) accj[f] = (f32x4){bsj[f], bsj[f], bsj[f], bsj[f]};
#pragma unroll
        for (int f = 0; f < 4; ++f) {
            accj[f] = __builtin_amdgcn_mfma_f32_16x16x32_bf16(a0, bjfrag[0][f], accj[f], 0, 0, 0);
            accj[f] = __builtin_amdgcn_mfma_f32_16x16x32_bf16(a1, bjfrag[1][f], accj[f], 0, 0, 0);
            accj[f] = __builtin_amdgcn_mfma_f32_16x16x32_bf16(a2, bjfrag[2][f], accj[f], 0, 0, 0);
            accj[f] = __builtin_amdgcn_mfma_f32_16x16x32_bf16(a3, bjfrag[3][f], accj[f], 0, 0, 0);
            accj[f] = __builtin_amdgcn_mfma_f32_16x16x32_bf16(a4, bjfrag[4][f], accj[f], 0, 0, 0);
            accj[f] = __builtin_amdgcn_mfma_f32_16x16x32_bf16(a5, bjfrag[5][f], accj[f], 0, 0, 0);
        }
#pragma unroll
        for (int f = 0; f < 4; ++f)
#pragma unroll
            for (int i = 0; i < 4; ++i)
                out[(size_t)(r0 + lhi * 4 + i) * 64 + f * 16 + l15] = accj[f][i];
    }
}

// ---------------- BN finalize: parallel reduce of partials ----------------
__global__ __launch_bounds__(1024) void bn_finalize_kernel(
        const float* __restrict__ stats_partial, int nblocks,
        const float* __restrict__ gamma, const float* __restrict__ beta,
        float* __restrict__ scale, float* __restrict__ shift) {
    __shared__ float red[2][1024];
    const int t = threadIdx.x;
    const int c = t & 63;
    const int chunk = t >> 6;        // 0..15
    float s = 0.f, q = 0.f;
    for (int b = chunk; b < nblocks; b += 16) {
        s += stats_partial[(size_t)b * 128 + c];
        q += stats_partial[(size_t)b * 128 + 64 + c];
    }
    red[0][t] = s;
    red[1][t] = q;
    __syncthreads();
    if (chunk == 0) {
        float ss = 0.f, qq = 0.f;
#pragma unroll
        for (int k = 0; k < 16; ++k) {
            ss += red[0][k * 64 + c];
            qq += red[1][k * 64 + c];
        }
        float mean = ss / (float)N_NODES;
        float var  = qq / (float)N_NODES - mean * mean;
        float scl  = gamma[c] * rsqrtf(var + BN_EPS);
        scale[c] = scl;
        shift[c] = beta[c] - mean * scl;
    }
}

extern "C" void kernel_launch(void* const* d_in, const int* in_sizes, int n_in,
                              void* d_out, int out_size, void* d_ws, size_t ws_size,
                              hipStream_t stream) {
    const float* x    = (const float*)d_in[0];
    const int*   ei   = (const int*)d_in[1];
    const int*   src  = ei;
    const int*   dst  = ei + N_EDGES;
    const float* W1_0 = (const float*)d_in[3];
    const float* b1_0 = (const float*)d_in[4];
    const float* g_0  = (const float*)d_in[5];
    const float* be_0 = (const float*)d_in[6];
    const float* W2_0 = (const float*)d_in[7];
    const float* b2_0 = (const float*)d_in[8];
    const float* W1_1 = (const float*)d_in[9];
    const float* b1_1 = (const float*)d_in[10];
    const float* g_1  = (const float*)d_in[11];
    const float* be_1 = (const float*)d_in[12];
    const float* W2_1 = (const float*)d_in[13];
    const float* b2_1 = (const float*)d_in[14];
    const float* Wjk  = (const float*)d_in[15];
    const float* bjk  = (const float*)d_in[16];

    const size_t FEAT = (size_t)N_NODES * HID;

    unsigned short* aggb = (unsigned short*)d_ws;          // FEAT bf16
    unsigned short* hb   = aggb + FEAT;                    // FEAT bf16
    unsigned short* xb   = hb + FEAT;                      // FEAT bf16
    unsigned short* h1b  = xb + FEAT;                      // FEAT bf16
    int*   bucketed = (int*)(h1b + FEAT);                  // N_EDGES
    float* stats = (float*)(bucketed + N_EDGES);           // G1_BLOCKS * 128
    float* scale = stats + (size_t)G1_BLOCKS * 128;
    float* shift = scale + 64;
    int*   off   = (int*)(shift + 64);                     // N_NODES + 1 (pad 2)
    int*   eidx  = off + N_NODES + 2;                      // N_EDGES
    int*   cnt   = eidx + N_EDGES;                         // MS_CNT
    int*   psum  = cnt + MS_CNT;                           // MS_CNT + 1 (pad 2)
    int*   bsums = psum + MS_CNT + 2;                      // 1024
    unsigned short* wjk_t = (unsigned short*)(bsums + 1024);// 64*192
    unsigned short* w2t_0 = wjk_t + 64 * 192;              // 64*64
    unsigned short* w2t_1 = w2t_0 + 64 * 64;               // 64*64
    unsigned short* w1t_0 = w2t_1 + 64 * 64;               // 64*64
    unsigned short* w1t_1 = w1t_0 + 64 * 64;               // 64*64
    float* out   = (float*)d_out;

    // ---------------- prep: cvt + wtrans + hist in one launch ----------------
    prep_kernel<<<PREP_BLOCKS, 256, 0, stream>>>(
        x, xb, Wjk, W1_0, W2_0, W1_1, W2_1,
        wjk_t, w1t_0, w2t_0, w1t_1, w2t_1, dst, cnt);

    // ---------------- CSR build ----------------
    scan_partial_g<<<GS_BLOCKS, 256, 0, stream>>>(cnt, psum, bsums, MS_CNT);
    scan_bsums_kernel<<<1, 256, 0, stream>>>(bsums, GS_BLOCKS);
    scan_addback_g<<<GS_BLOCKS, 256, 0, stream>>>(psum, bsums, MS_CNT, N_EDGES);
    msplit_scatter_kernel<<<MS_BLOCKS, 256, 0, stream>>>(src, dst, psum, bucketed);
    bucket_csr_kernel<<<NB, 256, 0, stream>>>(bucketed, psum, off, eidx);

    // ---------------- layer 0 ----------------
    gather_kernel<<<GATHER_BLOCKS, 256, 0, stream>>>(xb, off, eidx, aggb);
    gemm1_mfma_kernel<<<G1_BLOCKS, 256, 0, stream>>>(aggb, w1t_0, b1_0, hb, stats);
    bn_finalize_kernel<<<1, 1024, 0, stream>>>(stats, G1_BLOCKS, g_0, be_0, scale, shift);
    bn_gemm_mfma_kernel<<<G2_BLOCKS, 256, 0, stream>>>(hb, w2t_0, b2_0, scale, shift, h1b);

    // ---------------- layer 1 (GEMM2 fused into jump head) ----------------
    gather_kernel<<<GATHER_BLOCKS, 256, 0, stream>>>(h1b, off, eidx, aggb);
    gemm1_mfma_kernel<<<G1_BLOCKS, 256, 0, stream>>>(aggb, w1t_1, b1_1, hb, stats);
    bn_finalize_kernel<<<1, 1024, 0, stream>>>(stats, G1_BLOCKS, g_1, be_1, scale, shift);
    bn_gemm_jumphead_kernel<<<G2_BLOCKS, 256, 0, stream>>>(
        hb, w2t_1, b2_1, scale, shift, xb, h1b, wjk_t, bjk, out);
}